// Round 1
// baseline (6228.876 us; speedup 1.0000x reference)
//
#include <hip/hip_runtime.h>
#include <math.h>

#define EPS 1e-5f

#define F_BIAS  1
#define F_BNB   2
#define F_DBN   4
#define F_GELU  8
#define F_RESID 16

// ---------------------------------------------------------------------------
// Pooling with fused BN1: out[n,c,lk] = mean_j(bn(x)) + max_j(bn(x)) over r
// ---------------------------------------------------------------------------
__global__ __launch_bounds__(256) void pool_bn_kernel(
    const float* __restrict__ x,
    const float* __restrict__ g, const float* __restrict__ b,
    const float* __restrict__ bm, const float* __restrict__ bvv,
    float* __restrict__ out,
    int N, int C, int L, int d, int c0, int r, int Lk)
{
    int idx = blockIdx.x * blockDim.x + threadIdx.x;
    int total = N * d * Lk;
    if (idx >= total) return;
    int lk = idx % Lk;
    int c  = (idx / Lk) % d;
    int n  = idx / (Lk * d);
    int cg = c0 + c;
    float inv = g[cg] * rsqrtf(bvv[cg] + EPS);
    float add = b[cg] - bm[cg] * inv;
    const float* xp = x + ((size_t)n * C + cg) * L + (size_t)lk * r;
    float s = 0.f, mx = -INFINITY;
    for (int j = 0; j < r; ++j) {
        float t = fmaf(xp[j], inv, add);
        s += t;
        mx = fmaxf(mx, t);
    }
    out[idx] = s * (1.0f / (float)r) + mx;
}

// ---------------------------------------------------------------------------
// Generic tiled fp32 GEMM:  C[m,p] = sum_k A[m,k] * B[k,p]  (+ epilogues)
// A: (M,K) row-major.  B: (K,Npos) row-major per batch (strideB).
// Tile 64x64, BK=16, 256 threads, 4x4 per thread.
// flags: F_BIAS add bias[m]; F_BNB apply BN (bng..bnv at koff+k) to B on load;
//        F_DBN double-BN epilogue per row; F_GELU tanh-gelu; F_RESID add resid.
// val = gelu(dbn((acc + bias) * oscale)) + resid
// ---------------------------------------------------------------------------
__global__ __launch_bounds__(256) void gemm_ep_kernel(
    const float* __restrict__ A, const float* __restrict__ B, float* __restrict__ C,
    int M, int K, int Npos, long long strideB, long long strideC,
    const float* __restrict__ bias, float oscale,
    const float* __restrict__ bng, const float* __restrict__ bnb,
    const float* __restrict__ bnm, const float* __restrict__ bnv, int koff,
    const float* __restrict__ agg, const float* __restrict__ agb,
    const float* __restrict__ agm, const float* __restrict__ agv,
    const float* __restrict__ ang, const float* __restrict__ anb,
    const float* __restrict__ anm, const float* __restrict__ anv,
    const float* __restrict__ resid, long long strideR, int flags)
{
    __shared__ float As[16][68];
    __shared__ float Bs[16][68];
    const int tid = threadIdx.x;
    const int m0 = blockIdx.y * 64;
    const int p0 = blockIdx.x * 64;
    const int nz = blockIdx.z;
    const float* Bn = B + (size_t)nz * strideB;

    const int tm = (tid >> 4) * 4;     // 0..60
    const int tn = (tid & 15) * 4;     // 0..60

    float acc[4][4] = {{0.f}};

    for (int k0 = 0; k0 < K; k0 += 16) {
        // stage A tile (64 rows x 16 k), transposed into As[k][m]
        #pragma unroll
        for (int i = 0; i < 4; ++i) {
            int e = tid + i * 256;
            int mrow = e >> 4, kk = e & 15;
            As[kk][mrow] = A[(size_t)(m0 + mrow) * K + (k0 + kk)];
        }
        // stage B tile (16 k x 64 pos), optional BN on load
        #pragma unroll
        for (int i = 0; i < 4; ++i) {
            int kk = (tid >> 6) + i * 4;
            int pp = tid & 63;
            float val = Bn[(size_t)(k0 + kk) * Npos + (p0 + pp)];
            if (flags & F_BNB) {
                int kg = koff + k0 + kk;
                float inv = bng[kg] * rsqrtf(bnv[kg] + EPS);
                val = fmaf(val, inv, bnb[kg] - bnm[kg] * inv);
            }
            Bs[kk][pp] = val;
        }
        __syncthreads();
        #pragma unroll
        for (int kk = 0; kk < 16; ++kk) {
            float4 av = *reinterpret_cast<const float4*>(&As[kk][tm]);
            float4 bv = *reinterpret_cast<const float4*>(&Bs[kk][tn]);
            float a[4] = {av.x, av.y, av.z, av.w};
            float bb4[4] = {bv.x, bv.y, bv.z, bv.w};
            #pragma unroll
            for (int ii = 0; ii < 4; ++ii)
                #pragma unroll
                for (int jj = 0; jj < 4; ++jj)
                    acc[ii][jj] = fmaf(a[ii], bb4[jj], acc[ii][jj]);
        }
        __syncthreads();
    }

    float* Cn = C + (size_t)nz * strideC;
    const float* Rn = resid + (size_t)nz * strideR;   // only deref'd if F_RESID
    #pragma unroll
    for (int ii = 0; ii < 4; ++ii) {
        int mi = m0 + tm + ii;
        float bval = (flags & F_BIAS) ? bias[mi] : 0.f;
        float s1 = 1.f, t1 = 0.f, s2 = 1.f, t2 = 0.f;
        if (flags & F_DBN) {
            float i1 = agg[mi] * rsqrtf(agv[mi] + EPS);
            s1 = i1; t1 = agb[mi] - agm[mi] * i1;
            float i2 = ang[mi] * rsqrtf(anv[mi] + EPS);
            s2 = i2; t2 = anb[mi] - anm[mi] * i2;
        }
        #pragma unroll
        for (int jj = 0; jj < 4; ++jj) {
            float val = (acc[ii][jj] + bval) * oscale;
            if (flags & F_DBN) { val = fmaf(val, s1, t1); val = fmaf(val, s2, t2); }
            if (flags & F_GELU) {
                float u = val;
                float t = tanhf(0.7978845608028654f * (u + 0.044715f * u * u * u));
                val = 0.5f * u * (1.f + t);
            }
            size_t off = (size_t)mi * Npos + (size_t)(p0 + tn + jj);
            if (flags & F_RESID) val += Rn[off];
            Cn[off] = val;
        }
    }
}

// ---------------------------------------------------------------------------
// Flash-style attention, fp32.
// q: (N,d,L) pre-scaled by 1/8.  k,v: (N,d,Lk).  o: (N,d,L).
// grid: (L/64, N*Nh). block 256 = 4 waves; wave handles 16 queries.
// lane = qi*4+mg: qi in 0..15 (query within wave), mg in 0..3 (16-wide slice
// of keys for scores / of e-dim for output accumulation).
// ---------------------------------------------------------------------------
__global__ __launch_bounds__(256) void attn_kernel(
    const float* __restrict__ q, const float* __restrict__ k,
    const float* __restrict__ v, float* __restrict__ o,
    int N, int d, int L, int Lk, int Nh)
{
    const int l0 = blockIdx.x * 64;
    const int nh = blockIdx.y;
    const int n = nh / Nh, h = nh % Nh;
    const size_t qbase = ((size_t)n * d + (size_t)h * 64) * L;
    const size_t kbase = ((size_t)n * d + (size_t)h * 64) * Lk;

    __shared__ float q_s[64][65];
    __shared__ float k_s[64][65];
    __shared__ float v_s[64][65];
    __shared__ float p_s[4][16][65];

    const int tid = threadIdx.x;
    // stage q tile: q_s[e][ql]
    #pragma unroll
    for (int i = 0; i < 16; ++i) {
        int e = (tid >> 6) + i * 4;
        int c = tid & 63;
        q_s[e][c] = q[qbase + (size_t)e * L + (l0 + c)];
    }
    __syncthreads();

    const int wave = tid >> 6;
    const int lane = tid & 63;
    const int qi = lane >> 2;
    const int mg = lane & 3;
    const int ql = wave * 16 + qi;

    float qreg[64];
    #pragma unroll
    for (int e = 0; e < 64; ++e) qreg[e] = q_s[e][ql];

    float o_acc[16];
    #pragma unroll
    for (int j = 0; j < 16; ++j) o_acc[j] = 0.f;
    float mrow = -INFINITY, lrow = 0.f;

    for (int mc = 0; mc < Lk; mc += 64) {
        __syncthreads();   // prev chunk's p_s/v_s reads done
        #pragma unroll
        for (int i = 0; i < 16; ++i) {
            int e = (tid >> 6) + i * 4;
            int c = tid & 63;
            k_s[e][c] = k[kbase + (size_t)e * Lk + (mc + c)];
            v_s[e][c] = v[kbase + (size_t)e * Lk + (mc + c)];
        }
        __syncthreads();

        // scores for 16 keys: m = mg*16 + j
        float s[16];
        #pragma unroll
        for (int j = 0; j < 16; ++j) s[j] = 0.f;
        #pragma unroll
        for (int e = 0; e < 64; ++e) {
            float qe = qreg[e];
            #pragma unroll
            for (int j = 0; j < 16; ++j)
                s[j] = fmaf(qe, k_s[e][mg * 16 + j], s[j]);
        }
        // online softmax (row state shared by the 4 mg-lanes of this qi)
        float cm = s[0];
        #pragma unroll
        for (int j = 1; j < 16; ++j) cm = fmaxf(cm, s[j]);
        cm = fmaxf(cm, __shfl_xor(cm, 1));
        cm = fmaxf(cm, __shfl_xor(cm, 2));
        float nm = fmaxf(mrow, cm);
        float alpha = __expf(mrow - nm);    // 0 on first chunk
        float csum = 0.f;
        float p[16];
        #pragma unroll
        for (int j = 0; j < 16; ++j) { p[j] = __expf(s[j] - nm); csum += p[j]; }
        csum += __shfl_xor(csum, 1);
        csum += __shfl_xor(csum, 2);
        lrow = lrow * alpha + csum;
        mrow = nm;
        // share p across the 4 mg-lanes via LDS (same wave -> DS in-order)
        #pragma unroll
        for (int j = 0; j < 16; ++j) p_s[wave][qi][mg * 16 + j] = p[j];
        #pragma unroll
        for (int j = 0; j < 16; ++j) o_acc[j] *= alpha;
        for (int m = 0; m < 64; ++m) {
            float pm = p_s[wave][qi][m];
            #pragma unroll
            for (int j = 0; j < 16; ++j)
                o_acc[j] = fmaf(pm, v_s[mg * 16 + j][m], o_acc[j]);
        }
    }
    float invl = 1.f / lrow;
    #pragma unroll
    for (int j = 0; j < 16; ++j)
        o[qbase + (size_t)(mg * 16 + j) * L + (l0 + ql)] = o_acc[j] * invl;
}

// ---------------------------------------------------------------------------
extern "C" void kernel_launch(void* const* d_in, const int* in_sizes, int n_in,
                              void* d_out, int out_size, void* d_ws, size_t ws_size,
                              hipStream_t stream)
{
    const float* x   = (const float*)d_in[0];
    const float* n1g = (const float*)d_in[1];
    const float* n1b = (const float*)d_in[2];
    const float* n1m = (const float*)d_in[3];
    const float* n1v = (const float*)d_in[4];
    const float* n2g = (const float*)d_in[5];
    const float* n2b = (const float*)d_in[6];
    const float* n2m = (const float*)d_in[7];
    const float* n2v = (const float*)d_in[8];
    const float* Wq  = (const float*)d_in[9];
    const float* Wk  = (const float*)d_in[10];
    const float* Wv  = (const float*)d_in[11];
    const float* Wo  = (const float*)d_in[12];
    const float* Wp  = (const float*)d_in[13];
    const float* bq  = (const float*)d_in[14];
    const float* bk  = (const float*)d_in[15];
    const float* bv  = (const float*)d_in[16];
    const float* bo  = (const float*)d_in[17];
    const float* agg = (const float*)d_in[18];
    const float* agb = (const float*)d_in[19];
    const float* agm = (const float*)d_in[20];
    const float* agv = (const float*)d_in[21];
    const float* ang = (const float*)d_in[22];
    const float* anb = (const float*)d_in[23];
    const float* anm = (const float*)d_in[24];
    const float* anv = (const float*)d_in[25];
    const float* W1  = (const float*)d_in[26];
    const float* b1  = (const float*)d_in[27];
    const float* W2  = (const float*)d_in[28];
    const float* b2  = (const float*)d_in[29];

    float* out = (float*)d_out;
    float* ws  = (float*)d_ws;

    const int N = 8, Cc = 512, L = 3072, P = 4, dd = 128, FF = 2048, Nh = 2;
    const int ratios[4] = {2, 4, 8, 16};

    // workspace layout (floats)
    float* qb  = ws;                                  // N*dd*L   = 3145728
    float* ob  = qb  + (size_t)N * dd * L;            // N*dd*L   = 3145728
    float* xa0 = ob  + (size_t)N * dd * L;            // N*dd*L/2 = 1572864
    float* xab = xa0 + (size_t)N * dd * (L / 2);
    float* kb  = xab + (size_t)N * dd * (L / 2);
    float* vb  = kb  + (size_t)N * dd * (L / 2);
    // FFN intermediate reuses [qb, ob] region (FF*L = 6291456 floats per n)
    float* m1 = ws;

    const float* nul = nullptr;

    for (int i = 0; i < P; ++i) {
        const int r = ratios[i], Lk = L / r;
        const int c0 = i * dd;

        int tot = N * dd * Lk;
        pool_bn_kernel<<<dim3((tot + 255) / 256), dim3(256), 0, stream>>>(
            x, n1g, n1b, n1m, n1v, xa0, N, Cc, L, dd, c0, r, Lk);

        // xa = doubleBN(Wp @ xa0)
        gemm_ep_kernel<<<dim3(Lk / 64, dd / 64, N), dim3(256), 0, stream>>>(
            Wp + (size_t)i * dd * dd, xa0, xab, dd, dd, Lk,
            (long long)dd * Lk, (long long)dd * Lk,
            nul, 1.f, nul, nul, nul, nul, 0,
            agg + c0, agb + c0, agm + c0, agv + c0,
            ang + c0, anb + c0, anm + c0, anv + c0,
            nul, 0, F_DBN);

        // q = (Wq @ bn1(x_slice) + bq) * 0.125
        gemm_ep_kernel<<<dim3(L / 64, dd / 64, N), dim3(256), 0, stream>>>(
            Wq + (size_t)i * dd * dd, x + (size_t)c0 * L, qb, dd, dd, L,
            (long long)Cc * L, (long long)dd * L,
            bq + c0, 0.125f, n1g, n1b, n1m, n1v, c0,
            nul, nul, nul, nul, nul, nul, nul, nul,
            nul, 0, F_BIAS | F_BNB);

        // k = Wk @ xa + bk ; v = Wv @ xa + bv
        gemm_ep_kernel<<<dim3(Lk / 64, dd / 64, N), dim3(256), 0, stream>>>(
            Wk + (size_t)i * dd * dd, xab, kb, dd, dd, Lk,
            (long long)dd * Lk, (long long)dd * Lk,
            bk + c0, 1.f, nul, nul, nul, nul, 0,
            nul, nul, nul, nul, nul, nul, nul, nul,
            nul, 0, F_BIAS);
        gemm_ep_kernel<<<dim3(Lk / 64, dd / 64, N), dim3(256), 0, stream>>>(
            Wv + (size_t)i * dd * dd, xab, vb, dd, dd, Lk,
            (long long)dd * Lk, (long long)dd * Lk,
            bv + c0, 1.f, nul, nul, nul, nul, 0,
            nul, nul, nul, nul, nul, nul, nul, nul,
            nul, 0, F_BIAS);

        attn_kernel<<<dim3(L / 64, N * Nh), dim3(256), 0, stream>>>(
            qb, kb, vb, ob, N, dd, L, Lk, Nh);

        // out_slice = x_slice + Wo @ o + bo
        gemm_ep_kernel<<<dim3(L / 64, dd / 64, N), dim3(256), 0, stream>>>(
            Wo + (size_t)i * dd * dd, ob, out + (size_t)c0 * L, dd, dd, L,
            (long long)dd * L, (long long)Cc * L,
            bo + c0, 1.f, nul, nul, nul, nul, 0,
            nul, nul, nul, nul, nul, nul, nul, nul,
            x + (size_t)c0 * L, (long long)Cc * L, F_BIAS | F_RESID);
    }

    // FFN per batch (m1 reuses q/o scratch)
    for (int n = 0; n < N; ++n) {
        float* xn = out + (size_t)n * Cc * L;
        gemm_ep_kernel<<<dim3(L / 64, FF / 64, 1), dim3(256), 0, stream>>>(
            W1, xn, m1, FF, Cc, L, 0, 0,
            b1, 1.f, n2g, n2b, n2m, n2v, 0,
            nul, nul, nul, nul, nul, nul, nul, nul,
            nul, 0, F_BIAS | F_BNB | F_GELU);
        gemm_ep_kernel<<<dim3(L / 64, Cc / 64, 1), dim3(256), 0, stream>>>(
            W2, m1, xn, Cc, FF, L, 0, 0,
            b2, 1.f, nul, nul, nul, nul, 0,
            nul, nul, nul, nul, nul, nul, nul, nul,
            xn, 0, F_BIAS | F_RESID);
    }
}

// Round 2
// 3100.058 us; speedup vs baseline: 2.0093x; 2.0093x over previous
//
#include <hip/hip_runtime.h>
#include <math.h>

#define EPS 1e-5f

#define F_BIAS  1
#define F_BNB   2
#define F_DBN   4
#define F_GELU  8
#define F_RESID 16

typedef __attribute__((ext_vector_type(8))) __bf16 bf16x8;
typedef __attribute__((ext_vector_type(4))) float f32x4;

__device__ __forceinline__ unsigned int pack2bf(float a, float b) {
    unsigned short ua = __builtin_bit_cast(unsigned short, (__bf16)a);
    unsigned short ub = __builtin_bit_cast(unsigned short, (__bf16)b);
    return (unsigned int)ua | ((unsigned int)ub << 16);
}

// ---------------------------------------------------------------------------
// Pooling with fused BN1: out[n,c,lk] = mean_j(bn(x)) + max_j(bn(x)) over r
// ---------------------------------------------------------------------------
__global__ __launch_bounds__(256) void pool_bn_kernel(
    const float* __restrict__ x,
    const float* __restrict__ g, const float* __restrict__ b,
    const float* __restrict__ bm, const float* __restrict__ bvv,
    float* __restrict__ out,
    int N, int C, int L, int d, int c0, int r, int Lk)
{
    int idx = blockIdx.x * blockDim.x + threadIdx.x;
    int total = N * d * Lk;
    if (idx >= total) return;
    int lk = idx % Lk;
    int c  = (idx / Lk) % d;
    int n  = idx / (Lk * d);
    int cg = c0 + c;
    float inv = g[cg] * rsqrtf(bvv[cg] + EPS);
    float add = b[cg] - bm[cg] * inv;
    const float* xp = x + ((size_t)n * C + cg) * L + (size_t)lk * r;
    float s = 0.f, mx = -INFINITY;
    for (int j = 0; j < r; ++j) {
        float t = fmaf(xp[j], inv, add);
        s += t;
        mx = fmaxf(mx, t);
    }
    out[idx] = s * (1.0f / (float)r) + mx;
}

// ---------------------------------------------------------------------------
// Generic tiled fp32 GEMM:  C[m,p] = sum_k A[m,k] * B[k,p]  (+ epilogues)
// ---------------------------------------------------------------------------
__global__ __launch_bounds__(256) void gemm_ep_kernel(
    const float* __restrict__ A, const float* __restrict__ B, float* __restrict__ C,
    int M, int K, int Npos, long long strideB, long long strideC,
    const float* __restrict__ bias, float oscale,
    const float* __restrict__ bng, const float* __restrict__ bnb,
    const float* __restrict__ bnm, const float* __restrict__ bnv, int koff,
    const float* __restrict__ agg, const float* __restrict__ agb,
    const float* __restrict__ agm, const float* __restrict__ agv,
    const float* __restrict__ ang, const float* __restrict__ anb,
    const float* __restrict__ anm, const float* __restrict__ anv,
    const float* __restrict__ resid, long long strideR, int flags)
{
    __shared__ float As[16][68];
    __shared__ float Bs[16][68];
    const int tid = threadIdx.x;
    const int m0 = blockIdx.y * 64;
    const int p0 = blockIdx.x * 64;
    const int nz = blockIdx.z;
    const float* Bn = B + (size_t)nz * strideB;

    const int tm = (tid >> 4) * 4;
    const int tn = (tid & 15) * 4;

    float acc[4][4] = {{0.f}};

    for (int k0 = 0; k0 < K; k0 += 16) {
        #pragma unroll
        for (int i = 0; i < 4; ++i) {
            int e = tid + i * 256;
            int mrow = e >> 4, kk = e & 15;
            As[kk][mrow] = A[(size_t)(m0 + mrow) * K + (k0 + kk)];
        }
        #pragma unroll
        for (int i = 0; i < 4; ++i) {
            int kk = (tid >> 6) + i * 4;
            int pp = tid & 63;
            float val = Bn[(size_t)(k0 + kk) * Npos + (p0 + pp)];
            if (flags & F_BNB) {
                int kg = koff + k0 + kk;
                float inv = bng[kg] * rsqrtf(bnv[kg] + EPS);
                val = fmaf(val, inv, bnb[kg] - bnm[kg] * inv);
            }
            Bs[kk][pp] = val;
        }
        __syncthreads();
        #pragma unroll
        for (int kk = 0; kk < 16; ++kk) {
            float4 av = *reinterpret_cast<const float4*>(&As[kk][tm]);
            float4 bv = *reinterpret_cast<const float4*>(&Bs[kk][tn]);
            float a[4] = {av.x, av.y, av.z, av.w};
            float bb4[4] = {bv.x, bv.y, bv.z, bv.w};
            #pragma unroll
            for (int ii = 0; ii < 4; ++ii)
                #pragma unroll
                for (int jj = 0; jj < 4; ++jj)
                    acc[ii][jj] = fmaf(a[ii], bb4[jj], acc[ii][jj]);
        }
        __syncthreads();
    }

    float* Cn = C + (size_t)nz * strideC;
    const float* Rn = resid + (size_t)nz * strideR;
    #pragma unroll
    for (int ii = 0; ii < 4; ++ii) {
        int mi = m0 + tm + ii;
        float bval = (flags & F_BIAS) ? bias[mi] : 0.f;
        float s1 = 1.f, t1 = 0.f, s2 = 1.f, t2 = 0.f;
        if (flags & F_DBN) {
            float i1 = agg[mi] * rsqrtf(agv[mi] + EPS);
            s1 = i1; t1 = agb[mi] - agm[mi] * i1;
            float i2 = ang[mi] * rsqrtf(anv[mi] + EPS);
            s2 = i2; t2 = anb[mi] - anm[mi] * i2;
        }
        #pragma unroll
        for (int jj = 0; jj < 4; ++jj) {
            float val = (acc[ii][jj] + bval) * oscale;
            if (flags & F_DBN) { val = fmaf(val, s1, t1); val = fmaf(val, s2, t2); }
            if (flags & F_GELU) {
                float u = val;
                float t = tanhf(0.7978845608028654f * (u + 0.044715f * u * u * u));
                val = 0.5f * u * (1.f + t);
            }
            size_t off = (size_t)mi * Npos + (size_t)(p0 + tn + jj);
            if (flags & F_RESID) val += Rn[off];
            Cn[off] = val;
        }
    }
}

// ---------------------------------------------------------------------------
// Flash attention with MFMA (bf16 inputs cast on staging, fp32 accum).
// q: (N,d,L) pre-scaled by 1/8.  k,v: (N,d,Lk).  o: (N,d,L).
// grid: (L/64, N*Nh). block 256 = 4 waves; each wave owns 16 queries.
// Per 64-key chunk, per wave:
//   S^T[key, q] via mfma(K_frag, Q_frag): A=K (16 keys x 32 e), B=Q (32 e x 16 q)
//   lane holds S for q = wave*16 + (lane&15), keys kt*16 + (lane>>4)*4 + r
//   online softmax: 16 regs + shfl_xor(16), shfl_xor(32)
//   P -> bf16 -> per-wave LDS [q][key] -> B-frags for PV
//   O^T[e, q] += mfma(V_frag, P_frag): A=V (16 e x 32 m), B=P (32 m x 16 q)
// All LDS rows padded to 72 bf16 (144 B): ds_read_b128 lands 8 lanes/16B-bank
// (optimal); all staging writes are 2-way or better (free per m136).
// ---------------------------------------------------------------------------
__global__ __launch_bounds__(256) void attn_mfma_kernel(
    const float* __restrict__ q, const float* __restrict__ k,
    const float* __restrict__ v, float* __restrict__ o,
    int N, int d, int L, int Lk, int Nh)
{
    const int l0 = blockIdx.x * 64;
    const int nh = blockIdx.y;
    const int n = nh / Nh, h = nh % Nh;
    const float* qg = q + ((size_t)n * d + (size_t)h * 64) * L;
    const float* kg = k + ((size_t)n * d + (size_t)h * 64) * Lk;
    const float* vg = v + ((size_t)n * d + (size_t)h * 64) * Lk;
    float*       og = o + ((size_t)n * d + (size_t)h * 64) * L;

    __shared__ unsigned short Qs[64][72];   // [q][e]
    __shared__ unsigned short Ks[64][72];   // [key][e]
    __shared__ unsigned short Vs[64][72];   // [e][m]
    __shared__ unsigned short Ps[4][16][72];// per-wave [q][key]

    const int tid = threadIdx.x;

    // ---- stage Q transposed: Qs[q][e] ----
    #pragma unroll
    for (int j = 0; j < 8; ++j) {
        int qq = (tid & 15) + 16 * (j & 3);
        int ep = (tid >> 4) + 16 * (j >> 2);
        float a0 = qg[(size_t)(2 * ep)     * L + l0 + qq];
        float a1 = qg[(size_t)(2 * ep + 1) * L + l0 + qq];
        *(unsigned int*)&Qs[qq][2 * ep] = pack2bf(a0, a1);
    }
    __syncthreads();

    const int wave = tid >> 6;
    const int lane = tid & 63;
    const int qcol = lane & 15;     // query within wave / MFMA col
    const int hi   = lane >> 4;     // k-split group

    bf16x8 qf0 = *(const bf16x8*)&Qs[wave * 16 + qcol][hi * 8];
    bf16x8 qf1 = *(const bf16x8*)&Qs[wave * 16 + qcol][hi * 8 + 32];

    f32x4 o_acc[4] = {};
    float mrow = -INFINITY, lrow = 0.f;

    for (int mc = 0; mc < Lk; mc += 64) {
        __syncthreads();
        // ---- stage K transposed: Ks[key][e] ----
        #pragma unroll
        for (int j = 0; j < 8; ++j) {
            int mm = (tid & 15) + 16 * (j & 3);
            int ep = (tid >> 4) + 16 * (j >> 2);
            float a0 = kg[(size_t)(2 * ep)     * Lk + mc + mm];
            float a1 = kg[(size_t)(2 * ep + 1) * Lk + mc + mm];
            *(unsigned int*)&Ks[mm][2 * ep] = pack2bf(a0, a1);
        }
        // ---- stage V: Vs[e][m] ----
        #pragma unroll
        for (int j = 0; j < 4; ++j) {
            int ee = (tid >> 4) + 16 * j;
            int m4 = (tid & 15) * 4;
            float4 vv = *(const float4*)&vg[(size_t)ee * Lk + mc + m4];
            unsigned int p0 = pack2bf(vv.x, vv.y);
            unsigned int p1 = pack2bf(vv.z, vv.w);
            *(uint2*)&Vs[ee][m4] = make_uint2(p0, p1);
        }
        __syncthreads();

        // ---- QK^T: S^T[key, q] ----
        f32x4 sacc[4];
        #pragma unroll
        for (int kt = 0; kt < 4; ++kt) {
            f32x4 a = {};
            bf16x8 k0 = *(const bf16x8*)&Ks[kt * 16 + qcol][hi * 8];
            bf16x8 k1 = *(const bf16x8*)&Ks[kt * 16 + qcol][hi * 8 + 32];
            a = __builtin_amdgcn_mfma_f32_16x16x32_bf16(k0, qf0, a, 0, 0, 0);
            a = __builtin_amdgcn_mfma_f32_16x16x32_bf16(k1, qf1, a, 0, 0, 0);
            sacc[kt] = a;
        }

        // ---- online softmax ----
        float cm = -INFINITY;
        #pragma unroll
        for (int kt = 0; kt < 4; ++kt)
            #pragma unroll
            for (int r2 = 0; r2 < 4; ++r2) cm = fmaxf(cm, sacc[kt][r2]);
        cm = fmaxf(cm, __shfl_xor(cm, 16));
        cm = fmaxf(cm, __shfl_xor(cm, 32));
        float nm = fmaxf(mrow, cm);
        float alpha = __expf(mrow - nm);
        float csum = 0.f;
        unsigned int pw[4][2];
        #pragma unroll
        for (int kt = 0; kt < 4; ++kt) {
            float p0 = __expf(sacc[kt][0] - nm);
            float p1 = __expf(sacc[kt][1] - nm);
            float p2 = __expf(sacc[kt][2] - nm);
            float p3 = __expf(sacc[kt][3] - nm);
            csum += (p0 + p1) + (p2 + p3);
            pw[kt][0] = pack2bf(p0, p1);
            pw[kt][1] = pack2bf(p2, p3);
        }
        csum += __shfl_xor(csum, 16);
        csum += __shfl_xor(csum, 32);
        lrow = lrow * alpha + csum;
        mrow = nm;

        // ---- P to per-wave LDS: Ps[wave][q][key] ----
        #pragma unroll
        for (int kt = 0; kt < 4; ++kt)
            *(uint2*)&Ps[wave][qcol][kt * 16 + hi * 4] =
                make_uint2(pw[kt][0], pw[kt][1]);

        // ---- rescale O ----
        #pragma unroll
        for (int et = 0; et < 4; ++et)
            #pragma unroll
            for (int r2 = 0; r2 < 4; ++r2) o_acc[et][r2] *= alpha;

        // ---- PV: O^T[e, q] += V * P ----
        bf16x8 pf0 = *(const bf16x8*)&Ps[wave][qcol][hi * 8];
        bf16x8 pf1 = *(const bf16x8*)&Ps[wave][qcol][hi * 8 + 32];
        #pragma unroll
        for (int et = 0; et < 4; ++et) {
            bf16x8 v0 = *(const bf16x8*)&Vs[et * 16 + qcol][hi * 8];
            bf16x8 v1 = *(const bf16x8*)&Vs[et * 16 + qcol][hi * 8 + 32];
            o_acc[et] = __builtin_amdgcn_mfma_f32_16x16x32_bf16(v0, pf0, o_acc[et], 0, 0, 0);
            o_acc[et] = __builtin_amdgcn_mfma_f32_16x16x32_bf16(v1, pf1, o_acc[et], 0, 0, 0);
        }
    }

    float invl = 1.f / lrow;
    #pragma unroll
    for (int et = 0; et < 4; ++et)
        #pragma unroll
        for (int r2 = 0; r2 < 4; ++r2) {
            int e = et * 16 + hi * 4 + r2;
            og[(size_t)e * L + l0 + wave * 16 + qcol] = o_acc[et][r2] * invl;
        }
}

// ---------------------------------------------------------------------------
extern "C" void kernel_launch(void* const* d_in, const int* in_sizes, int n_in,
                              void* d_out, int out_size, void* d_ws, size_t ws_size,
                              hipStream_t stream)
{
    const float* x   = (const float*)d_in[0];
    const float* n1g = (const float*)d_in[1];
    const float* n1b = (const float*)d_in[2];
    const float* n1m = (const float*)d_in[3];
    const float* n1v = (const float*)d_in[4];
    const float* n2g = (const float*)d_in[5];
    const float* n2b = (const float*)d_in[6];
    const float* n2m = (const float*)d_in[7];
    const float* n2v = (const float*)d_in[8];
    const float* Wq  = (const float*)d_in[9];
    const float* Wk  = (const float*)d_in[10];
    const float* Wv  = (const float*)d_in[11];
    const float* Wo  = (const float*)d_in[12];
    const float* Wp  = (const float*)d_in[13];
    const float* bq  = (const float*)d_in[14];
    const float* bk  = (const float*)d_in[15];
    const float* bv  = (const float*)d_in[16];
    const float* bo  = (const float*)d_in[17];
    const float* agg = (const float*)d_in[18];
    const float* agb = (const float*)d_in[19];
    const float* agm = (const float*)d_in[20];
    const float* agv = (const float*)d_in[21];
    const float* ang = (const float*)d_in[22];
    const float* anb = (const float*)d_in[23];
    const float* anm = (const float*)d_in[24];
    const float* anv = (const float*)d_in[25];
    const float* W1  = (const float*)d_in[26];
    const float* b1  = (const float*)d_in[27];
    const float* W2  = (const float*)d_in[28];
    const float* b2  = (const float*)d_in[29];

    float* out = (float*)d_out;
    float* ws  = (float*)d_ws;

    const int N = 8, Cc = 512, L = 3072, P = 4, dd = 128, FF = 2048, Nh = 2;
    const int ratios[4] = {2, 4, 8, 16};

    // workspace layout (floats)
    float* qb  = ws;                                  // N*dd*L
    float* ob  = qb  + (size_t)N * dd * L;            // N*dd*L
    float* xa0 = ob  + (size_t)N * dd * L;            // N*dd*L/2
    float* xab = xa0 + (size_t)N * dd * (L / 2);
    float* kb  = xab + (size_t)N * dd * (L / 2);
    float* vb  = kb  + (size_t)N * dd * (L / 2);
    float* m1 = ws;   // FFN intermediate reuses q/o region

    const float* nul = nullptr;

    for (int i = 0; i < P; ++i) {
        const int r = ratios[i], Lk = L / r;
        const int c0 = i * dd;

        int tot = N * dd * Lk;
        pool_bn_kernel<<<dim3((tot + 255) / 256), dim3(256), 0, stream>>>(
            x, n1g, n1b, n1m, n1v, xa0, N, Cc, L, dd, c0, r, Lk);

        // xa = doubleBN(Wp @ xa0)
        gemm_ep_kernel<<<dim3(Lk / 64, dd / 64, N), dim3(256), 0, stream>>>(
            Wp + (size_t)i * dd * dd, xa0, xab, dd, dd, Lk,
            (long long)dd * Lk, (long long)dd * Lk,
            nul, 1.f, nul, nul, nul, nul, 0,
            agg + c0, agb + c0, agm + c0, agv + c0,
            ang + c0, anb + c0, anm + c0, anv + c0,
            nul, 0, F_DBN);

        // q = (Wq @ bn1(x_slice) + bq) * 0.125
        gemm_ep_kernel<<<dim3(L / 64, dd / 64, N), dim3(256), 0, stream>>>(
            Wq + (size_t)i * dd * dd, x + (size_t)c0 * L, qb, dd, dd, L,
            (long long)Cc * L, (long long)dd * L,
            bq + c0, 0.125f, n1g, n1b, n1m, n1v, c0,
            nul, nul, nul, nul, nul, nul, nul, nul,
            nul, 0, F_BIAS | F_BNB);

        // k = Wk @ xa + bk ; v = Wv @ xa + bv
        gemm_ep_kernel<<<dim3(Lk / 64, dd / 64, N), dim3(256), 0, stream>>>(
            Wk + (size_t)i * dd * dd, xab, kb, dd, dd, Lk,
            (long long)dd * Lk, (long long)dd * Lk,
            bk + c0, 1.f, nul, nul, nul, nul, 0,
            nul, nul, nul, nul, nul, nul, nul, nul,
            nul, 0, F_BIAS);
        gemm_ep_kernel<<<dim3(Lk / 64, dd / 64, N), dim3(256), 0, stream>>>(
            Wv + (size_t)i * dd * dd, xab, vb, dd, dd, Lk,
            (long long)dd * Lk, (long long)dd * Lk,
            bv + c0, 1.f, nul, nul, nul, nul, 0,
            nul, nul, nul, nul, nul, nul, nul, nul,
            nul, 0, F_BIAS);

        attn_mfma_kernel<<<dim3(L / 64, N * Nh), dim3(256), 0, stream>>>(
            qb, kb, vb, ob, N, dd, L, Lk, Nh);

        // out_slice = x_slice + Wo @ o + bo
        gemm_ep_kernel<<<dim3(L / 64, dd / 64, N), dim3(256), 0, stream>>>(
            Wo + (size_t)i * dd * dd, ob, out + (size_t)c0 * L, dd, dd, L,
            (long long)dd * L, (long long)Cc * L,
            bo + c0, 1.f, nul, nul, nul, nul, 0,
            nul, nul, nul, nul, nul, nul, nul, nul,
            x + (size_t)c0 * L, (long long)Cc * L, F_BIAS | F_RESID);
    }

    // FFN per batch (m1 reuses q/o scratch)
    for (int n = 0; n < N; ++n) {
        float* xn = out + (size_t)n * Cc * L;
        gemm_ep_kernel<<<dim3(L / 64, FF / 64, 1), dim3(256), 0, stream>>>(
            W1, xn, m1, FF, Cc, L, 0, 0,
            b1, 1.f, n2g, n2b, n2m, n2v, 0,
            nul, nul, nul, nul, nul, nul, nul, nul,
            nul, 0, F_BIAS | F_BNB | F_GELU);
        gemm_ep_kernel<<<dim3(L / 64, Cc / 64, 1), dim3(256), 0, stream>>>(
            W2, m1, xn, Cc, FF, L, 0, 0,
            b2, 1.f, nul, nul, nul, nul, 0,
            nul, nul, nul, nul, nul, nul, nul, nul,
            xn, 0, F_BIAS | F_RESID);
    }
}

// Round 3
// 1263.752 us; speedup vs baseline: 4.9289x; 2.4531x over previous
//
#include <hip/hip_runtime.h>
#include <math.h>

#define EPS 1e-5f

#define F_BIAS  1
#define F_BNB   2
#define F_DBN   4
#define F_GELU  8
#define F_RESID 16

typedef __attribute__((ext_vector_type(8))) __bf16 bf16x8;
typedef __attribute__((ext_vector_type(4))) float f32x4;

__device__ __forceinline__ unsigned int pack2bf(float a, float b) {
    unsigned short ua = __builtin_bit_cast(unsigned short, (__bf16)a);
    unsigned short ub = __builtin_bit_cast(unsigned short, (__bf16)b);
    return (unsigned int)ua | ((unsigned int)ub << 16);
}

// ---------------------------------------------------------------------------
// Pooling with fused BN1: out[n,c,lk] = mean_j(bn(x)) + max_j(bn(x)) over r
// ---------------------------------------------------------------------------
__global__ __launch_bounds__(256) void pool_bn_kernel(
    const float* __restrict__ x,
    const float* __restrict__ g, const float* __restrict__ b,
    const float* __restrict__ bm, const float* __restrict__ bvv,
    float* __restrict__ out,
    int N, int C, int L, int d, int c0, int r, int Lk)
{
    int idx = blockIdx.x * blockDim.x + threadIdx.x;
    int total = N * d * Lk;
    if (idx >= total) return;
    int lk = idx % Lk;
    int c  = (idx / Lk) % d;
    int n  = idx / (Lk * d);
    int cg = c0 + c;
    float inv = g[cg] * rsqrtf(bvv[cg] + EPS);
    float add = b[cg] - bm[cg] * inv;
    const float* xp = x + ((size_t)n * C + cg) * L + (size_t)lk * r;
    float s = 0.f, mx = -INFINITY;
    for (int j = 0; j < r; ++j) {
        float t = fmaf(xp[j], inv, add);
        s += t;
        mx = fmaxf(mx, t);
    }
    out[idx] = s * (1.0f / (float)r) + mx;
}

// ---------------------------------------------------------------------------
// bf16 MFMA GEMM: C[m,p] = sum_k A[m,k]*B[k,p] (+ fused epilogues).
// A: (M,K) fp32 row-major (weights). B: (K,Npos) fp32 per batch (strideB).
// Tile 128x128, BK=32, 256 threads = 4 waves (2x2), wave = 64x64 out.
// Inputs cast to bf16 on LDS staging; fp32 MFMA accumulation.
// LDS rows padded to 40 bf16 (80 B): 16B-aligned b128 frag reads at the
// 8-lanes-per-4-bank-group optimum; staging writes 2-way (free).
// B staged TRANSPOSED (Bs[p][k]) via 2-row pack2bf, attention-style mapping
// (16-lane p-groups x 4 k-pairs per instr -> 2-way write conflicts only).
// M, K must be multiples of 128/32 (true here); Npos guarded.
// ---------------------------------------------------------------------------
__global__ __launch_bounds__(256) void gemm_mfma_kernel(
    const float* __restrict__ A, const float* __restrict__ B, float* __restrict__ C,
    int M, int K, int Npos, long long strideB, long long strideC,
    const float* __restrict__ bias, float oscale,
    const float* __restrict__ bng, const float* __restrict__ bnb,
    const float* __restrict__ bnm, const float* __restrict__ bnv, int koff,
    const float* __restrict__ agg, const float* __restrict__ agb,
    const float* __restrict__ agm, const float* __restrict__ agv,
    const float* __restrict__ ang, const float* __restrict__ anb,
    const float* __restrict__ anm, const float* __restrict__ anv,
    const float* __restrict__ resid, long long strideR, int flags)
{
    __shared__ __align__(16) unsigned short As[128][40];   // [m][k]
    __shared__ __align__(16) unsigned short Bs[128][40];   // [p][k]

    const int tid = threadIdx.x;
    const int m0 = blockIdx.y * 128;
    const int p0 = blockIdx.x * 128;
    const int nz = blockIdx.z;
    const float* Bn = B + (size_t)nz * strideB;

    const int wave = tid >> 6;
    const int lane = tid & 63;
    const int qcol = lane & 15;
    const int hi   = lane >> 4;
    const int wr   = wave >> 1;
    const int wc   = wave & 1;

    // B staging role (fixed per thread): k-pair kp, 8 p-groups over jj
    const int kp = tid >> 4;          // 0..15 -> k = 2kp, 2kp+1

    f32x4 acc[4][4] = {};

    for (int k0 = 0; k0 < K; k0 += 32) {
        // ---- stage A: 128 m x 32 k, natural [m][k] ----
        #pragma unroll
        for (int i = 0; i < 4; ++i) {
            int mm = (tid >> 3) + 32 * i;
            int kk = (tid & 7) * 4;
            float4 av = *(const float4*)&A[(size_t)(m0 + mm) * K + k0 + kk];
            *(uint2*)&As[mm][kk] =
                make_uint2(pack2bf(av.x, av.y), pack2bf(av.z, av.w));
        }
        // ---- stage B transposed: Bs[p][k] ----
        {
            int kg0 = k0 + 2 * kp, kg1 = kg0 + 1;
            float i0 = 1.f, a0 = 0.f, i1 = 1.f, a1 = 0.f;
            if (flags & F_BNB) {
                int g0 = koff + kg0, g1 = koff + kg1;
                i0 = bng[g0] * rsqrtf(bnv[g0] + EPS);
                a0 = bnb[g0] - bnm[g0] * i0;
                i1 = bng[g1] * rsqrtf(bnv[g1] + EPS);
                a1 = bnb[g1] - bnm[g1] * i1;
            }
            const float* Br0 = Bn + (size_t)kg0 * Npos + p0;
            const float* Br1 = Bn + (size_t)kg1 * Npos + p0;
            #pragma unroll
            for (int jj = 0; jj < 8; ++jj) {
                int pp = (tid & 15) + 16 * jj;
                float b0 = 0.f, b1 = 0.f;
                if (p0 + pp < Npos) {
                    b0 = fmaf(Br0[pp], i0, a0);
                    b1 = fmaf(Br1[pp], i1, a1);
                }
                *(unsigned int*)&Bs[pp][2 * kp] = pack2bf(b0, b1);
            }
        }
        __syncthreads();

        // ---- fragments + MFMA ----
        bf16x8 af[4], bf[4];
        #pragma unroll
        for (int mi = 0; mi < 4; ++mi)
            af[mi] = *(const bf16x8*)&As[wr * 64 + mi * 16 + qcol][hi * 8];
        #pragma unroll
        for (int ni = 0; ni < 4; ++ni)
            bf[ni] = *(const bf16x8*)&Bs[wc * 64 + ni * 16 + qcol][hi * 8];
        #pragma unroll
        for (int mi = 0; mi < 4; ++mi)
            #pragma unroll
            for (int ni = 0; ni < 4; ++ni)
                acc[mi][ni] = __builtin_amdgcn_mfma_f32_16x16x32_bf16(
                    af[mi], bf[ni], acc[mi][ni], 0, 0, 0);
        __syncthreads();
    }

    // ---- epilogue ----
    float* Cn = C + (size_t)nz * strideC;
    const float* Rn = resid + (size_t)nz * strideR;
    const int colb = p0 + wc * 64;
    #pragma unroll
    for (int mi = 0; mi < 4; ++mi) {
        #pragma unroll
        for (int r2 = 0; r2 < 4; ++r2) {
            int gm = m0 + wr * 64 + mi * 16 + hi * 4 + r2;
            float bval = (flags & F_BIAS) ? bias[gm] : 0.f;
            float s1 = 1.f, t1 = 0.f, s2 = 1.f, t2 = 0.f;
            if (flags & F_DBN) {
                float j1 = agg[gm] * rsqrtf(agv[gm] + EPS);
                s1 = j1; t1 = agb[gm] - agm[gm] * j1;
                float j2 = ang[gm] * rsqrtf(anv[gm] + EPS);
                s2 = j2; t2 = anb[gm] - anm[gm] * j2;
            }
            #pragma unroll
            for (int ni = 0; ni < 4; ++ni) {
                int cp = colb + ni * 16 + qcol;
                if (cp >= Npos) continue;
                float val = (acc[mi][ni][r2] + bval) * oscale;
                if (flags & F_DBN) { val = fmaf(val, s1, t1); val = fmaf(val, s2, t2); }
                if (flags & F_GELU) {
                    float u = val;
                    float z = 0.7978845608028654f * (u + 0.044715f * u * u * u);
                    float e = __expf(2.f * z);
                    val = 0.5f * u * (1.f + (1.f - 2.f / (e + 1.f)));
                }
                size_t off = (size_t)gm * Npos + cp;
                if (flags & F_RESID) val += Rn[off];
                Cn[off] = val;
            }
        }
    }
}

// ---------------------------------------------------------------------------
// Flash attention with MFMA (bf16 inputs cast on staging, fp32 accum).
// ---------------------------------------------------------------------------
__global__ __launch_bounds__(256) void attn_mfma_kernel(
    const float* __restrict__ q, const float* __restrict__ k,
    const float* __restrict__ v, float* __restrict__ o,
    int N, int d, int L, int Lk, int Nh)
{
    const int l0 = blockIdx.x * 64;
    const int nh = blockIdx.y;
    const int n = nh / Nh, h = nh % Nh;
    const float* qg = q + ((size_t)n * d + (size_t)h * 64) * L;
    const float* kg = k + ((size_t)n * d + (size_t)h * 64) * Lk;
    const float* vg = v + ((size_t)n * d + (size_t)h * 64) * Lk;
    float*       og = o + ((size_t)n * d + (size_t)h * 64) * L;

    __shared__ __align__(16) unsigned short Qs[64][72];   // [q][e]
    __shared__ __align__(16) unsigned short Ks[64][72];   // [key][e]
    __shared__ __align__(16) unsigned short Vs[64][72];   // [e][m]
    __shared__ __align__(16) unsigned short Ps[4][16][72];// per-wave [q][key]

    const int tid = threadIdx.x;

    #pragma unroll
    for (int j = 0; j < 8; ++j) {
        int qq = (tid & 15) + 16 * (j & 3);
        int ep = (tid >> 4) + 16 * (j >> 2);
        float a0 = qg[(size_t)(2 * ep)     * L + l0 + qq];
        float a1 = qg[(size_t)(2 * ep + 1) * L + l0 + qq];
        *(unsigned int*)&Qs[qq][2 * ep] = pack2bf(a0, a1);
    }
    __syncthreads();

    const int wave = tid >> 6;
    const int lane = tid & 63;
    const int qcol = lane & 15;
    const int hi   = lane >> 4;

    bf16x8 qf0 = *(const bf16x8*)&Qs[wave * 16 + qcol][hi * 8];
    bf16x8 qf1 = *(const bf16x8*)&Qs[wave * 16 + qcol][hi * 8 + 32];

    f32x4 o_acc[4] = {};
    float mrow = -INFINITY, lrow = 0.f;

    for (int mc = 0; mc < Lk; mc += 64) {
        __syncthreads();
        #pragma unroll
        for (int j = 0; j < 8; ++j) {
            int mm = (tid & 15) + 16 * (j & 3);
            int ep = (tid >> 4) + 16 * (j >> 2);
            float a0 = kg[(size_t)(2 * ep)     * Lk + mc + mm];
            float a1 = kg[(size_t)(2 * ep + 1) * Lk + mc + mm];
            *(unsigned int*)&Ks[mm][2 * ep] = pack2bf(a0, a1);
        }
        #pragma unroll
        for (int j = 0; j < 4; ++j) {
            int ee = (tid >> 4) + 16 * j;
            int m4 = (tid & 15) * 4;
            float4 vv = *(const float4*)&vg[(size_t)ee * Lk + mc + m4];
            *(uint2*)&Vs[ee][m4] =
                make_uint2(pack2bf(vv.x, vv.y), pack2bf(vv.z, vv.w));
        }
        __syncthreads();

        f32x4 sacc[4];
        #pragma unroll
        for (int kt = 0; kt < 4; ++kt) {
            f32x4 a = {};
            bf16x8 k0 = *(const bf16x8*)&Ks[kt * 16 + qcol][hi * 8];
            bf16x8 k1 = *(const bf16x8*)&Ks[kt * 16 + qcol][hi * 8 + 32];
            a = __builtin_amdgcn_mfma_f32_16x16x32_bf16(k0, qf0, a, 0, 0, 0);
            a = __builtin_amdgcn_mfma_f32_16x16x32_bf16(k1, qf1, a, 0, 0, 0);
            sacc[kt] = a;
        }

        float cm = -INFINITY;
        #pragma unroll
        for (int kt = 0; kt < 4; ++kt)
            #pragma unroll
            for (int r2 = 0; r2 < 4; ++r2) cm = fmaxf(cm, sacc[kt][r2]);
        cm = fmaxf(cm, __shfl_xor(cm, 16));
        cm = fmaxf(cm, __shfl_xor(cm, 32));
        float nm = fmaxf(mrow, cm);
        float alpha = __expf(mrow - nm);
        float csum = 0.f;
        unsigned int pw[4][2];
        #pragma unroll
        for (int kt = 0; kt < 4; ++kt) {
            float p0 = __expf(sacc[kt][0] - nm);
            float p1 = __expf(sacc[kt][1] - nm);
            float p2 = __expf(sacc[kt][2] - nm);
            float p3 = __expf(sacc[kt][3] - nm);
            csum += (p0 + p1) + (p2 + p3);
            pw[kt][0] = pack2bf(p0, p1);
            pw[kt][1] = pack2bf(p2, p3);
        }
        csum += __shfl_xor(csum, 16);
        csum += __shfl_xor(csum, 32);
        lrow = lrow * alpha + csum;
        mrow = nm;

        #pragma unroll
        for (int kt = 0; kt < 4; ++kt)
            *(uint2*)&Ps[wave][qcol][kt * 16 + hi * 4] =
                make_uint2(pw[kt][0], pw[kt][1]);

        #pragma unroll
        for (int et = 0; et < 4; ++et)
            #pragma unroll
            for (int r2 = 0; r2 < 4; ++r2) o_acc[et][r2] *= alpha;

        bf16x8 pf0 = *(const bf16x8*)&Ps[wave][qcol][hi * 8];
        bf16x8 pf1 = *(const bf16x8*)&Ps[wave][qcol][hi * 8 + 32];
        #pragma unroll
        for (int et = 0; et < 4; ++et) {
            bf16x8 v0 = *(const bf16x8*)&Vs[et * 16 + qcol][hi * 8];
            bf16x8 v1 = *(const bf16x8*)&Vs[et * 16 + qcol][hi * 8 + 32];
            o_acc[et] = __builtin_amdgcn_mfma_f32_16x16x32_bf16(v0, pf0, o_acc[et], 0, 0, 0);
            o_acc[et] = __builtin_amdgcn_mfma_f32_16x16x32_bf16(v1, pf1, o_acc[et], 0, 0, 0);
        }
    }

    float invl = 1.f / lrow;
    #pragma unroll
    for (int et = 0; et < 4; ++et)
        #pragma unroll
        for (int r2 = 0; r2 < 4; ++r2) {
            int e = et * 16 + hi * 4 + r2;
            og[(size_t)e * L + l0 + wave * 16 + qcol] = o_acc[et][r2] * invl;
        }
}

// ---------------------------------------------------------------------------
extern "C" void kernel_launch(void* const* d_in, const int* in_sizes, int n_in,
                              void* d_out, int out_size, void* d_ws, size_t ws_size,
                              hipStream_t stream)
{
    const float* x   = (const float*)d_in[0];
    const float* n1g = (const float*)d_in[1];
    const float* n1b = (const float*)d_in[2];
    const float* n1m = (const float*)d_in[3];
    const float* n1v = (const float*)d_in[4];
    const float* n2g = (const float*)d_in[5];
    const float* n2b = (const float*)d_in[6];
    const float* n2m = (const float*)d_in[7];
    const float* n2v = (const float*)d_in[8];
    const float* Wq  = (const float*)d_in[9];
    const float* Wk  = (const float*)d_in[10];
    const float* Wv  = (const float*)d_in[11];
    const float* Wo  = (const float*)d_in[12];
    const float* Wp  = (const float*)d_in[13];
    const float* bq  = (const float*)d_in[14];
    const float* bk  = (const float*)d_in[15];
    const float* bv  = (const float*)d_in[16];
    const float* bo  = (const float*)d_in[17];
    const float* agg = (const float*)d_in[18];
    const float* agb = (const float*)d_in[19];
    const float* agm = (const float*)d_in[20];
    const float* agv = (const float*)d_in[21];
    const float* ang = (const float*)d_in[22];
    const float* anb = (const float*)d_in[23];
    const float* anm = (const float*)d_in[24];
    const float* anv = (const float*)d_in[25];
    const float* W1  = (const float*)d_in[26];
    const float* b1  = (const float*)d_in[27];
    const float* W2  = (const float*)d_in[28];
    const float* b2  = (const float*)d_in[29];

    float* out = (float*)d_out;
    float* ws  = (float*)d_ws;

    const int N = 8, Cc = 512, L = 3072, P = 4, dd = 128, FF = 2048, Nh = 2;
    const int ratios[4] = {2, 4, 8, 16};

    float* qb  = ws;
    float* ob  = qb  + (size_t)N * dd * L;
    float* xa0 = ob  + (size_t)N * dd * L;
    float* xab = xa0 + (size_t)N * dd * (L / 2);
    float* kb  = xab + (size_t)N * dd * (L / 2);
    float* vb  = kb  + (size_t)N * dd * (L / 2);
    float* m1  = ws;   // FFN intermediate reuses front of ws

    const float* nul = nullptr;
    auto GX = [](int np) { return (np + 127) / 128; };

    for (int i = 0; i < P; ++i) {
        const int r = ratios[i], Lk = L / r;
        const int c0 = i * dd;

        int tot = N * dd * Lk;
        pool_bn_kernel<<<dim3((tot + 255) / 256), dim3(256), 0, stream>>>(
            x, n1g, n1b, n1m, n1v, xa0, N, Cc, L, dd, c0, r, Lk);

        // xa = doubleBN(Wp @ xa0)
        gemm_mfma_kernel<<<dim3(GX(Lk), 1, N), dim3(256), 0, stream>>>(
            Wp + (size_t)i * dd * dd, xa0, xab, dd, dd, Lk,
            (long long)dd * Lk, (long long)dd * Lk,
            nul, 1.f, nul, nul, nul, nul, 0,
            agg + c0, agb + c0, agm + c0, agv + c0,
            ang + c0, anb + c0, anm + c0, anv + c0,
            nul, 0, F_DBN);

        // q = (Wq @ bn1(x_slice) + bq) * 0.125
        gemm_mfma_kernel<<<dim3(GX(L), 1, N), dim3(256), 0, stream>>>(
            Wq + (size_t)i * dd * dd, x + (size_t)c0 * L, qb, dd, dd, L,
            (long long)Cc * L, (long long)dd * L,
            bq + c0, 0.125f, n1g, n1b, n1m, n1v, c0,
            nul, nul, nul, nul, nul, nul, nul, nul,
            nul, 0, F_BIAS | F_BNB);

        // k = Wk @ xa + bk ; v = Wv @ xa + bv
        gemm_mfma_kernel<<<dim3(GX(Lk), 1, N), dim3(256), 0, stream>>>(
            Wk + (size_t)i * dd * dd, xab, kb, dd, dd, Lk,
            (long long)dd * Lk, (long long)dd * Lk,
            bk + c0, 1.f, nul, nul, nul, nul, 0,
            nul, nul, nul, nul, nul, nul, nul, nul,
            nul, 0, F_BIAS);
        gemm_mfma_kernel<<<dim3(GX(Lk), 1, N), dim3(256), 0, stream>>>(
            Wv + (size_t)i * dd * dd, xab, vb, dd, dd, Lk,
            (long long)dd * Lk, (long long)dd * Lk,
            bv + c0, 1.f, nul, nul, nul, nul, 0,
            nul, nul, nul, nul, nul, nul, nul, nul,
            nul, 0, F_BIAS);

        attn_mfma_kernel<<<dim3(L / 64, N * Nh), dim3(256), 0, stream>>>(
            qb, kb, vb, ob, N, dd, L, Lk, Nh);

        // out_slice = x_slice + Wo @ o + bo
        gemm_mfma_kernel<<<dim3(GX(L), 1, N), dim3(256), 0, stream>>>(
            Wo + (size_t)i * dd * dd, ob, out + (size_t)c0 * L, dd, dd, L,
            (long long)dd * L, (long long)Cc * L,
            bo + c0, 1.f, nul, nul, nul, nul, 0,
            nul, nul, nul, nul, nul, nul, nul, nul,
            x + (size_t)c0 * L, (long long)Cc * L, F_BIAS | F_RESID);
    }

    // FFN: batched over N if workspace allows, else per batch
    size_t need = (size_t)N * FF * L * sizeof(float);
    if (ws_size >= need) {
        gemm_mfma_kernel<<<dim3(GX(L), FF / 128, N), dim3(256), 0, stream>>>(
            W1, out, m1, FF, Cc, L, (long long)Cc * L, (long long)FF * L,
            b1, 1.f, n2g, n2b, n2m, n2v, 0,
            nul, nul, nul, nul, nul, nul, nul, nul,
            nul, 0, F_BIAS | F_BNB | F_GELU);
        gemm_mfma_kernel<<<dim3(GX(L), Cc / 128, N), dim3(256), 0, stream>>>(
            W2, m1, out, Cc, FF, L, (long long)FF * L, (long long)Cc * L,
            b2, 1.f, nul, nul, nul, nul, 0,
            nul, nul, nul, nul, nul, nul, nul, nul,
            out, (long long)Cc * L, F_BIAS | F_RESID);
    } else {
        for (int n = 0; n < N; ++n) {
            float* xn = out + (size_t)n * Cc * L;
            gemm_mfma_kernel<<<dim3(GX(L), FF / 128, 1), dim3(256), 0, stream>>>(
                W1, xn, m1, FF, Cc, L, 0, 0,
                b1, 1.f, n2g, n2b, n2m, n2v, 0,
                nul, nul, nul, nul, nul, nul, nul, nul,
                nul, 0, F_BIAS | F_BNB | F_GELU);
            gemm_mfma_kernel<<<dim3(GX(L), Cc / 128, 1), dim3(256), 0, stream>>>(
                W2, m1, xn, Cc, FF, L, 0, 0,
                b2, 1.f, nul, nul, nul, nul, 0,
                nul, nul, nul, nul, nul, nul, nul, nul,
                xn, 0, F_BIAS | F_RESID);
        }
    }
}

// Round 4
// 1047.534 us; speedup vs baseline: 5.9462x; 1.2064x over previous
//
#include <hip/hip_runtime.h>
#include <math.h>

#define EPS 1e-5f

#define F_BIAS  1
#define F_DBN   2
#define F_GELU  4
#define F_RESID 8

typedef __attribute__((ext_vector_type(8))) __bf16 bf16x8;
typedef __attribute__((ext_vector_type(4))) float f32x4;
typedef __attribute__((ext_vector_type(8))) unsigned short u16x8;

__device__ __forceinline__ unsigned int pack2bf(float a, float b) {
    unsigned short ua = __builtin_bit_cast(unsigned short, (__bf16)a);
    unsigned short ub = __builtin_bit_cast(unsigned short, (__bf16)b);
    return (unsigned int)ua | ((unsigned int)ub << 16);
}

// ---------------------------------------------------------------------------
// Convert all weights fp32 -> bf16 into one ws region (7 tensors, fixed sizes)
// ---------------------------------------------------------------------------
__global__ __launch_bounds__(256) void wcvt_kernel(
    const float* __restrict__ Wq, const float* __restrict__ Wk,
    const float* __restrict__ Wv, const float* __restrict__ Wo,
    const float* __restrict__ Wp, const float* __restrict__ W1,
    const float* __restrict__ W2, unsigned short* __restrict__ dst)
{
    const int WSZ = 65536;           // 4*128*128
    const int FSZ = 1048576;         // 2048*512
    int i4 = blockIdx.x * blockDim.x + threadIdx.x;
    long long i = (long long)i4 * 4;
    const long long total = 5LL * WSZ + 2LL * FSZ;
    if (i >= total) return;
    #pragma unroll
    for (int j = 0; j < 4; ++j) {
        long long idx = i + j;
        float v;
        if      (idx < WSZ)            v = Wq[idx];
        else if (idx < 2 * WSZ)        v = Wk[idx - WSZ];
        else if (idx < 3 * WSZ)        v = Wv[idx - 2 * WSZ];
        else if (idx < 4 * WSZ)        v = Wo[idx - 3 * WSZ];
        else if (idx < 5 * WSZ)        v = Wp[idx - 4 * WSZ];
        else if (idx < 5 * WSZ + FSZ)  v = W1[idx - 5 * WSZ];
        else                           v = W2[idx - 5 * WSZ - FSZ];
        dst[idx] = __builtin_bit_cast(unsigned short, (__bf16)v);
    }
}

// ---------------------------------------------------------------------------
// hT = bf16(bn1(x)) transposed: x (N,C,L) f32 -> hT (N,L,C) bf16
// grid (L/64, C/64, N), 256 threads, LDS 64x65 f32 tile transpose
// ---------------------------------------------------------------------------
__global__ __launch_bounds__(256) void bn_transpose_kernel(
    const float* __restrict__ x,
    const float* __restrict__ g, const float* __restrict__ b,
    const float* __restrict__ bm, const float* __restrict__ bvv,
    unsigned short* __restrict__ hT, int C, int L)
{
    __shared__ float ps[64][65];
    const int l0 = blockIdx.x * 64, ct = blockIdx.y, n = blockIdx.z;
    const int tid = threadIdx.x;
    const int c = tid >> 2, q = tid & 3;
    const int cg = ct * 64 + c;
    float inv = g[cg] * rsqrtf(bvv[cg] + EPS);
    float add = b[cg] - bm[cg] * inv;
    const float* xp = x + ((size_t)n * C + cg) * L + l0 + q * 16;
    #pragma unroll
    for (int s = 0; s < 4; ++s) {
        float4 vv = *(const float4*)&xp[s * 4];
        ps[c][q * 16 + s * 4 + 0] = fmaf(vv.x, inv, add);
        ps[c][q * 16 + s * 4 + 1] = fmaf(vv.y, inv, add);
        ps[c][q * 16 + s * 4 + 2] = fmaf(vv.z, inv, add);
        ps[c][q * 16 + s * 4 + 3] = fmaf(vv.w, inv, add);
    }
    __syncthreads();
    // write hT[l][C]: rows l, 64 c's (this tile) at col ct*64
    #pragma unroll
    for (int j = 0; j < 2; ++j) {
        int row = (tid >> 3) + 32 * j;
        int cc0 = (tid & 7) * 8;
        unsigned int w0 = pack2bf(ps[cc0 + 0][row], ps[cc0 + 1][row]);
        unsigned int w1 = pack2bf(ps[cc0 + 2][row], ps[cc0 + 3][row]);
        unsigned int w2 = pack2bf(ps[cc0 + 4][row], ps[cc0 + 5][row]);
        unsigned int w3 = pack2bf(ps[cc0 + 6][row], ps[cc0 + 7][row]);
        uint4 wv = make_uint4(w0, w1, w2, w3);
        *(uint4*)&hT[((size_t)n * L + l0 + row) * C + ct * 64 + cc0] = wv;
    }
}

// ---------------------------------------------------------------------------
// Pool with fused BN1, transposed bf16 out: xa0T[n][lk][c(0..127)]
// grid (Lk/64, 2, N), 256 threads
// ---------------------------------------------------------------------------
__global__ __launch_bounds__(256) void pool_bn_t_kernel(
    const float* __restrict__ x,
    const float* __restrict__ g, const float* __restrict__ b,
    const float* __restrict__ bm, const float* __restrict__ bvv,
    unsigned short* __restrict__ xa0T,
    int C, int L, int c0, int r, int Lk)
{
    __shared__ float ps[64][65];
    const int lk0 = blockIdx.x * 64, ct = blockIdx.y, n = blockIdx.z;
    const int tid = threadIdx.x;
    const int c = tid >> 2, q = tid & 3;
    const int cg = c0 + ct * 64 + c;
    float inv = g[cg] * rsqrtf(bvv[cg] + EPS);
    float add = b[cg] - bm[cg] * inv;
    const float* xp = x + ((size_t)n * C + cg) * L;
    float rinv = 1.0f / (float)r;
    #pragma unroll
    for (int s = 0; s < 16; ++s) {
        int lk = q * 16 + s;
        const float* base = xp + (size_t)(lk0 + lk) * r;
        float sum = 0.f, mx = -INFINITY;
        for (int j = 0; j < r; j += 2) {
            float2 vv = *(const float2*)&base[j];
            float t0 = fmaf(vv.x, inv, add);
            float t1 = fmaf(vv.y, inv, add);
            sum += t0 + t1;
            mx = fmaxf(mx, fmaxf(t0, t1));
        }
        ps[c][lk] = sum * rinv + mx;
    }
    __syncthreads();
    #pragma unroll
    for (int j = 0; j < 2; ++j) {
        int row = (tid >> 3) + 32 * j;
        int cc0 = (tid & 7) * 8;
        unsigned int w0 = pack2bf(ps[cc0 + 0][row], ps[cc0 + 1][row]);
        unsigned int w1 = pack2bf(ps[cc0 + 2][row], ps[cc0 + 3][row]);
        unsigned int w2 = pack2bf(ps[cc0 + 4][row], ps[cc0 + 5][row]);
        unsigned int w3 = pack2bf(ps[cc0 + 6][row], ps[cc0 + 7][row]);
        *(uint4*)&xa0T[((size_t)n * Lk + lk0 + row) * 128 + ct * 64 + cc0] =
            make_uint4(w0, w1, w2, w3);
    }
}

// ---------------------------------------------------------------------------
// bf16 MFMA GEMM, both operands k-contiguous bf16.
// A: [M][K] bf16. BT: [Npos][ldBT] bf16 rows = output column position.
// Tile 128x128, BK=32, 4 waves (2x2). LDS linear [128][32] (64B rows).
// OMODE: 0 = f32 natural out (+resid)
//        1 = bf16 transposed out [p][ldT] at col offset moff
//        2 = bf16 natural out [m][Npos]
//        3 = f32 natural out (+resid) AND bf16T aux with BN (g1 params)
// ---------------------------------------------------------------------------
template<int OMODE>
__global__ __launch_bounds__(256) void gemm_bf(
    const unsigned short* __restrict__ A, const unsigned short* __restrict__ BT,
    int M, int K, int Npos, int ldBT, long long strideBT,
    const float* __restrict__ bias, float oscale, int flags,
    const float* __restrict__ g1, const float* __restrict__ b1p,
    const float* __restrict__ m1p, const float* __restrict__ v1p,
    const float* __restrict__ g2, const float* __restrict__ b2p,
    const float* __restrict__ m2p, const float* __restrict__ v2p,
    float* __restrict__ outN, long long strideN,
    const float* __restrict__ resid, long long strideR,
    unsigned short* __restrict__ outT, int ldT, int moff, long long strideT)
{
    __shared__ __align__(16) unsigned short As[128][32];
    __shared__ __align__(16) unsigned short Bs[128][32];

    const int tid = threadIdx.x;
    const int m0 = blockIdx.y * 128;
    const int p0 = blockIdx.x * 128;
    const int nz = blockIdx.z;
    const unsigned short* Bn = BT + (size_t)nz * strideBT;

    const int wave = tid >> 6;
    const int lane = tid & 63;
    const int qcol = lane & 15;
    const int hi   = lane >> 4;
    const int wr   = wave >> 1;
    const int wc   = wave & 1;

    const int srow = tid >> 2;          // 0..63
    const int sseg = (tid & 3) * 8;     // 0,8,16,24

    f32x4 acc[4][4] = {};

    for (int k0 = 0; k0 < K; k0 += 32) {
        #pragma unroll
        for (int j = 0; j < 2; ++j) {
            int row = srow + 64 * j;
            *(u16x8*)&As[row][sseg] =
                *(const u16x8*)&A[(size_t)(m0 + row) * K + k0 + sseg];
            int prow = p0 + row; if (prow > Npos - 1) prow = Npos - 1;
            *(u16x8*)&Bs[row][sseg] =
                *(const u16x8*)&Bn[(size_t)prow * ldBT + k0 + sseg];
        }
        __syncthreads();
        bf16x8 af[4], bfr[4];
        #pragma unroll
        for (int mi = 0; mi < 4; ++mi)
            af[mi] = *(const bf16x8*)&As[wr * 64 + mi * 16 + qcol][hi * 8];
        #pragma unroll
        for (int ni = 0; ni < 4; ++ni)
            bfr[ni] = *(const bf16x8*)&Bs[wc * 64 + ni * 16 + qcol][hi * 8];
        #pragma unroll
        for (int mi = 0; mi < 4; ++mi)
            #pragma unroll
            for (int ni = 0; ni < 4; ++ni)
                acc[mi][ni] = __builtin_amdgcn_mfma_f32_16x16x32_bf16(
                    af[mi], bfr[ni], acc[mi][ni], 0, 0, 0);
        __syncthreads();
    }

    float* Cn = outN + (size_t)nz * strideN;
    const float* Rn = resid + (size_t)nz * strideR;
    unsigned short* Tn = outT + (size_t)nz * strideT;

    #pragma unroll
    for (int mi = 0; mi < 4; ++mi) {
        const int mb = m0 + wr * 64 + mi * 16 + hi * 4;   // first of 4 rows
        float4 bv4 = make_float4(0.f, 0.f, 0.f, 0.f);
        if (flags & F_BIAS) bv4 = *(const float4*)&bias[mb];
        float s1[4], t1[4];
        if ((flags & F_DBN) || OMODE == 3) {
            float4 gg = *(const float4*)&g1[mb];
            float4 bb = *(const float4*)&b1p[mb];
            float4 mm = *(const float4*)&m1p[mb];
            float4 vv = *(const float4*)&v1p[mb];
            float gga[4] = {gg.x, gg.y, gg.z, gg.w};
            float bba[4] = {bb.x, bb.y, bb.z, bb.w};
            float mma[4] = {mm.x, mm.y, mm.z, mm.w};
            float vva[4] = {vv.x, vv.y, vv.z, vv.w};
            #pragma unroll
            for (int r2 = 0; r2 < 4; ++r2) {
                float iv = gga[r2] * rsqrtf(vva[r2] + EPS);
                s1[r2] = iv; t1[r2] = bba[r2] - mma[r2] * iv;
            }
        }
        float s2[4], t2[4];
        if (flags & F_DBN) {
            float4 gg = *(const float4*)&g2[mb];
            float4 bb = *(const float4*)&b2p[mb];
            float4 mm = *(const float4*)&m2p[mb];
            float4 vv = *(const float4*)&v2p[mb];
            float gga[4] = {gg.x, gg.y, gg.z, gg.w};
            float bba[4] = {bb.x, bb.y, bb.z, bb.w};
            float mma[4] = {mm.x, mm.y, mm.z, mm.w};
            float vva[4] = {vv.x, vv.y, vv.z, vv.w};
            #pragma unroll
            for (int r2 = 0; r2 < 4; ++r2) {
                float iv = gga[r2] * rsqrtf(vva[r2] + EPS);
                s2[r2] = iv; t2[r2] = bba[r2] - mma[r2] * iv;
            }
        }
        const float ba[4] = {bv4.x, bv4.y, bv4.z, bv4.w};
        #pragma unroll
        for (int ni = 0; ni < 4; ++ni) {
            const int cp = p0 + wc * 64 + ni * 16 + qcol;
            if (cp >= Npos) continue;
            float vals[4];
            #pragma unroll
            for (int r2 = 0; r2 < 4; ++r2) {
                float val = (acc[mi][ni][r2] + ba[r2]) * oscale;
                if (flags & F_DBN) {
                    val = fmaf(val, s1[r2], t1[r2]);
                    val = fmaf(val, s2[r2], t2[r2]);
                }
                if (flags & F_GELU) {
                    float u = val;
                    float z = 0.7978845608028654f * (u + 0.044715f * u * u * u);
                    float e = __expf(2.f * z);
                    val = 0.5f * u * (1.f + (1.f - 2.f / (e + 1.f)));
                }
                vals[r2] = val;
            }
            if (OMODE == 0 || OMODE == 3) {
                #pragma unroll
                for (int r2 = 0; r2 < 4; ++r2) {
                    size_t off = (size_t)(mb + r2) * Npos + cp;
                    float v = vals[r2];
                    if (flags & F_RESID) v += Rn[off];
                    Cn[off] = v;
                    vals[r2] = v;
                }
            }
            if (OMODE == 1) {
                *(uint2*)&Tn[(size_t)cp * ldT + moff + mb] =
                    make_uint2(pack2bf(vals[0], vals[1]), pack2bf(vals[2], vals[3]));
            }
            if (OMODE == 2) {
                #pragma unroll
                for (int r2 = 0; r2 < 4; ++r2)
                    Tn[(size_t)(mb + r2) * Npos + cp] =
                        __builtin_bit_cast(unsigned short, (__bf16)vals[r2]);
            }
            if (OMODE == 3) {
                float a0 = fmaf(vals[0], s1[0], t1[0]);
                float a1 = fmaf(vals[1], s1[1], t1[1]);
                float a2 = fmaf(vals[2], s1[2], t1[2]);
                float a3 = fmaf(vals[3], s1[3], t1[3]);
                *(uint2*)&Tn[(size_t)cp * ldT + moff + mb] =
                    make_uint2(pack2bf(a0, a1), pack2bf(a2, a3));
            }
        }
    }
}

// ---------------------------------------------------------------------------
// Flash attention, all-bf16 operands loaded fragment-direct from global.
// qT,kT: [n][pos][128] bf16 (head cols h*64..). vN: [n][128][Lk] bf16.
// obT out: [n][pos][128] bf16. No barriers; per-wave P bounce in LDS.
// grid (L/64, N*2), 256 threads = 4 independent waves (16 queries each).
// ---------------------------------------------------------------------------
__global__ __launch_bounds__(256) void attn_bf_kernel(
    const unsigned short* __restrict__ qT, const unsigned short* __restrict__ kT,
    const unsigned short* __restrict__ vN, unsigned short* __restrict__ obT,
    int L, int Lk)
{
    const int l0 = blockIdx.x * 64;
    const int nh = blockIdx.y;
    const int n = nh >> 1, h = nh & 1;
    const unsigned short* qn = qT + (size_t)n * L * 128 + h * 64;
    const unsigned short* kn = kT + (size_t)n * Lk * 128 + h * 64;
    const unsigned short* vn = vN + ((size_t)n * 128 + h * 64) * Lk;
    unsigned short*       on = obT + (size_t)n * L * 128 + h * 64;

    __shared__ __align__(16) unsigned short Ps[4][16][72];

    const int tid = threadIdx.x;
    const int wave = tid >> 6;
    const int lane = tid & 63;
    const int qcol = lane & 15;
    const int hi   = lane >> 4;
    const int ql   = wave * 16 + qcol;

    bf16x8 qf0 = *(const bf16x8*)&qn[(size_t)(l0 + ql) * 128 + hi * 8];
    bf16x8 qf1 = *(const bf16x8*)&qn[(size_t)(l0 + ql) * 128 + 32 + hi * 8];

    f32x4 o_acc[4] = {};
    float mrow = -INFINITY, lrow = 0.f;

    for (int mc = 0; mc < Lk; mc += 64) {
        // ---- S^T[key, q] ----
        f32x4 sacc[4];
        #pragma unroll
        for (int kt = 0; kt < 4; ++kt) {
            const size_t kr = (size_t)(mc + kt * 16 + qcol) * 128;
            bf16x8 k0 = *(const bf16x8*)&kn[kr + hi * 8];
            bf16x8 k1 = *(const bf16x8*)&kn[kr + 32 + hi * 8];
            f32x4 a = {};
            a = __builtin_amdgcn_mfma_f32_16x16x32_bf16(k0, qf0, a, 0, 0, 0);
            a = __builtin_amdgcn_mfma_f32_16x16x32_bf16(k1, qf1, a, 0, 0, 0);
            sacc[kt] = a;
        }

        // ---- online softmax ----
        float cm = -INFINITY;
        #pragma unroll
        for (int kt = 0; kt < 4; ++kt)
            #pragma unroll
            for (int r2 = 0; r2 < 4; ++r2) cm = fmaxf(cm, sacc[kt][r2]);
        cm = fmaxf(cm, __shfl_xor(cm, 16));
        cm = fmaxf(cm, __shfl_xor(cm, 32));
        float nm = fmaxf(mrow, cm);
        float alpha = __expf(mrow - nm);
        float csum = 0.f;
        unsigned int pw[4][2];
        #pragma unroll
        for (int kt = 0; kt < 4; ++kt) {
            float p0 = __expf(sacc[kt][0] - nm);
            float p1 = __expf(sacc[kt][1] - nm);
            float p2 = __expf(sacc[kt][2] - nm);
            float p3 = __expf(sacc[kt][3] - nm);
            csum += (p0 + p1) + (p2 + p3);
            pw[kt][0] = pack2bf(p0, p1);
            pw[kt][1] = pack2bf(p2, p3);
        }
        csum += __shfl_xor(csum, 16);
        csum += __shfl_xor(csum, 32);
        lrow = lrow * alpha + csum;
        mrow = nm;

        #pragma unroll
        for (int kt = 0; kt < 4; ++kt)
            *(uint2*)&Ps[wave][qcol][kt * 16 + hi * 4] =
                make_uint2(pw[kt][0], pw[kt][1]);

        #pragma unroll
        for (int et = 0; et < 4; ++et)
            #pragma unroll
            for (int r2 = 0; r2 < 4; ++r2) o_acc[et][r2] *= alpha;

        bf16x8 pf0 = *(const bf16x8*)&Ps[wave][qcol][hi * 8];
        bf16x8 pf1 = *(const bf16x8*)&Ps[wave][qcol][hi * 8 + 32];
        #pragma unroll
        for (int et = 0; et < 4; ++et) {
            const size_t vr = (size_t)(et * 16 + qcol) * Lk + mc;
            bf16x8 v0 = *(const bf16x8*)&vn[vr + hi * 8];
            bf16x8 v1 = *(const bf16x8*)&vn[vr + 32 + hi * 8];
            o_acc[et] = __builtin_amdgcn_mfma_f32_16x16x32_bf16(v0, pf0, o_acc[et], 0, 0, 0);
            o_acc[et] = __builtin_amdgcn_mfma_f32_16x16x32_bf16(v1, pf1, o_acc[et], 0, 0, 0);
        }
    }

    float invl = 1.f / lrow;
    #pragma unroll
    for (int et = 0; et < 4; ++et) {
        float a0 = o_acc[et][0] * invl, a1 = o_acc[et][1] * invl;
        float a2 = o_acc[et][2] * invl, a3 = o_acc[et][3] * invl;
        *(uint2*)&on[(size_t)(l0 + ql) * 128 + et * 16 + hi * 4] =
            make_uint2(pack2bf(a0, a1), pack2bf(a2, a3));
    }
}

// ---------------------------------------------------------------------------
extern "C" void kernel_launch(void* const* d_in, const int* in_sizes, int n_in,
                              void* d_out, int out_size, void* d_ws, size_t ws_size,
                              hipStream_t stream)
{
    const float* x   = (const float*)d_in[0];
    const float* n1g = (const float*)d_in[1];
    const float* n1b = (const float*)d_in[2];
    const float* n1m = (const float*)d_in[3];
    const float* n1v = (const float*)d_in[4];
    const float* n2g = (const float*)d_in[5];
    const float* n2b = (const float*)d_in[6];
    const float* n2m = (const float*)d_in[7];
    const float* n2v = (const float*)d_in[8];
    const float* Wq  = (const float*)d_in[9];
    const float* Wk  = (const float*)d_in[10];
    const float* Wv  = (const float*)d_in[11];
    const float* Wo  = (const float*)d_in[12];
    const float* Wp  = (const float*)d_in[13];
    const float* bq  = (const float*)d_in[14];
    const float* bk  = (const float*)d_in[15];
    const float* bv  = (const float*)d_in[16];
    const float* bo  = (const float*)d_in[17];
    const float* agg = (const float*)d_in[18];
    const float* agb = (const float*)d_in[19];
    const float* agm = (const float*)d_in[20];
    const float* agv = (const float*)d_in[21];
    const float* ang = (const float*)d_in[22];
    const float* anb = (const float*)d_in[23];
    const float* anm = (const float*)d_in[24];
    const float* anv = (const float*)d_in[25];
    const float* W1  = (const float*)d_in[26];
    const float* b1  = (const float*)d_in[27];
    const float* W2  = (const float*)d_in[28];
    const float* b2  = (const float*)d_in[29];

    float* out = (float*)d_out;
    unsigned short* wsb = (unsigned short*)d_ws;

    const int N = 8, Cc = 512, L = 3072, P = 4, dd = 128, FF = 2048;
    const int ratios[4] = {2, 4, 8, 16};
    const int WSZ = 65536, FSZ = 1048576;

    // ws layout (u16 elems)
    unsigned short* wbf   = wsb;                       // 2,424,832
    unsigned short* hT    = wbf   + 5 * WSZ + 2 * FSZ; // 12,582,912
    unsigned short* qT    = hT    + (size_t)N * L * Cc;
    unsigned short* obT   = qT    + (size_t)N * L * dd;
    unsigned short* xa0T  = obT   + (size_t)N * L * dd;
    unsigned short* xabT  = xa0T  + (size_t)N * (L / 2) * dd;
    unsigned short* kTb   = xabT  + (size_t)N * (L / 2) * dd;
    unsigned short* vNb   = kTb   + (size_t)N * (L / 2) * dd;
    unsigned short* h2T   = vNb   + (size_t)N * (L / 2) * dd;
    unsigned short* m1T   = h2T   + (size_t)N * L * Cc;

    const unsigned short* WqB = wbf;
    const unsigned short* WkB = wbf + WSZ;
    const unsigned short* WvB = wbf + 2 * WSZ;
    const unsigned short* WoB = wbf + 3 * WSZ;
    const unsigned short* WpB = wbf + 4 * WSZ;
    const unsigned short* W1B = wbf + 5 * WSZ;
    const unsigned short* W2B = wbf + 5 * WSZ + FSZ;

    const float* nul = nullptr;
    float* nulf = nullptr;
    unsigned short* nulu = nullptr;

    // 1) weights -> bf16
    {
        long long tot4 = (5LL * WSZ + 2LL * FSZ) / 4;
        wcvt_kernel<<<dim3((unsigned)((tot4 + 255) / 256)), dim3(256), 0, stream>>>(
            Wq, Wk, Wv, Wo, Wp, W1, W2, wbf);
    }
    // 2) hT = bf16(bn1(x))^T
    bn_transpose_kernel<<<dim3(L / 64, Cc / 64, N), dim3(256), 0, stream>>>(
        x, n1g, n1b, n1m, n1v, hT, Cc, L);

    for (int i = 0; i < P; ++i) {
        const int r = ratios[i], Lk = L / r;
        const int c0 = i * dd;
        const int gx = (Lk + 127) / 128;

        pool_bn_t_kernel<<<dim3(Lk / 64, 2, N), dim3(256), 0, stream>>>(
            x, n1g, n1b, n1m, n1v, xa0T, Cc, L, c0, r, Lk);

        // xabT = bf16(doubleBN(Wp @ xa0))^T
        gemm_bf<1><<<dim3(gx, 1, N), dim3(256), 0, stream>>>(
            WpB + (size_t)i * dd * dd, xa0T, dd, dd, Lk, dd, (long long)Lk * dd,
            nul, 1.f, F_DBN,
            agg + c0, agb + c0, agm + c0, agv + c0,
            ang + c0, anb + c0, anm + c0, anv + c0,
            nulf, 0, nul, 0, xabT, dd, 0, (long long)Lk * dd);

        // qT = bf16((Wq @ h_slice + bq) * 0.125)^T
        gemm_bf<1><<<dim3(L / 128, 1, N), dim3(256), 0, stream>>>(
            WqB + (size_t)i * dd * dd, hT + c0, dd, dd, L, Cc, (long long)L * Cc,
            bq + c0, 0.125f, F_BIAS,
            nul, nul, nul, nul, nul, nul, nul, nul,
            nulf, 0, nul, 0, qT, dd, 0, (long long)L * dd);

        // kT = bf16(Wk @ xa + bk)^T
        gemm_bf<1><<<dim3(gx, 1, N), dim3(256), 0, stream>>>(
            WkB + (size_t)i * dd * dd, xabT, dd, dd, Lk, dd, (long long)Lk * dd,
            bk + c0, 1.f, F_BIAS,
            nul, nul, nul, nul, nul, nul, nul, nul,
            nulf, 0, nul, 0, kTb, dd, 0, (long long)Lk * dd);

        // vN = bf16(Wv @ xa + bv) natural
        gemm_bf<2><<<dim3(gx, 1, N), dim3(256), 0, stream>>>(
            WvB + (size_t)i * dd * dd, xabT, dd, dd, Lk, dd, (long long)Lk * dd,
            bv + c0, 1.f, F_BIAS,
            nul, nul, nul, nul, nul, nul, nul, nul,
            nulf, 0, nul, 0, vNb, 0, 0, (long long)dd * Lk);

        attn_bf_kernel<<<dim3(L / 64, N * 2), dim3(256), 0, stream>>>(
            qT, kTb, vNb, obT, L, Lk);

        // out_slice = x_slice + Wo @ o + bo  (f32) ; h2T aux = bf16(bn2(out))
        gemm_bf<3><<<dim3(L / 128, 1, N), dim3(256), 0, stream>>>(
            WoB + (size_t)i * dd * dd, obT, dd, dd, L, dd, (long long)L * dd,
            bo + c0, 1.f, F_BIAS | F_RESID,
            n2g + c0, n2b + c0, n2m + c0, n2v + c0,
            nul, nul, nul, nul,
            out + (size_t)c0 * L, (long long)Cc * L,
            x + (size_t)c0 * L, (long long)Cc * L,
            h2T, Cc, c0, (long long)L * Cc);
    }

    // FFN: m1T = bf16(gelu(W1 @ h2 + b1))^T
    gemm_bf<1><<<dim3(L / 128, FF / 128, N), dim3(256), 0, stream>>>(
        W1B, h2T, FF, Cc, L, Cc, (long long)L * Cc,
        b1, 1.f, F_BIAS | F_GELU,
        nul, nul, nul, nul, nul, nul, nul, nul,
        nulf, 0, nul, 0, m1T, FF, 0, (long long)L * FF);

    // out += W2 @ m1 + b2
    gemm_bf<0><<<dim3(L / 128, Cc / 128, N), dim3(256), 0, stream>>>(
        W2B, m1T, Cc, FF, L, FF, (long long)L * FF,
        b2, 1.f, F_BIAS | F_RESID,
        nul, nul, nul, nul, nul, nul, nul, nul,
        out, (long long)Cc * L, out, (long long)Cc * L,
        nulu, 0, 0, 0);
}

// Round 5
// 1047.290 us; speedup vs baseline: 5.9476x; 1.0002x over previous
//
#include <hip/hip_runtime.h>
#include <math.h>

#define EPS 1e-5f

#define F_BIAS  1
#define F_DBN   2
#define F_GELU  4
#define F_RESID 8

typedef __attribute__((ext_vector_type(8))) __bf16 bf16x8;
typedef __attribute__((ext_vector_type(4))) float f32x4;
typedef __attribute__((ext_vector_type(8))) unsigned short u16x8;

__device__ __forceinline__ unsigned int pack2bf(float a, float b) {
    unsigned short ua = __builtin_bit_cast(unsigned short, (__bf16)a);
    unsigned short ub = __builtin_bit_cast(unsigned short, (__bf16)b);
    return (unsigned int)ua | ((unsigned int)ub << 16);
}

// async global->LDS, 16B per lane; dst must be wave-uniform, src per-lane
__device__ __forceinline__ void gload_lds16(const unsigned short* g, unsigned short* l) {
    __builtin_amdgcn_global_load_lds(
        (const __attribute__((address_space(1))) unsigned int*)g,
        (__attribute__((address_space(3))) unsigned int*)l,
        16, 0, 0);
}

// ---------------------------------------------------------------------------
// Convert all weights fp32 -> bf16 into one ws region (7 tensors, fixed sizes)
// ---------------------------------------------------------------------------
__global__ __launch_bounds__(256) void wcvt_kernel(
    const float* __restrict__ Wq, const float* __restrict__ Wk,
    const float* __restrict__ Wv, const float* __restrict__ Wo,
    const float* __restrict__ Wp, const float* __restrict__ W1,
    const float* __restrict__ W2, unsigned short* __restrict__ dst)
{
    const int WSZ = 65536;           // 4*128*128
    const int FSZ = 1048576;         // 2048*512
    int i4 = blockIdx.x * blockDim.x + threadIdx.x;
    long long i = (long long)i4 * 4;
    const long long total = 5LL * WSZ + 2LL * FSZ;
    if (i >= total) return;
    #pragma unroll
    for (int j = 0; j < 4; ++j) {
        long long idx = i + j;
        float v;
        if      (idx < WSZ)            v = Wq[idx];
        else if (idx < 2 * WSZ)        v = Wk[idx - WSZ];
        else if (idx < 3 * WSZ)        v = Wv[idx - 2 * WSZ];
        else if (idx < 4 * WSZ)        v = Wo[idx - 3 * WSZ];
        else if (idx < 5 * WSZ)        v = Wp[idx - 4 * WSZ];
        else if (idx < 5 * WSZ + FSZ)  v = W1[idx - 5 * WSZ];
        else                           v = W2[idx - 5 * WSZ - FSZ];
        dst[idx] = __builtin_bit_cast(unsigned short, (__bf16)v);
    }
}

// ---------------------------------------------------------------------------
// hT = bf16(bn1(x)) transposed: x (N,C,L) f32 -> hT (N,L,C) bf16
// ---------------------------------------------------------------------------
__global__ __launch_bounds__(256) void bn_transpose_kernel(
    const float* __restrict__ x,
    const float* __restrict__ g, const float* __restrict__ b,
    const float* __restrict__ bm, const float* __restrict__ bvv,
    unsigned short* __restrict__ hT, int C, int L)
{
    __shared__ float ps[64][65];
    const int l0 = blockIdx.x * 64, ct = blockIdx.y, n = blockIdx.z;
    const int tid = threadIdx.x;
    const int c = tid >> 2, q = tid & 3;
    const int cg = ct * 64 + c;
    float inv = g[cg] * rsqrtf(bvv[cg] + EPS);
    float add = b[cg] - bm[cg] * inv;
    const float* xp = x + ((size_t)n * C + cg) * L + l0 + q * 16;
    #pragma unroll
    for (int s = 0; s < 4; ++s) {
        float4 vv = *(const float4*)&xp[s * 4];
        ps[c][q * 16 + s * 4 + 0] = fmaf(vv.x, inv, add);
        ps[c][q * 16 + s * 4 + 1] = fmaf(vv.y, inv, add);
        ps[c][q * 16 + s * 4 + 2] = fmaf(vv.z, inv, add);
        ps[c][q * 16 + s * 4 + 3] = fmaf(vv.w, inv, add);
    }
    __syncthreads();
    #pragma unroll
    for (int j = 0; j < 2; ++j) {
        int row = (tid >> 3) + 32 * j;
        int cc0 = (tid & 7) * 8;
        unsigned int w0 = pack2bf(ps[cc0 + 0][row], ps[cc0 + 1][row]);
        unsigned int w1 = pack2bf(ps[cc0 + 2][row], ps[cc0 + 3][row]);
        unsigned int w2 = pack2bf(ps[cc0 + 4][row], ps[cc0 + 5][row]);
        unsigned int w3 = pack2bf(ps[cc0 + 6][row], ps[cc0 + 7][row]);
        uint4 wv = make_uint4(w0, w1, w2, w3);
        *(uint4*)&hT[((size_t)n * L + l0 + row) * C + ct * 64 + cc0] = wv;
    }
}

// ---------------------------------------------------------------------------
// Pool with fused BN1, transposed bf16 out: xa0T[n][lk][c(0..127)]
// ---------------------------------------------------------------------------
__global__ __launch_bounds__(256) void pool_bn_t_kernel(
    const float* __restrict__ x,
    const float* __restrict__ g, const float* __restrict__ b,
    const float* __restrict__ bm, const float* __restrict__ bvv,
    unsigned short* __restrict__ xa0T,
    int C, int L, int c0, int r, int Lk)
{
    __shared__ float ps[64][65];
    const int lk0 = blockIdx.x * 64, ct = blockIdx.y, n = blockIdx.z;
    const int tid = threadIdx.x;
    const int c = tid >> 2, q = tid & 3;
    const int cg = c0 + ct * 64 + c;
    float inv = g[cg] * rsqrtf(bvv[cg] + EPS);
    float add = b[cg] - bm[cg] * inv;
    const float* xp = x + ((size_t)n * C + cg) * L;
    float rinv = 1.0f / (float)r;
    #pragma unroll
    for (int s = 0; s < 16; ++s) {
        int lk = q * 16 + s;
        const float* base = xp + (size_t)(lk0 + lk) * r;
        float sum = 0.f, mx = -INFINITY;
        for (int j = 0; j < r; j += 2) {
            float2 vv = *(const float2*)&base[j];
            float t0 = fmaf(vv.x, inv, add);
            float t1 = fmaf(vv.y, inv, add);
            sum += t0 + t1;
            mx = fmaxf(mx, fmaxf(t0, t1));
        }
        ps[c][lk] = sum * rinv + mx;
    }
    __syncthreads();
    #pragma unroll
    for (int j = 0; j < 2; ++j) {
        int row = (tid >> 3) + 32 * j;
        int cc0 = (tid & 7) * 8;
        unsigned int w0 = pack2bf(ps[cc0 + 0][row], ps[cc0 + 1][row]);
        unsigned int w1 = pack2bf(ps[cc0 + 2][row], ps[cc0 + 3][row]);
        unsigned int w2 = pack2bf(ps[cc0 + 4][row], ps[cc0 + 5][row]);
        unsigned int w3 = pack2bf(ps[cc0 + 6][row], ps[cc0 + 7][row]);
        *(uint4*)&xa0T[((size_t)n * Lk + lk0 + row) * 128 + ct * 64 + cc0] =
            make_uint4(w0, w1, w2, w3);
    }
}

// ---------------------------------------------------------------------------
// bf16 MFMA GEMM, both operands k-contiguous bf16, global_load_lds staging.
// A: [M][K] bf16. BT: [Npos][ldBT] bf16 rows = output column position.
// Tile 128x128, BK=32, 4 waves (2x2). LDS linear [128][32] (64B rows) --
// exactly the wave-uniform-base + lane*16B DMA order (no padding allowed).
// OMODE: 0 = f32 natural out (+resid)
//        1 = bf16 transposed out [p][ldT] at col offset moff
//        2 = bf16 natural out [m][Npos]
//        3 = f32 natural out (+resid) AND bf16T aux with BN (g1 params)
// ---------------------------------------------------------------------------
template<int OMODE>
__global__ __launch_bounds__(256) void gemm_bf(
    const unsigned short* __restrict__ A, const unsigned short* __restrict__ BT,
    int M, int K, int Npos, int ldBT, long long strideBT,
    const float* __restrict__ bias, float oscale, int flags,
    const float* __restrict__ g1, const float* __restrict__ b1p,
    const float* __restrict__ m1p, const float* __restrict__ v1p,
    const float* __restrict__ g2, const float* __restrict__ b2p,
    const float* __restrict__ m2p, const float* __restrict__ v2p,
    float* __restrict__ outN, long long strideN,
    const float* __restrict__ resid, long long strideR,
    unsigned short* __restrict__ outT, int ldT, int moff, long long strideT)
{
    __shared__ __align__(16) unsigned short As[128][32];
    __shared__ __align__(16) unsigned short Bs[128][32];

    const int tid = threadIdx.x;
    const int m0 = blockIdx.y * 128;
    const int p0 = blockIdx.x * 128;
    const int nz = blockIdx.z;
    const unsigned short* Bn = BT + (size_t)nz * strideBT;

    const int wave = tid >> 6;
    const int lane = tid & 63;
    const int qcol = lane & 15;
    const int hi   = lane >> 4;
    const int wr   = wave >> 1;
    const int wc   = wave & 1;

    // staging roles: wave covers 32 rows (2 DMA instrs x 16 rows);
    // lane l sources row +l/4, k-segment (l%4)*8 u16 (16B)
    const int lrow = lane >> 2;
    const int lseg = (lane & 3) * 8;

    f32x4 acc[4][4] = {};

    for (int k0 = 0; k0 < K; k0 += 32) {
        #pragma unroll
        for (int j = 0; j < 2; ++j) {
            int row = wave * 32 + j * 16 + lrow;
            gload_lds16(&A[(size_t)(m0 + row) * K + k0 + lseg],
                        &As[wave * 32 + j * 16][0]);
        }
        #pragma unroll
        for (int j = 0; j < 2; ++j) {
            int row = wave * 32 + j * 16 + lrow;
            int prow = p0 + row; if (prow > Npos - 1) prow = Npos - 1;
            gload_lds16(&Bn[(size_t)prow * ldBT + k0 + lseg],
                        &Bs[wave * 32 + j * 16][0]);
        }
        __syncthreads();
        bf16x8 af[4], bfr[4];
        #pragma unroll
        for (int mi = 0; mi < 4; ++mi)
            af[mi] = *(const bf16x8*)&As[wr * 64 + mi * 16 + qcol][hi * 8];
        #pragma unroll
        for (int ni = 0; ni < 4; ++ni)
            bfr[ni] = *(const bf16x8*)&Bs[wc * 64 + ni * 16 + qcol][hi * 8];
        #pragma unroll
        for (int mi = 0; mi < 4; ++mi)
            #pragma unroll
            for (int ni = 0; ni < 4; ++ni)
                acc[mi][ni] = __builtin_amdgcn_mfma_f32_16x16x32_bf16(
                    af[mi], bfr[ni], acc[mi][ni], 0, 0, 0);
        __syncthreads();
    }

    float* Cn = outN + (size_t)nz * strideN;
    const float* Rn = resid + (size_t)nz * strideR;
    unsigned short* Tn = outT + (size_t)nz * strideT;

    #pragma unroll
    for (int mi = 0; mi < 4; ++mi) {
        const int mb = m0 + wr * 64 + mi * 16 + hi * 4;   // first of 4 rows
        float4 bv4 = make_float4(0.f, 0.f, 0.f, 0.f);
        if (flags & F_BIAS) bv4 = *(const float4*)&bias[mb];
        float s1[4], t1[4];
        if ((flags & F_DBN) || OMODE == 3) {
            float4 gg = *(const float4*)&g1[mb];
            float4 bb = *(const float4*)&b1p[mb];
            float4 mm = *(const float4*)&m1p[mb];
            float4 vv = *(const float4*)&v1p[mb];
            float gga[4] = {gg.x, gg.y, gg.z, gg.w};
            float bba[4] = {bb.x, bb.y, bb.z, bb.w};
            float mma[4] = {mm.x, mm.y, mm.z, mm.w};
            float vva[4] = {vv.x, vv.y, vv.z, vv.w};
            #pragma unroll
            for (int r2 = 0; r2 < 4; ++r2) {
                float iv = gga[r2] * rsqrtf(vva[r2] + EPS);
                s1[r2] = iv; t1[r2] = bba[r2] - mma[r2] * iv;
            }
        }
        float s2[4], t2[4];
        if (flags & F_DBN) {
            float4 gg = *(const float4*)&g2[mb];
            float4 bb = *(const float4*)&b2p[mb];
            float4 mm = *(const float4*)&m2p[mb];
            float4 vv = *(const float4*)&v2p[mb];
            float gga[4] = {gg.x, gg.y, gg.z, gg.w};
            float bba[4] = {bb.x, bb.y, bb.z, bb.w};
            float mma[4] = {mm.x, mm.y, mm.z, mm.w};
            float vva[4] = {vv.x, vv.y, vv.z, vv.w};
            #pragma unroll
            for (int r2 = 0; r2 < 4; ++r2) {
                float iv = gga[r2] * rsqrtf(vva[r2] + EPS);
                s2[r2] = iv; t2[r2] = bba[r2] - mma[r2] * iv;
            }
        }
        const float ba[4] = {bv4.x, bv4.y, bv4.z, bv4.w};
        #pragma unroll
        for (int ni = 0; ni < 4; ++ni) {
            const int cp = p0 + wc * 64 + ni * 16 + qcol;
            if (cp >= Npos) continue;
            float vals[4];
            #pragma unroll
            for (int r2 = 0; r2 < 4; ++r2) {
                float val = (acc[mi][ni][r2] + ba[r2]) * oscale;
                if (flags & F_DBN) {
                    val = fmaf(val, s1[r2], t1[r2]);
                    val = fmaf(val, s2[r2], t2[r2]);
                }
                if (flags & F_GELU) {
                    float u = val;
                    float z = 0.7978845608028654f * (u + 0.044715f * u * u * u);
                    float e = __expf(2.f * z);
                    val = 0.5f * u * (1.f + (1.f - 2.f / (e + 1.f)));
                }
                vals[r2] = val;
            }
            if (OMODE == 0 || OMODE == 3) {
                #pragma unroll
                for (int r2 = 0; r2 < 4; ++r2) {
                    size_t off = (size_t)(mb + r2) * Npos + cp;
                    float v = vals[r2];
                    if (flags & F_RESID) v += Rn[off];
                    Cn[off] = v;
                    vals[r2] = v;
                }
            }
            if (OMODE == 1) {
                *(uint2*)&Tn[(size_t)cp * ldT + moff + mb] =
                    make_uint2(pack2bf(vals[0], vals[1]), pack2bf(vals[2], vals[3]));
            }
            if (OMODE == 2) {
                #pragma unroll
                for (int r2 = 0; r2 < 4; ++r2)
                    Tn[(size_t)(mb + r2) * Npos + cp] =
                        __builtin_bit_cast(unsigned short, (__bf16)vals[r2]);
            }
            if (OMODE == 3) {
                float a0 = fmaf(vals[0], s1[0], t1[0]);
                float a1 = fmaf(vals[1], s1[1], t1[1]);
                float a2 = fmaf(vals[2], s1[2], t1[2]);
                float a3 = fmaf(vals[3], s1[3], t1[3]);
                *(uint2*)&Tn[(size_t)cp * ldT + moff + mb] =
                    make_uint2(pack2bf(a0, a1), pack2bf(a2, a3));
            }
        }
    }
}

// ---------------------------------------------------------------------------
// Flash attention, all-bf16 operands loaded fragment-direct from global.
// qT,kT: [n][pos][128] bf16 (head cols h*64..). vN: [n][128][Lk] bf16.
// obT out: [n][pos][128] bf16. No barriers; per-wave P bounce in LDS.
// ---------------------------------------------------------------------------
__global__ __launch_bounds__(256) void attn_bf_kernel(
    const unsigned short* __restrict__ qT, const unsigned short* __restrict__ kT,
    const unsigned short* __restrict__ vN, unsigned short* __restrict__ obT,
    int L, int Lk)
{
    const int l0 = blockIdx.x * 64;
    const int nh = blockIdx.y;
    const int n = nh >> 1, h = nh & 1;
    const unsigned short* qn = qT + (size_t)n * L * 128 + h * 64;
    const unsigned short* kn = kT + (size_t)n * Lk * 128 + h * 64;
    const unsigned short* vn = vN + ((size_t)n * 128 + h * 64) * Lk;
    unsigned short*       on = obT + (size_t)n * L * 128 + h * 64;

    __shared__ __align__(16) unsigned short Ps[4][16][72];

    const int tid = threadIdx.x;
    const int wave = tid >> 6;
    const int lane = tid & 63;
    const int qcol = lane & 15;
    const int hi   = lane >> 4;
    const int ql   = wave * 16 + qcol;

    bf16x8 qf0 = *(const bf16x8*)&qn[(size_t)(l0 + ql) * 128 + hi * 8];
    bf16x8 qf1 = *(const bf16x8*)&qn[(size_t)(l0 + ql) * 128 + 32 + hi * 8];

    f32x4 o_acc[4] = {};
    float mrow = -INFINITY, lrow = 0.f;

    for (int mc = 0; mc < Lk; mc += 64) {
        f32x4 sacc[4];
        #pragma unroll
        for (int kt = 0; kt < 4; ++kt) {
            const size_t kr = (size_t)(mc + kt * 16 + qcol) * 128;
            bf16x8 k0 = *(const bf16x8*)&kn[kr + hi * 8];
            bf16x8 k1 = *(const bf16x8*)&kn[kr + 32 + hi * 8];
            f32x4 a = {};
            a = __builtin_amdgcn_mfma_f32_16x16x32_bf16(k0, qf0, a, 0, 0, 0);
            a = __builtin_amdgcn_mfma_f32_16x16x32_bf16(k1, qf1, a, 0, 0, 0);
            sacc[kt] = a;
        }

        float cm = -INFINITY;
        #pragma unroll
        for (int kt = 0; kt < 4; ++kt)
            #pragma unroll
            for (int r2 = 0; r2 < 4; ++r2) cm = fmaxf(cm, sacc[kt][r2]);
        cm = fmaxf(cm, __shfl_xor(cm, 16));
        cm = fmaxf(cm, __shfl_xor(cm, 32));
        float nm = fmaxf(mrow, cm);
        float alpha = __expf(mrow - nm);
        float csum = 0.f;
        unsigned int pw[4][2];
        #pragma unroll
        for (int kt = 0; kt < 4; ++kt) {
            float p0 = __expf(sacc[kt][0] - nm);
            float p1 = __expf(sacc[kt][1] - nm);
            float p2 = __expf(sacc[kt][2] - nm);
            float p3 = __expf(sacc[kt][3] - nm);
            csum += (p0 + p1) + (p2 + p3);
            pw[kt][0] = pack2bf(p0, p1);
            pw[kt][1] = pack2bf(p2, p3);
        }
        csum += __shfl_xor(csum, 16);
        csum += __shfl_xor(csum, 32);
        lrow = lrow * alpha + csum;
        mrow = nm;

        #pragma unroll
        for (int kt = 0; kt < 4; ++kt)
            *(uint2*)&Ps[wave][qcol][kt * 16 + hi * 4] =
                make_uint2(pw[kt][0], pw[kt][1]);

        #pragma unroll
        for (int et = 0; et < 4; ++et)
            #pragma unroll
            for (int r2 = 0; r2 < 4; ++r2) o_acc[et][r2] *= alpha;

        bf16x8 pf0 = *(const bf16x8*)&Ps[wave][qcol][hi * 8];
        bf16x8 pf1 = *(const bf16x8*)&Ps[wave][qcol][hi * 8 + 32];
        #pragma unroll
        for (int et = 0; et < 4; ++et) {
            const size_t vr = (size_t)(et * 16 + qcol) * Lk + mc;
            bf16x8 v0 = *(const bf16x8*)&vn[vr + hi * 8];
            bf16x8 v1 = *(const bf16x8*)&vn[vr + 32 + hi * 8];
            o_acc[et] = __builtin_amdgcn_mfma_f32_16x16x32_bf16(v0, pf0, o_acc[et], 0, 0, 0);
            o_acc[et] = __builtin_amdgcn_mfma_f32_16x16x32_bf16(v1, pf1, o_acc[et], 0, 0, 0);
        }
    }

    float invl = 1.f / lrow;
    #pragma unroll
    for (int et = 0; et < 4; ++et) {
        float a0 = o_acc[et][0] * invl, a1 = o_acc[et][1] * invl;
        float a2 = o_acc[et][2] * invl, a3 = o_acc[et][3] * invl;
        *(uint2*)&on[(size_t)(l0 + ql) * 128 + et * 16 + hi * 4] =
            make_uint2(pack2bf(a0, a1), pack2bf(a2, a3));
    }
}

// ---------------------------------------------------------------------------
extern "C" void kernel_launch(void* const* d_in, const int* in_sizes, int n_in,
                              void* d_out, int out_size, void* d_ws, size_t ws_size,
                              hipStream_t stream)
{
    const float* x   = (const float*)d_in[0];
    const float* n1g = (const float*)d_in[1];
    const float* n1b = (const float*)d_in[2];
    const float* n1m = (const float*)d_in[3];
    const float* n1v = (const float*)d_in[4];
    const float* n2g = (const float*)d_in[5];
    const float* n2b = (const float*)d_in[6];
    const float* n2m = (const float*)d_in[7];
    const float* n2v = (const float*)d_in[8];
    const float* Wq  = (const float*)d_in[9];
    const float* Wk  = (const float*)d_in[10];
    const float* Wv  = (const float*)d_in[11];
    const float* Wo  = (const float*)d_in[12];
    const float* Wp  = (const float*)d_in[13];
    const float* bq  = (const float*)d_in[14];
    const float* bk  = (const float*)d_in[15];
    const float* bv  = (const float*)d_in[16];
    const float* bo  = (const float*)d_in[17];
    const float* agg = (const float*)d_in[18];
    const float* agb = (const float*)d_in[19];
    const float* agm = (const float*)d_in[20];
    const float* agv = (const float*)d_in[21];
    const float* ang = (const float*)d_in[22];
    const float* anb = (const float*)d_in[23];
    const float* anm = (const float*)d_in[24];
    const float* anv = (const float*)d_in[25];
    const float* W1  = (const float*)d_in[26];
    const float* b1  = (const float*)d_in[27];
    const float* W2  = (const float*)d_in[28];
    const float* b2  = (const float*)d_in[29];

    float* out = (float*)d_out;
    unsigned short* wsb = (unsigned short*)d_ws;

    const int N = 8, Cc = 512, L = 3072, P = 4, dd = 128, FF = 2048;
    const int ratios[4] = {2, 4, 8, 16};
    const int WSZ = 65536, FSZ = 1048576;

    // ws layout (u16 elems)
    unsigned short* wbf   = wsb;
    unsigned short* hT    = wbf   + 5 * WSZ + 2 * FSZ;
    unsigned short* qT    = hT    + (size_t)N * L * Cc;
    unsigned short* obT   = qT    + (size_t)N * L * dd;
    unsigned short* xa0T  = obT   + (size_t)N * L * dd;
    unsigned short* xabT  = xa0T  + (size_t)N * (L / 2) * dd;
    unsigned short* kTb   = xabT  + (size_t)N * (L / 2) * dd;
    unsigned short* vNb   = kTb   + (size_t)N * (L / 2) * dd;
    unsigned short* h2T   = vNb   + (size_t)N * (L / 2) * dd;
    unsigned short* m1T   = h2T   + (size_t)N * L * Cc;

    const unsigned short* WqB = wbf;
    const unsigned short* WkB = wbf + WSZ;
    const unsigned short* WvB = wbf + 2 * WSZ;
    const unsigned short* WoB = wbf + 3 * WSZ;
    const unsigned short* WpB = wbf + 4 * WSZ;
    const unsigned short* W1B = wbf + 5 * WSZ;
    const unsigned short* W2B = wbf + 5 * WSZ + FSZ;

    const float* nul = nullptr;
    float* nulf = nullptr;
    unsigned short* nulu = nullptr;

    {
        long long tot4 = (5LL * WSZ + 2LL * FSZ) / 4;
        wcvt_kernel<<<dim3((unsigned)((tot4 + 255) / 256)), dim3(256), 0, stream>>>(
            Wq, Wk, Wv, Wo, Wp, W1, W2, wbf);
    }
    bn_transpose_kernel<<<dim3(L / 64, Cc / 64, N), dim3(256), 0, stream>>>(
        x, n1g, n1b, n1m, n1v, hT, Cc, L);

    for (int i = 0; i < P; ++i) {
        const int r = ratios[i], Lk = L / r;
        const int c0 = i * dd;
        const int gx = (Lk + 127) / 128;

        pool_bn_t_kernel<<<dim3(Lk / 64, 2, N), dim3(256), 0, stream>>>(
            x, n1g, n1b, n1m, n1v, xa0T, Cc, L, c0, r, Lk);

        // xabT = bf16(doubleBN(Wp @ xa0))^T
        gemm_bf<1><<<dim3(gx, 1, N), dim3(256), 0, stream>>>(
            WpB + (size_t)i * dd * dd, xa0T, dd, dd, Lk, dd, (long long)Lk * dd,
            nul, 1.f, F_DBN,
            agg + c0, agb + c0, agm + c0, agv + c0,
            ang + c0, anb + c0, anm + c0, anv + c0,
            nulf, 0, nul, 0, xabT, dd, 0, (long long)Lk * dd);

        // qT = bf16((Wq @ h_slice + bq) * 0.125)^T
        gemm_bf<1><<<dim3(L / 128, 1, N), dim3(256), 0, stream>>>(
            WqB + (size_t)i * dd * dd, hT + c0, dd, dd, L, Cc, (long long)L * Cc,
            bq + c0, 0.125f, F_BIAS,
            nul, nul, nul, nul, nul, nul, nul, nul,
            nulf, 0, nul, 0, qT, dd, 0, (long long)L * dd);

        // kT = bf16(Wk @ xa + bk)^T
        gemm_bf<1><<<dim3(gx, 1, N), dim3(256), 0, stream>>>(
            WkB + (size_t)i * dd * dd, xabT, dd, dd, Lk, dd, (long long)Lk * dd,
            bk + c0, 1.f, F_BIAS,
            nul, nul, nul, nul, nul, nul, nul, nul,
            nulf, 0, nul, 0, kTb, dd, 0, (long long)Lk * dd);

        // vN = bf16(Wv @ xa + bv) natural
        gemm_bf<2><<<dim3(gx, 1, N), dim3(256), 0, stream>>>(
            WvB + (size_t)i * dd * dd, xabT, dd, dd, Lk, dd, (long long)Lk * dd,
            bv + c0, 1.f, F_BIAS,
            nul, nul, nul, nul, nul, nul, nul, nul,
            nulf, 0, nul, 0, vNb, 0, 0, (long long)dd * Lk);

        attn_bf_kernel<<<dim3(L / 64, N * 2), dim3(256), 0, stream>>>(
            qT, kTb, vNb, obT, L, Lk);

        // out_slice = x_slice + Wo @ o + bo  (f32) ; h2T aux = bf16(bn2(out))
        gemm_bf<3><<<dim3(L / 128, 1, N), dim3(256), 0, stream>>>(
            WoB + (size_t)i * dd * dd, obT, dd, dd, L, dd, (long long)L * dd,
            bo + c0, 1.f, F_BIAS | F_RESID,
            n2g + c0, n2b + c0, n2m + c0, n2v + c0,
            nul, nul, nul, nul,
            out + (size_t)c0 * L, (long long)Cc * L,
            x + (size_t)c0 * L, (long long)Cc * L,
            h2T, Cc, c0, (long long)L * Cc);
    }

    // FFN: m1T = bf16(gelu(W1 @ h2 + b1))^T
    gemm_bf<1><<<dim3(L / 128, FF / 128, N), dim3(256), 0, stream>>>(
        W1B, h2T, FF, Cc, L, Cc, (long long)L * Cc,
        b1, 1.f, F_BIAS | F_GELU,
        nul, nul, nul, nul, nul, nul, nul, nul,
        nulf, 0, nul, 0, m1T, FF, 0, (long long)L * FF);

    // out += W2 @ m1 + b2
    gemm_bf<0><<<dim3(L / 128, Cc / 128, N), dim3(256), 0, stream>>>(
        W2B, m1T, Cc, FF, L, FF, (long long)L * FF,
        b2, 1.f, F_BIAS | F_RESID,
        nul, nul, nul, nul, nul, nul, nul, nul,
        out, (long long)Cc * L, out, (long long)Cc * L,
        nulu, 0, 0, 0);
}

// Round 6
// 993.917 us; speedup vs baseline: 6.2670x; 1.0537x over previous
//
#include <hip/hip_runtime.h>
#include <math.h>

#define EPS 1e-5f

#define F_BIAS  1
#define F_DBN   2
#define F_GELU  4
#define F_RESID 8

typedef __attribute__((ext_vector_type(8))) __bf16 bf16x8;
typedef __attribute__((ext_vector_type(4))) float f32x4;
typedef __attribute__((ext_vector_type(8))) unsigned short u16x8;

__device__ __forceinline__ unsigned int pack2bf(float a, float b) {
    unsigned short ua = __builtin_bit_cast(unsigned short, (__bf16)a);
    unsigned short ub = __builtin_bit_cast(unsigned short, (__bf16)b);
    return (unsigned int)ua | ((unsigned int)ub << 16);
}

// async global->LDS, 16B per lane; dst wave-uniform, src per-lane
__device__ __forceinline__ void gload_lds16(const unsigned short* g, unsigned short* l) {
    __builtin_amdgcn_global_load_lds(
        (const __attribute__((address_space(1))) unsigned int*)g,
        (__attribute__((address_space(3))) unsigned int*)l,
        16, 0, 0);
}

// ---------------------------------------------------------------------------
// Convert all weights fp32 -> bf16 into one ws region
// ---------------------------------------------------------------------------
__global__ __launch_bounds__(256) void wcvt_kernel(
    const float* __restrict__ Wq, const float* __restrict__ Wk,
    const float* __restrict__ Wv, const float* __restrict__ Wo,
    const float* __restrict__ Wp, const float* __restrict__ W1,
    const float* __restrict__ W2, unsigned short* __restrict__ dst)
{
    const int WSZ = 65536;           // 4*128*128
    const int FSZ = 1048576;         // 2048*512
    int i4 = blockIdx.x * blockDim.x + threadIdx.x;
    long long i = (long long)i4 * 4;
    const long long total = 5LL * WSZ + 2LL * FSZ;
    if (i >= total) return;
    #pragma unroll
    for (int j = 0; j < 4; ++j) {
        long long idx = i + j;
        float v;
        if      (idx < WSZ)            v = Wq[idx];
        else if (idx < 2 * WSZ)        v = Wk[idx - WSZ];
        else if (idx < 3 * WSZ)        v = Wv[idx - 2 * WSZ];
        else if (idx < 4 * WSZ)        v = Wo[idx - 3 * WSZ];
        else if (idx < 5 * WSZ)        v = Wp[idx - 4 * WSZ];
        else if (idx < 5 * WSZ + FSZ)  v = W1[idx - 5 * WSZ];
        else                           v = W2[idx - 5 * WSZ - FSZ];
        dst[idx] = __builtin_bit_cast(unsigned short, (__bf16)v);
    }
}

// ---------------------------------------------------------------------------
// hT = bf16(bn1(x)) transposed: x (N,C,L) f32 -> hT (N,L,C) bf16
// ---------------------------------------------------------------------------
__global__ __launch_bounds__(256) void bn_transpose_kernel(
    const float* __restrict__ x,
    const float* __restrict__ g, const float* __restrict__ b,
    const float* __restrict__ bm, const float* __restrict__ bvv,
    unsigned short* __restrict__ hT, int C, int L)
{
    __shared__ float ps[64][65];
    const int l0 = blockIdx.x * 64, ct = blockIdx.y, n = blockIdx.z;
    const int tid = threadIdx.x;
    const int c = tid >> 2, q = tid & 3;
    const int cg = ct * 64 + c;
    float inv = g[cg] * rsqrtf(bvv[cg] + EPS);
    float add = b[cg] - bm[cg] * inv;
    const float* xp = x + ((size_t)n * C + cg) * L + l0 + q * 16;
    #pragma unroll
    for (int s = 0; s < 4; ++s) {
        float4 vv = *(const float4*)&xp[s * 4];
        ps[c][q * 16 + s * 4 + 0] = fmaf(vv.x, inv, add);
        ps[c][q * 16 + s * 4 + 1] = fmaf(vv.y, inv, add);
        ps[c][q * 16 + s * 4 + 2] = fmaf(vv.z, inv, add);
        ps[c][q * 16 + s * 4 + 3] = fmaf(vv.w, inv, add);
    }
    __syncthreads();
    #pragma unroll
    for (int j = 0; j < 2; ++j) {
        int row = (tid >> 3) + 32 * j;
        int cc0 = (tid & 7) * 8;
        unsigned int w0 = pack2bf(ps[cc0 + 0][row], ps[cc0 + 1][row]);
        unsigned int w1 = pack2bf(ps[cc0 + 2][row], ps[cc0 + 3][row]);
        unsigned int w2 = pack2bf(ps[cc0 + 4][row], ps[cc0 + 5][row]);
        unsigned int w3 = pack2bf(ps[cc0 + 6][row], ps[cc0 + 7][row]);
        uint4 wv = make_uint4(w0, w1, w2, w3);
        *(uint4*)&hT[((size_t)n * L + l0 + row) * C + ct * 64 + cc0] = wv;
    }
}

// ---------------------------------------------------------------------------
// Pool with fused BN1, transposed bf16 out: xa0T[n][lk][c(0..127)]
// ---------------------------------------------------------------------------
__global__ __launch_bounds__(256) void pool_bn_t_kernel(
    const float* __restrict__ x,
    const float* __restrict__ g, const float* __restrict__ b,
    const float* __restrict__ bm, const float* __restrict__ bvv,
    unsigned short* __restrict__ xa0T,
    int C, int L, int c0, int r, int Lk)
{
    __shared__ float ps[64][65];
    const int lk0 = blockIdx.x * 64, ct = blockIdx.y, n = blockIdx.z;
    const int tid = threadIdx.x;
    const int c = tid >> 2, q = tid & 3;
    const int cg = c0 + ct * 64 + c;
    float inv = g[cg] * rsqrtf(bvv[cg] + EPS);
    float add = b[cg] - bm[cg] * inv;
    const float* xp = x + ((size_t)n * C + cg) * L;
    float rinv = 1.0f / (float)r;
    #pragma unroll
    for (int s = 0; s < 16; ++s) {
        int lk = q * 16 + s;
        const float* base = xp + (size_t)(lk0 + lk) * r;
        float sum = 0.f, mx = -INFINITY;
        for (int j = 0; j < r; j += 2) {
            float2 vv = *(const float2*)&base[j];
            float t0 = fmaf(vv.x, inv, add);
            float t1 = fmaf(vv.y, inv, add);
            sum += t0 + t1;
            mx = fmaxf(mx, fmaxf(t0, t1));
        }
        ps[c][lk] = sum * rinv + mx;
    }
    __syncthreads();
    #pragma unroll
    for (int j = 0; j < 2; ++j) {
        int row = (tid >> 3) + 32 * j;
        int cc0 = (tid & 7) * 8;
        unsigned int w0 = pack2bf(ps[cc0 + 0][row], ps[cc0 + 1][row]);
        unsigned int w1 = pack2bf(ps[cc0 + 2][row], ps[cc0 + 3][row]);
        unsigned int w2 = pack2bf(ps[cc0 + 4][row], ps[cc0 + 5][row]);
        unsigned int w3 = pack2bf(ps[cc0 + 6][row], ps[cc0 + 7][row]);
        *(uint4*)&xa0T[((size_t)n * Lk + lk0 + row) * 128 + ct * 64 + cc0] =
            make_uint4(w0, w1, w2, w3);
    }
}

// ---------------------------------------------------------------------------
// bf16 MFMA GEMM, k-contiguous bf16 operands, global_load_lds staging,
// 2-phase double-buffered K-loop (T3-min recipe):
//   prologue STAGE(buf0,0); loop { STAGE(buf^1,t+1); MFMA(buf); barrier }
// A: [M][K] bf16. BT: [Npos][ldBT] bf16. Tile 128x128, BK=32, 4 waves (2x2).
// gKoff: per-m-block B column offset (grouped/block-diagonal GEMM: path =
// m0/128 reads B k-columns at path*gKoff). 0 for normal GEMM.
// OMODE: 0 = f32 natural out (+resid)
//        1 = bf16 transposed out [p][ldT] at col offset moff
//        2 = bf16 natural out [m][Npos]
//        3 = f32 natural out (+resid) AND bf16T aux with BN (g1 params)
// ---------------------------------------------------------------------------
template<int OMODE>
__global__ __launch_bounds__(256) void gemm_bf(
    const unsigned short* __restrict__ A, const unsigned short* __restrict__ BT,
    int M, int K, int Npos, int ldBT, long long strideBT,
    const float* __restrict__ bias, float oscale, int flags,
    const float* __restrict__ g1, const float* __restrict__ b1p,
    const float* __restrict__ m1p, const float* __restrict__ v1p,
    const float* __restrict__ g2, const float* __restrict__ b2p,
    const float* __restrict__ m2p, const float* __restrict__ v2p,
    float* __restrict__ outN, long long strideN,
    const float* __restrict__ resid, long long strideR,
    unsigned short* __restrict__ outT, int ldT, int moff, long long strideT,
    int gKoff)
{
    __shared__ __align__(16) unsigned short As[2][128][32];
    __shared__ __align__(16) unsigned short Bs[2][128][32];

    const int tid = threadIdx.x;
    const int m0 = blockIdx.y * 128;
    const int p0 = blockIdx.x * 128;
    const int nz = blockIdx.z;
    const unsigned short* Bn = BT + (size_t)nz * strideBT
                              + (size_t)(m0 >> 7) * gKoff;

    const int wave = tid >> 6;
    const int lane = tid & 63;
    const int qcol = lane & 15;
    const int hi   = lane >> 4;
    const int wr   = wave >> 1;
    const int wc   = wave & 1;

    // staging roles: wave covers 32 rows (2 DMA x 16 rows);
    // lane l sources row +l/4, k-seg (l%4)*8 u16 (16B)
    const int lrow = lane >> 2;
    const int lseg = (lane & 3) * 8;

    auto STAGE = [&](int b, int t) {
        const int k0 = t * 32;
        #pragma unroll
        for (int j = 0; j < 2; ++j) {
            int row = wave * 32 + j * 16 + lrow;
            gload_lds16(&A[(size_t)(m0 + row) * K + k0 + lseg],
                        &As[b][wave * 32 + j * 16][0]);
        }
        #pragma unroll
        for (int j = 0; j < 2; ++j) {
            int row = wave * 32 + j * 16 + lrow;
            int prow = p0 + row; if (prow > Npos - 1) prow = Npos - 1;
            gload_lds16(&Bn[(size_t)prow * ldBT + k0 + lseg],
                        &Bs[b][wave * 32 + j * 16][0]);
        }
    };

    f32x4 acc[4][4] = {};
    const int nt = K >> 5;

    STAGE(0, 0);
    asm volatile("s_waitcnt vmcnt(0)" ::: "memory");
    __syncthreads();

    int cur = 0;
    for (int t = 0; t < nt; ++t) {
        if (t + 1 < nt) STAGE(cur ^ 1, t + 1);
        bf16x8 af[4], bfr[4];
        #pragma unroll
        for (int mi = 0; mi < 4; ++mi)
            af[mi] = *(const bf16x8*)&As[cur][wr * 64 + mi * 16 + qcol][hi * 8];
        #pragma unroll
        for (int ni = 0; ni < 4; ++ni)
            bfr[ni] = *(const bf16x8*)&Bs[cur][wc * 64 + ni * 16 + qcol][hi * 8];
        #pragma unroll
        for (int mi = 0; mi < 4; ++mi)
            #pragma unroll
            for (int ni = 0; ni < 4; ++ni)
                acc[mi][ni] = __builtin_amdgcn_mfma_f32_16x16x32_bf16(
                    af[mi], bfr[ni], acc[mi][ni], 0, 0, 0);
        asm volatile("s_waitcnt vmcnt(0)" ::: "memory");
        __syncthreads();
        cur ^= 1;
    }

    float* Cn = outN + (size_t)nz * strideN;
    const float* Rn = resid + (size_t)nz * strideR;
    unsigned short* Tn = outT + (size_t)nz * strideT;

    #pragma unroll
    for (int mi = 0; mi < 4; ++mi) {
        const int mb = m0 + wr * 64 + mi * 16 + hi * 4;   // first of 4 rows
        float4 bv4 = make_float4(0.f, 0.f, 0.f, 0.f);
        if (flags & F_BIAS) bv4 = *(const float4*)&bias[mb];
        float s1[4], t1[4];
        if ((flags & F_DBN) || OMODE == 3) {
            float4 gg = *(const float4*)&g1[mb];
            float4 bb = *(const float4*)&b1p[mb];
            float4 mm = *(const float4*)&m1p[mb];
            float4 vv = *(const float4*)&v1p[mb];
            float gga[4] = {gg.x, gg.y, gg.z, gg.w};
            float bba[4] = {bb.x, bb.y, bb.z, bb.w};
            float mma[4] = {mm.x, mm.y, mm.z, mm.w};
            float vva[4] = {vv.x, vv.y, vv.z, vv.w};
            #pragma unroll
            for (int r2 = 0; r2 < 4; ++r2) {
                float iv = gga[r2] * rsqrtf(vva[r2] + EPS);
                s1[r2] = iv; t1[r2] = bba[r2] - mma[r2] * iv;
            }
        }
        float s2[4], t2[4];
        if (flags & F_DBN) {
            float4 gg = *(const float4*)&g2[mb];
            float4 bb = *(const float4*)&b2p[mb];
            float4 mm = *(const float4*)&m2p[mb];
            float4 vv = *(const float4*)&v2p[mb];
            float gga[4] = {gg.x, gg.y, gg.z, gg.w};
            float bba[4] = {bb.x, bb.y, bb.z, bb.w};
            float mma[4] = {mm.x, mm.y, mm.z, mm.w};
            float vva[4] = {vv.x, vv.y, vv.z, vv.w};
            #pragma unroll
            for (int r2 = 0; r2 < 4; ++r2) {
                float iv = gga[r2] * rsqrtf(vva[r2] + EPS);
                s2[r2] = iv; t2[r2] = bba[r2] - mma[r2] * iv;
            }
        }
        const float ba[4] = {bv4.x, bv4.y, bv4.z, bv4.w};
        #pragma unroll
        for (int ni = 0; ni < 4; ++ni) {
            const int cp = p0 + wc * 64 + ni * 16 + qcol;
            if (cp >= Npos) continue;
            float vals[4];
            #pragma unroll
            for (int r2 = 0; r2 < 4; ++r2) {
                float val = (acc[mi][ni][r2] + ba[r2]) * oscale;
                if (flags & F_DBN) {
                    val = fmaf(val, s1[r2], t1[r2]);
                    val = fmaf(val, s2[r2], t2[r2]);
                }
                if (flags & F_GELU) {
                    float u = val;
                    float z = 0.7978845608028654f * (u + 0.044715f * u * u * u);
                    float e = __expf(2.f * z);
                    val = 0.5f * u * (1.f + (1.f - 2.f / (e + 1.f)));
                }
                vals[r2] = val;
            }
            if (OMODE == 0 || OMODE == 3) {
                #pragma unroll
                for (int r2 = 0; r2 < 4; ++r2) {
                    size_t off = (size_t)(mb + r2) * Npos + cp;
                    float v = vals[r2];
                    if (flags & F_RESID) v += Rn[off];
                    Cn[off] = v;
                    vals[r2] = v;
                }
            }
            if (OMODE == 1) {
                *(uint2*)&Tn[(size_t)cp * ldT + moff + mb] =
                    make_uint2(pack2bf(vals[0], vals[1]), pack2bf(vals[2], vals[3]));
            }
            if (OMODE == 2) {
                #pragma unroll
                for (int r2 = 0; r2 < 4; ++r2)
                    Tn[(size_t)(mb + r2) * Npos + cp] =
                        __builtin_bit_cast(unsigned short, (__bf16)vals[r2]);
            }
            if (OMODE == 3) {
                float a0 = fmaf(vals[0], s1[0], t1[0]);
                float a1 = fmaf(vals[1], s1[1], t1[1]);
                float a2 = fmaf(vals[2], s1[2], t1[2]);
                float a3 = fmaf(vals[3], s1[3], t1[3]);
                *(uint2*)&Tn[(size_t)cp * ldT + moff + mb] =
                    make_uint2(pack2bf(a0, a1), pack2bf(a2, a3));
            }
        }
    }
}

// ---------------------------------------------------------------------------
// Flash attention, all-bf16 operands loaded fragment-direct from global.
// qT rows have stride qld (grouped-Q buffer). kT: [n][pos][128]. vN: [n][128][Lk].
// ---------------------------------------------------------------------------
__global__ __launch_bounds__(256) void attn_bf_kernel(
    const unsigned short* __restrict__ qT, const unsigned short* __restrict__ kT,
    const unsigned short* __restrict__ vN, unsigned short* __restrict__ obT,
    int L, int Lk, int qld)
{
    const int l0 = blockIdx.x * 64;
    const int nh = blockIdx.y;
    const int n = nh >> 1, h = nh & 1;
    const unsigned short* qn = qT + (size_t)n * L * qld + h * 64;
    const unsigned short* kn = kT + (size_t)n * Lk * 128 + h * 64;
    const unsigned short* vn = vN + ((size_t)n * 128 + h * 64) * Lk;
    unsigned short*       on = obT + (size_t)n * L * 128 + h * 64;

    __shared__ __align__(16) unsigned short Ps[4][16][72];

    const int tid = threadIdx.x;
    const int wave = tid >> 6;
    const int lane = tid & 63;
    const int qcol = lane & 15;
    const int hi   = lane >> 4;
    const int ql   = wave * 16 + qcol;

    bf16x8 qf0 = *(const bf16x8*)&qn[(size_t)(l0 + ql) * qld + hi * 8];
    bf16x8 qf1 = *(const bf16x8*)&qn[(size_t)(l0 + ql) * qld + 32 + hi * 8];

    f32x4 o_acc[4] = {};
    float mrow = -INFINITY, lrow = 0.f;

    for (int mc = 0; mc < Lk; mc += 64) {
        f32x4 sacc[4];
        #pragma unroll
        for (int kt = 0; kt < 4; ++kt) {
            const size_t kr = (size_t)(mc + kt * 16 + qcol) * 128;
            bf16x8 k0 = *(const bf16x8*)&kn[kr + hi * 8];
            bf16x8 k1 = *(const bf16x8*)&kn[kr + 32 + hi * 8];
            f32x4 a = {};
            a = __builtin_amdgcn_mfma_f32_16x16x32_bf16(k0, qf0, a, 0, 0, 0);
            a = __builtin_amdgcn_mfma_f32_16x16x32_bf16(k1, qf1, a, 0, 0, 0);
            sacc[kt] = a;
        }

        float cm = -INFINITY;
        #pragma unroll
        for (int kt = 0; kt < 4; ++kt)
            #pragma unroll
            for (int r2 = 0; r2 < 4; ++r2) cm = fmaxf(cm, sacc[kt][r2]);
        cm = fmaxf(cm, __shfl_xor(cm, 16));
        cm = fmaxf(cm, __shfl_xor(cm, 32));
        float nm = fmaxf(mrow, cm);
        float alpha = __expf(mrow - nm);
        float csum = 0.f;
        unsigned int pw[4][2];
        #pragma unroll
        for (int kt = 0; kt < 4; ++kt) {
            float p0 = __expf(sacc[kt][0] - nm);
            float p1 = __expf(sacc[kt][1] - nm);
            float p2 = __expf(sacc[kt][2] - nm);
            float p3 = __expf(sacc[kt][3] - nm);
            csum += (p0 + p1) + (p2 + p3);
            pw[kt][0] = pack2bf(p0, p1);
            pw[kt][1] = pack2bf(p2, p3);
        }
        csum += __shfl_xor(csum, 16);
        csum += __shfl_xor(csum, 32);
        lrow = lrow * alpha + csum;
        mrow = nm;

        #pragma unroll
        for (int kt = 0; kt < 4; ++kt)
            *(uint2*)&Ps[wave][qcol][kt * 16 + hi * 4] =
                make_uint2(pw[kt][0], pw[kt][1]);

        #pragma unroll
        for (int et = 0; et < 4; ++et)
            #pragma unroll
            for (int r2 = 0; r2 < 4; ++r2) o_acc[et][r2] *= alpha;

        bf16x8 pf0 = *(const bf16x8*)&Ps[wave][qcol][hi * 8];
        bf16x8 pf1 = *(const bf16x8*)&Ps[wave][qcol][hi * 8 + 32];
        #pragma unroll
        for (int et = 0; et < 4; ++et) {
            const size_t vr = (size_t)(et * 16 + qcol) * Lk + mc;
            bf16x8 v0 = *(const bf16x8*)&vn[vr + hi * 8];
            bf16x8 v1 = *(const bf16x8*)&vn[vr + 32 + hi * 8];
            o_acc[et] = __builtin_amdgcn_mfma_f32_16x16x32_bf16(v0, pf0, o_acc[et], 0, 0, 0);
            o_acc[et] = __builtin_amdgcn_mfma_f32_16x16x32_bf16(v1, pf1, o_acc[et], 0, 0, 0);
        }
    }

    float invl = 1.f / lrow;
    #pragma unroll
    for (int et = 0; et < 4; ++et) {
        float a0 = o_acc[et][0] * invl, a1 = o_acc[et][1] * invl;
        float a2 = o_acc[et][2] * invl, a3 = o_acc[et][3] * invl;
        *(uint2*)&on[(size_t)(l0 + ql) * 128 + et * 16 + hi * 4] =
            make_uint2(pack2bf(a0, a1), pack2bf(a2, a3));
    }
}

// ---------------------------------------------------------------------------
extern "C" void kernel_launch(void* const* d_in, const int* in_sizes, int n_in,
                              void* d_out, int out_size, void* d_ws, size_t ws_size,
                              hipStream_t stream)
{
    const float* x   = (const float*)d_in[0];
    const float* n1g = (const float*)d_in[1];
    const float* n1b = (const float*)d_in[2];
    const float* n1m = (const float*)d_in[3];
    const float* n1v = (const float*)d_in[4];
    const float* n2g = (const float*)d_in[5];
    const float* n2b = (const float*)d_in[6];
    const float* n2m = (const float*)d_in[7];
    const float* n2v = (const float*)d_in[8];
    const float* Wq  = (const float*)d_in[9];
    const float* Wk  = (const float*)d_in[10];
    const float* Wv  = (const float*)d_in[11];
    const float* Wo  = (const float*)d_in[12];
    const float* Wp  = (const float*)d_in[13];
    const float* bq  = (const float*)d_in[14];
    const float* bk  = (const float*)d_in[15];
    const float* bv  = (const float*)d_in[16];
    const float* bo  = (const float*)d_in[17];
    const float* agg = (const float*)d_in[18];
    const float* agb = (const float*)d_in[19];
    const float* agm = (const float*)d_in[20];
    const float* agv = (const float*)d_in[21];
    const float* ang = (const float*)d_in[22];
    const float* anb = (const float*)d_in[23];
    const float* anm = (const float*)d_in[24];
    const float* anv = (const float*)d_in[25];
    const float* W1  = (const float*)d_in[26];
    const float* b1  = (const float*)d_in[27];
    const float* W2  = (const float*)d_in[28];
    const float* b2  = (const float*)d_in[29];

    float* out = (float*)d_out;
    unsigned short* wsb = (unsigned short*)d_ws;

    const int N = 8, Cc = 512, L = 3072, P = 4, dd = 128, FF = 2048;
    const int ratios[4] = {2, 4, 8, 16};
    const int WSZ = 65536, FSZ = 1048576;

    // ws layout (u16 elems) -- same offsets as round 4/5; qT slot unused,
    // grouped qTall aliases the m1T region (dead by the time W1 writes m1T)
    unsigned short* wbf   = wsb;
    unsigned short* hT    = wbf   + 5 * WSZ + 2 * FSZ;
    unsigned short* qTold = hT    + (size_t)N * L * Cc;
    unsigned short* obT   = qTold + (size_t)N * L * dd;
    unsigned short* xa0T  = obT   + (size_t)N * L * dd;
    unsigned short* xabT  = xa0T  + (size_t)N * (L / 2) * dd;
    unsigned short* kTb   = xabT  + (size_t)N * (L / 2) * dd;
    unsigned short* vNb   = kTb   + (size_t)N * (L / 2) * dd;
    unsigned short* h2T   = vNb   + (size_t)N * (L / 2) * dd;
    unsigned short* m1T   = h2T   + (size_t)N * L * Cc;
    unsigned short* qTall = m1T;   // [N][L][512], dead before FFN writes m1T

    const unsigned short* WqB = wbf;
    const unsigned short* WkB = wbf + WSZ;
    const unsigned short* WvB = wbf + 2 * WSZ;
    const unsigned short* WoB = wbf + 3 * WSZ;
    const unsigned short* WpB = wbf + 4 * WSZ;
    const unsigned short* W1B = wbf + 5 * WSZ;
    const unsigned short* W2B = wbf + 5 * WSZ + FSZ;

    const float* nul = nullptr;
    float* nulf = nullptr;
    unsigned short* nulu = nullptr;

    {
        long long tot4 = (5LL * WSZ + 2LL * FSZ) / 4;
        wcvt_kernel<<<dim3((unsigned)((tot4 + 255) / 256)), dim3(256), 0, stream>>>(
            Wq, Wk, Wv, Wo, Wp, W1, W2, wbf);
    }
    bn_transpose_kernel<<<dim3(L / 64, Cc / 64, N), dim3(256), 0, stream>>>(
        x, n1g, n1b, n1m, n1v, hT, Cc, L);

    // grouped Q for ALL paths: Wq block-diag (path = m0/128, B k-offset m0)
    // qTall[n][l][512] = bf16((Wq_i @ h_slice_i + bq_i) * 0.125)^T
    gemm_bf<1><<<dim3(L / 128, P, N), dim3(256), 0, stream>>>(
        WqB, hT, P * dd, dd, L, Cc, (long long)L * Cc,
        bq, 0.125f, F_BIAS,
        nul, nul, nul, nul, nul, nul, nul, nul,
        nulf, 0, nul, 0, qTall, P * dd, 0, (long long)L * P * dd, dd);

    for (int i = 0; i < P; ++i) {
        const int r = ratios[i], Lk = L / r;
        const int c0 = i * dd;
        const int gx = (Lk + 127) / 128;

        pool_bn_t_kernel<<<dim3(Lk / 64, 2, N), dim3(256), 0, stream>>>(
            x, n1g, n1b, n1m, n1v, xa0T, Cc, L, c0, r, Lk);

        // xabT = bf16(doubleBN(Wp @ xa0))^T
        gemm_bf<1><<<dim3(gx, 1, N), dim3(256), 0, stream>>>(
            WpB + (size_t)i * dd * dd, xa0T, dd, dd, Lk, dd, (long long)Lk * dd,
            nul, 1.f, F_DBN,
            agg + c0, agb + c0, agm + c0, agv + c0,
            ang + c0, anb + c0, anm + c0, anv + c0,
            nulf, 0, nul, 0, xabT, dd, 0, (long long)Lk * dd, 0);

        // kT = bf16(Wk @ xa + bk)^T
        gemm_bf<1><<<dim3(gx, 1, N), dim3(256), 0, stream>>>(
            WkB + (size_t)i * dd * dd, xabT, dd, dd, Lk, dd, (long long)Lk * dd,
            bk + c0, 1.f, F_BIAS,
            nul, nul, nul, nul, nul, nul, nul, nul,
            nulf, 0, nul, 0, kTb, dd, 0, (long long)Lk * dd, 0);

        // vN = bf16(Wv @ xa + bv) natural
        gemm_bf<2><<<dim3(gx, 1, N), dim3(256), 0, stream>>>(
            WvB + (size_t)i * dd * dd, xabT, dd, dd, Lk, dd, (long long)Lk * dd,
            bv + c0, 1.f, F_BIAS,
            nul, nul, nul, nul, nul, nul, nul, nul,
            nulf, 0, nul, 0, vNb, 0, 0, (long long)dd * Lk, 0);

        attn_bf_kernel<<<dim3(L / 64, N * 2), dim3(256), 0, stream>>>(
            qTall + (size_t)i * dd, kTb, vNb, obT, L, Lk, P * dd);

        // out_slice = x_slice + Wo @ o + bo  (f32) ; h2T aux = bf16(bn2(out))
        gemm_bf<3><<<dim3(L / 128, 1, N), dim3(256), 0, stream>>>(
            WoB + (size_t)i * dd * dd, obT, dd, dd, L, dd, (long long)L * dd,
            bo + c0, 1.f, F_BIAS | F_RESID,
            n2g + c0, n2b + c0, n2m + c0, n2v + c0,
            nul, nul, nul, nul,
            out + (size_t)c0 * L, (long long)Cc * L,
            x + (size_t)c0 * L, (long long)Cc * L,
            h2T, Cc, c0, (long long)L * Cc, 0);
    }

    // FFN: m1T = bf16(gelu(W1 @ h2 + b1))^T   (overwrites qTall -- Q is dead)
    gemm_bf<1><<<dim3(L / 128, FF / 128, N), dim3(256), 0, stream>>>(
        W1B, h2T, FF, Cc, L, Cc, (long long)L * Cc,
        b1, 1.f, F_BIAS | F_GELU,
        nul, nul, nul, nul, nul, nul, nul, nul,
        nulf, 0, nul, 0, m1T, FF, 0, (long long)L * FF, 0);

    // out += W2 @ m1 + b2
    gemm_bf<0><<<dim3(L / 128, Cc / 128, N), dim3(256), 0, stream>>>(
        W2B, m1T, Cc, FF, L, FF, (long long)L * FF,
        b2, 1.f, F_BIAS | F_RESID,
        nul, nul, nul, nul, nul, nul, nul, nul,
        out, (long long)Cc * L, out, (long long)Cc * L,
        nulu, 0, 0, 0, 0);
}

// Round 7
// 991.420 us; speedup vs baseline: 6.2828x; 1.0025x over previous
//
#include <hip/hip_runtime.h>
#include <math.h>

#define EPS 1e-5f

#define F_BIAS  1
#define F_DBN   2
#define F_GELU  4
#define F_RESID 8

typedef __attribute__((ext_vector_type(8))) __bf16 bf16x8;
typedef __attribute__((ext_vector_type(4))) float f32x4;
typedef __attribute__((ext_vector_type(8))) unsigned short u16x8;

__device__ __forceinline__ unsigned int pack2bf(float a, float b) {
    unsigned short ua = __builtin_bit_cast(unsigned short, (__bf16)a);
    unsigned short ub = __builtin_bit_cast(unsigned short, (__bf16)b);
    return (unsigned int)ua | ((unsigned int)ub << 16);
}

// async global->LDS, 16B per lane; dst wave-uniform, src per-lane
__device__ __forceinline__ void gload_lds16(const unsigned short* g, unsigned short* l) {
    __builtin_amdgcn_global_load_lds(
        (const __attribute__((address_space(1))) unsigned int*)g,
        (__attribute__((address_space(3))) unsigned int*)l,
        16, 0, 0);
}

// ---------------------------------------------------------------------------
// Convert all weights fp32 -> bf16 into one ws region
// ---------------------------------------------------------------------------
__global__ __launch_bounds__(256) void wcvt_kernel(
    const float* __restrict__ Wq, const float* __restrict__ Wk,
    const float* __restrict__ Wv, const float* __restrict__ Wo,
    const float* __restrict__ Wp, const float* __restrict__ W1,
    const float* __restrict__ W2, unsigned short* __restrict__ dst)
{
    const int WSZ = 65536;           // 4*128*128
    const int FSZ = 1048576;         // 2048*512
    int i4 = blockIdx.x * blockDim.x + threadIdx.x;
    long long i = (long long)i4 * 4;
    const long long total = 5LL * WSZ + 2LL * FSZ;
    if (i >= total) return;
    #pragma unroll
    for (int j = 0; j < 4; ++j) {
        long long idx = i + j;
        float v;
        if      (idx < WSZ)            v = Wq[idx];
        else if (idx < 2 * WSZ)        v = Wk[idx - WSZ];
        else if (idx < 3 * WSZ)        v = Wv[idx - 2 * WSZ];
        else if (idx < 4 * WSZ)        v = Wo[idx - 3 * WSZ];
        else if (idx < 5 * WSZ)        v = Wp[idx - 4 * WSZ];
        else if (idx < 5 * WSZ + FSZ)  v = W1[idx - 5 * WSZ];
        else                           v = W2[idx - 5 * WSZ - FSZ];
        dst[idx] = __builtin_bit_cast(unsigned short, (__bf16)v);
    }
}

// ---------------------------------------------------------------------------
// hT = bf16(bn1(x)) transposed: x (N,C,L) f32 -> hT (N,L,C) bf16
// ---------------------------------------------------------------------------
__global__ __launch_bounds__(256) void bn_transpose_kernel(
    const float* __restrict__ x,
    const float* __restrict__ g, const float* __restrict__ b,
    const float* __restrict__ bm, const float* __restrict__ bvv,
    unsigned short* __restrict__ hT, int C, int L)
{
    __shared__ float ps[64][65];
    const int l0 = blockIdx.x * 64, ct = blockIdx.y, n = blockIdx.z;
    const int tid = threadIdx.x;
    const int c = tid >> 2, q = tid & 3;
    const int cg = ct * 64 + c;
    float inv = g[cg] * rsqrtf(bvv[cg] + EPS);
    float add = b[cg] - bm[cg] * inv;
    const float* xp = x + ((size_t)n * C + cg) * L + l0 + q * 16;
    #pragma unroll
    for (int s = 0; s < 4; ++s) {
        float4 vv = *(const float4*)&xp[s * 4];
        ps[c][q * 16 + s * 4 + 0] = fmaf(vv.x, inv, add);
        ps[c][q * 16 + s * 4 + 1] = fmaf(vv.y, inv, add);
        ps[c][q * 16 + s * 4 + 2] = fmaf(vv.z, inv, add);
        ps[c][q * 16 + s * 4 + 3] = fmaf(vv.w, inv, add);
    }
    __syncthreads();
    #pragma unroll
    for (int j = 0; j < 2; ++j) {
        int row = (tid >> 3) + 32 * j;
        int cc0 = (tid & 7) * 8;
        unsigned int w0 = pack2bf(ps[cc0 + 0][row], ps[cc0 + 1][row]);
        unsigned int w1 = pack2bf(ps[cc0 + 2][row], ps[cc0 + 3][row]);
        unsigned int w2 = pack2bf(ps[cc0 + 4][row], ps[cc0 + 5][row]);
        unsigned int w3 = pack2bf(ps[cc0 + 6][row], ps[cc0 + 7][row]);
        uint4 wv = make_uint4(w0, w1, w2, w3);
        *(uint4*)&hT[((size_t)n * L + l0 + row) * C + ct * 64 + cc0] = wv;
    }
}

// ---------------------------------------------------------------------------
// Pool with fused BN1, transposed bf16 out: xa0T[n][lk][c(0..127)]
// ---------------------------------------------------------------------------
__global__ __launch_bounds__(256) void pool_bn_t_kernel(
    const float* __restrict__ x,
    const float* __restrict__ g, const float* __restrict__ b,
    const float* __restrict__ bm, const float* __restrict__ bvv,
    unsigned short* __restrict__ xa0T,
    int C, int L, int c0, int r, int Lk)
{
    __shared__ float ps[64][65];
    const int lk0 = blockIdx.x * 64, ct = blockIdx.y, n = blockIdx.z;
    const int tid = threadIdx.x;
    const int c = tid >> 2, q = tid & 3;
    const int cg = c0 + ct * 64 + c;
    float inv = g[cg] * rsqrtf(bvv[cg] + EPS);
    float add = b[cg] - bm[cg] * inv;
    const float* xp = x + ((size_t)n * C + cg) * L;
    float rinv = 1.0f / (float)r;
    #pragma unroll
    for (int s = 0; s < 16; ++s) {
        int lk = q * 16 + s;
        const float* base = xp + (size_t)(lk0 + lk) * r;
        float sum = 0.f, mx = -INFINITY;
        for (int j = 0; j < r; j += 2) {
            float2 vv = *(const float2*)&base[j];
            float t0 = fmaf(vv.x, inv, add);
            float t1 = fmaf(vv.y, inv, add);
            sum += t0 + t1;
            mx = fmaxf(mx, fmaxf(t0, t1));
        }
        ps[c][lk] = sum * rinv + mx;
    }
    __syncthreads();
    #pragma unroll
    for (int j = 0; j < 2; ++j) {
        int row = (tid >> 3) + 32 * j;
        int cc0 = (tid & 7) * 8;
        unsigned int w0 = pack2bf(ps[cc0 + 0][row], ps[cc0 + 1][row]);
        unsigned int w1 = pack2bf(ps[cc0 + 2][row], ps[cc0 + 3][row]);
        unsigned int w2 = pack2bf(ps[cc0 + 4][row], ps[cc0 + 5][row]);
        unsigned int w3 = pack2bf(ps[cc0 + 6][row], ps[cc0 + 7][row]);
        *(uint4*)&xa0T[((size_t)n * Lk + lk0 + row) * 128 + ct * 64 + cc0] =
            make_uint4(w0, w1, w2, w3);
    }
}

// ---------------------------------------------------------------------------
// bf16 MFMA GEMM, k-contiguous bf16 operands, global_load_lds staging,
// 2-buffer pipeline with COUNTED vmcnt + raw s_barrier (T4 recipe):
//   prologue STAGE(0),STAGE(1);
//   loop { vmcnt(4); s_barrier; MFMA(cur); s_barrier; STAGE(cur,t+2) }
//   tail  { vmcnt(0); s_barrier; MFMA }
// (__syncthreads would drain vmcnt(0) -- that was round-6's dead pipeline.)
// Blocks are XCD-swizzled (bijective m204) so each XCD's L2 keeps one
// contiguous chunk of B-panels (FFN: one batch per XCD).
// A: [M][K] bf16. BT: [Npos][ldBT] bf16. Tile 128x128, BK=32, 4 waves (2x2).
// gKoff: per-m-block B column offset (block-diagonal grouped GEMM).
// OMODE: 0 = f32 natural out (+resid)
//        1 = bf16 transposed out [p][ldT] at col offset moff
//        2 = bf16 natural out [m][Npos]
//        3 = f32 natural out (+resid) AND bf16T aux with BN (g1 params)
// ---------------------------------------------------------------------------
template<int OMODE>
__global__ __launch_bounds__(256) void gemm_bf(
    const unsigned short* __restrict__ A, const unsigned short* __restrict__ BT,
    int M, int K, int Npos, int ldBT, long long strideBT,
    const float* __restrict__ bias, float oscale, int flags,
    const float* __restrict__ g1, const float* __restrict__ b1p,
    const float* __restrict__ m1p, const float* __restrict__ v1p,
    const float* __restrict__ g2, const float* __restrict__ b2p,
    const float* __restrict__ m2p, const float* __restrict__ v2p,
    float* __restrict__ outN, long long strideN,
    const float* __restrict__ resid, long long strideR,
    unsigned short* __restrict__ outT, int ldT, int moff, long long strideT,
    int gKoff)
{
    __shared__ __align__(16) unsigned short As[2][128][32];
    __shared__ __align__(16) unsigned short Bs[2][128][32];

    const int tid = threadIdx.x;

    // ---- bijective XCD-chunked block swizzle (m204) ----
    const int gdx = gridDim.x, gdy = gridDim.y;
    const int nwg = gdx * gdy * gridDim.z;
    int bid = blockIdx.x + gdx * (blockIdx.y + gdy * blockIdx.z);
    {
        int q = nwg >> 3, rr = nwg & 7;
        int xcd = bid & 7, idx = bid >> 3;
        bid = (xcd < rr ? xcd * (q + 1) : rr * (q + 1) + (xcd - rr) * q) + idx;
    }
    const int bx = bid % gdx;
    const int by = (bid / gdx) % gdy;
    const int bz = bid / (gdx * gdy);

    const int m0 = by * 128;
    const int p0 = bx * 128;
    const unsigned short* Bn = BT + (size_t)bz * strideBT
                              + (size_t)(m0 >> 7) * gKoff;

    const int wave = tid >> 6;
    const int lane = tid & 63;
    const int qcol = lane & 15;
    const int hi   = lane >> 4;
    const int wr   = wave >> 1;
    const int wc   = wave & 1;

    // staging roles: wave covers 32 rows (2 DMA x 16 rows);
    // lane l sources row +l/4, k-seg (l%4)*8 u16 (16B)
    const int lrow = lane >> 2;
    const int lseg = (lane & 3) * 8;

    auto STAGE = [&](int b, int t) {   // 4 vm-ops per wave
        const int k0 = t * 32;
        #pragma unroll
        for (int j = 0; j < 2; ++j) {
            int row = wave * 32 + j * 16 + lrow;
            gload_lds16(&A[(size_t)(m0 + row) * K + k0 + lseg],
                        &As[b][wave * 32 + j * 16][0]);
        }
        #pragma unroll
        for (int j = 0; j < 2; ++j) {
            int row = wave * 32 + j * 16 + lrow;
            int prow = p0 + row; if (prow > Npos - 1) prow = Npos - 1;
            gload_lds16(&Bn[(size_t)prow * ldBT + k0 + lseg],
                        &Bs[b][wave * 32 + j * 16][0]);
        }
    };

    f32x4 acc[4][4] = {};
    const int nt = K >> 5;              // >= 4 for all our shapes

    STAGE(0, 0);
    STAGE(1, 1);                         // 8 vm-ops in flight per wave

    auto MFMA_STEP = [&](int b) {
        bf16x8 af[4], bfr[4];
        #pragma unroll
        for (int mi = 0; mi < 4; ++mi)
            af[mi] = *(const bf16x8*)&As[b][wr * 64 + mi * 16 + qcol][hi * 8];
        #pragma unroll
        for (int ni = 0; ni < 4; ++ni)
            bfr[ni] = *(const bf16x8*)&Bs[b][wc * 64 + ni * 16 + qcol][hi * 8];
        #pragma unroll
        for (int mi = 0; mi < 4; ++mi)
            #pragma unroll
            for (int ni = 0; ni < 4; ++ni)
                acc[mi][ni] = __builtin_amdgcn_mfma_f32_16x16x32_bf16(
                    af[mi], bfr[ni], acc[mi][ni], 0, 0, 0);
    };

    int cur = 0;
    for (int t = 0; t < nt - 1; ++t) {
        // own oldest 4 (buf cur) landed; barrier => ALL waves' buf-cur landed
        asm volatile("s_waitcnt vmcnt(4)" ::: "memory");
        __builtin_amdgcn_s_barrier();
        MFMA_STEP(cur);
        __builtin_amdgcn_s_barrier();    // all waves done reading buf cur
        if (t + 2 < nt) STAGE(cur, t + 2);
        cur ^= 1;
    }
    asm volatile("s_waitcnt vmcnt(0)" ::: "memory");
    __builtin_amdgcn_s_barrier();
    MFMA_STEP(cur);

    float* Cn = outN + (size_t)bz * strideN;
    const float* Rn = resid + (size_t)bz * strideR;
    unsigned short* Tn = outT + (size_t)bz * strideT;

    #pragma unroll
    for (int mi = 0; mi < 4; ++mi) {
        const int mb = m0 + wr * 64 + mi * 16 + hi * 4;   // first of 4 rows
        float4 bv4 = make_float4(0.f, 0.f, 0.f, 0.f);
        if (flags & F_BIAS) bv4 = *(const float4*)&bias[mb];
        float s1[4], t1[4];
        if ((flags & F_DBN) || OMODE == 3) {
            float4 gg = *(const float4*)&g1[mb];
            float4 bb = *(const float4*)&b1p[mb];
            float4 mm = *(const float4*)&m1p[mb];
            float4 vv = *(const float4*)&v1p[mb];
            float gga[4] = {gg.x, gg.y, gg.z, gg.w};
            float bba[4] = {bb.x, bb.y, bb.z, bb.w};
            float mma[4] = {mm.x, mm.y, mm.z, mm.w};
            float vva[4] = {vv.x, vv.y, vv.z, vv.w};
            #pragma unroll
            for (int r2 = 0; r2 < 4; ++r2) {
                float iv = gga[r2] * rsqrtf(vva[r2] + EPS);
                s1[r2] = iv; t1[r2] = bba[r2] - mma[r2] * iv;
            }
        }
        float s2[4], t2[4];
        if (flags & F_DBN) {
            float4 gg = *(const float4*)&g2[mb];
            float4 bb = *(const float4*)&b2p[mb];
            float4 mm = *(const float4*)&m2p[mb];
            float4 vv = *(const float4*)&v2p[mb];
            float gga[4] = {gg.x, gg.y, gg.z, gg.w};
            float bba[4] = {bb.x, bb.y, bb.z, bb.w};
            float mma[4] = {mm.x, mm.y, mm.z, mm.w};
            float vva[4] = {vv.x, vv.y, vv.z, vv.w};
            #pragma unroll
            for (int r2 = 0; r2 < 4; ++r2) {
                float iv = gga[r2] * rsqrtf(vva[r2] + EPS);
                s2[r2] = iv; t2[r2] = bba[r2] - mma[r2] * iv;
            }
        }
        const float ba[4] = {bv4.x, bv4.y, bv4.z, bv4.w};
        #pragma unroll
        for (int ni = 0; ni < 4; ++ni) {
            const int cp = p0 + wc * 64 + ni * 16 + qcol;
            if (cp >= Npos) continue;
            float vals[4];
            #pragma unroll
            for (int r2 = 0; r2 < 4; ++r2) {
                float val = (acc[mi][ni][r2] + ba[r2]) * oscale;
                if (flags & F_DBN) {
                    val = fmaf(val, s1[r2], t1[r2]);
                    val = fmaf(val, s2[r2], t2[r2]);
                }
                if (flags & F_GELU) {
                    float u = val;
                    float z = 0.7978845608028654f * (u + 0.044715f * u * u * u);
                    float e = __expf(2.f * z);
                    val = 0.5f * u * (1.f + (1.f - 2.f / (e + 1.f)));
                }
                vals[r2] = val;
            }
            if (OMODE == 0 || OMODE == 3) {
                #pragma unroll
                for (int r2 = 0; r2 < 4; ++r2) {
                    size_t off = (size_t)(mb + r2) * Npos + cp;
                    float v = vals[r2];
                    if (flags & F_RESID) v += Rn[off];
                    Cn[off] = v;
                    vals[r2] = v;
                }
            }
            if (OMODE == 1) {
                *(uint2*)&Tn[(size_t)cp * ldT + moff + mb] =
                    make_uint2(pack2bf(vals[0], vals[1]), pack2bf(vals[2], vals[3]));
            }
            if (OMODE == 2) {
                #pragma unroll
                for (int r2 = 0; r2 < 4; ++r2)
                    Tn[(size_t)(mb + r2) * Npos + cp] =
                        __builtin_bit_cast(unsigned short, (__bf16)vals[r2]);
            }
            if (OMODE == 3) {
                float a0 = fmaf(vals[0], s1[0], t1[0]);
                float a1 = fmaf(vals[1], s1[1], t1[1]);
                float a2 = fmaf(vals[2], s1[2], t1[2]);
                float a3 = fmaf(vals[3], s1[3], t1[3]);
                *(uint2*)&Tn[(size_t)cp * ldT + moff + mb] =
                    make_uint2(pack2bf(a0, a1), pack2bf(a2, a3));
            }
        }
    }
}

// ---------------------------------------------------------------------------
// Flash attention, all-bf16 operands loaded fragment-direct from global.
// qT rows have stride qld (grouped-Q buffer). kT: [n][pos][128]. vN: [n][128][Lk].
// ---------------------------------------------------------------------------
__global__ __launch_bounds__(256) void attn_bf_kernel(
    const unsigned short* __restrict__ qT, const unsigned short* __restrict__ kT,
    const unsigned short* __restrict__ vN, unsigned short* __restrict__ obT,
    int L, int Lk, int qld)
{
    const int l0 = blockIdx.x * 64;
    const int nh = blockIdx.y;
    const int n = nh >> 1, h = nh & 1;
    const unsigned short* qn = qT + (size_t)n * L * qld + h * 64;
    const unsigned short* kn = kT + (size_t)n * Lk * 128 + h * 64;
    const unsigned short* vn = vN + ((size_t)n * 128 + h * 64) * Lk;
    unsigned short*       on = obT + (size_t)n * L * 128 + h * 64;

    __shared__ __align__(16) unsigned short Ps[4][16][72];

    const int tid = threadIdx.x;
    const int wave = tid >> 6;
    const int lane = tid & 63;
    const int qcol = lane & 15;
    const int hi   = lane >> 4;
    const int ql   = wave * 16 + qcol;

    bf16x8 qf0 = *(const bf16x8*)&qn[(size_t)(l0 + ql) * qld + hi * 8];
    bf16x8 qf1 = *(const bf16x8*)&qn[(size_t)(l0 + ql) * qld + 32 + hi * 8];

    f32x4 o_acc[4] = {};
    float mrow = -INFINITY, lrow = 0.f;

    for (int mc = 0; mc < Lk; mc += 64) {
        f32x4 sacc[4];
        #pragma unroll
        for (int kt = 0; kt < 4; ++kt) {
            const size_t kr = (size_t)(mc + kt * 16 + qcol) * 128;
            bf16x8 k0 = *(const bf16x8*)&kn[kr + hi * 8];
            bf16x8 k1 = *(const bf16x8*)&kn[kr + 32 + hi * 8];
            f32x4 a = {};
            a = __builtin_amdgcn_mfma_f32_16x16x32_bf16(k0, qf0, a, 0, 0, 0);
            a = __builtin_amdgcn_mfma_f32_16x16x32_bf16(k1, qf1, a, 0, 0, 0);
            sacc[kt] = a;
        }

        float cm = -INFINITY;
        #pragma unroll
        for (int kt = 0; kt < 4; ++kt)
            #pragma unroll
            for (int r2 = 0; r2 < 4; ++r2) cm = fmaxf(cm, sacc[kt][r2]);
        cm = fmaxf(cm, __shfl_xor(cm, 16));
        cm = fmaxf(cm, __shfl_xor(cm, 32));
        float nm = fmaxf(mrow, cm);
        float alpha = __expf(mrow - nm);
        float csum = 0.f;
        unsigned int pw[4][2];
        #pragma unroll
        for (int kt = 0; kt < 4; ++kt) {
            float p0 = __expf(sacc[kt][0] - nm);
            float p1 = __expf(sacc[kt][1] - nm);
            float p2 = __expf(sacc[kt][2] - nm);
            float p3 = __expf(sacc[kt][3] - nm);
            csum += (p0 + p1) + (p2 + p3);
            pw[kt][0] = pack2bf(p0, p1);
            pw[kt][1] = pack2bf(p2, p3);
        }
        csum += __shfl_xor(csum, 16);
        csum += __shfl_xor(csum, 32);
        lrow = lrow * alpha + csum;
        mrow = nm;

        #pragma unroll
        for (int kt = 0; kt < 4; ++kt)
            *(uint2*)&Ps[wave][qcol][kt * 16 + hi * 4] =
                make_uint2(pw[kt][0], pw[kt][1]);

        #pragma unroll
        for (int et = 0; et < 4; ++et)
            #pragma unroll
            for (int r2 = 0; r2 < 4; ++r2) o_acc[et][r2] *= alpha;

        bf16x8 pf0 = *(const bf16x8*)&Ps[wave][qcol][hi * 8];
        bf16x8 pf1 = *(const bf16x8*)&Ps[wave][qcol][hi * 8 + 32];
        #pragma unroll
        for (int et = 0; et < 4; ++et) {
            const size_t vr = (size_t)(et * 16 + qcol) * Lk + mc;
            bf16x8 v0 = *(const bf16x8*)&vn[vr + hi * 8];
            bf16x8 v1 = *(const bf16x8*)&vn[vr + 32 + hi * 8];
            o_acc[et] = __builtin_amdgcn_mfma_f32_16x16x32_bf16(v0, pf0, o_acc[et], 0, 0, 0);
            o_acc[et] = __builtin_amdgcn_mfma_f32_16x16x32_bf16(v1, pf1, o_acc[et], 0, 0, 0);
        }
    }

    float invl = 1.f / lrow;
    #pragma unroll
    for (int et = 0; et < 4; ++et) {
        float a0 = o_acc[et][0] * invl, a1 = o_acc[et][1] * invl;
        float a2 = o_acc[et][2] * invl, a3 = o_acc[et][3] * invl;
        *(uint2*)&on[(size_t)(l0 + ql) * 128 + et * 16 + hi * 4] =
            make_uint2(pack2bf(a0, a1), pack2bf(a2, a3));
    }
}

// ---------------------------------------------------------------------------
extern "C" void kernel_launch(void* const* d_in, const int* in_sizes, int n_in,
                              void* d_out, int out_size, void* d_ws, size_t ws_size,
                              hipStream_t stream)
{
    const float* x   = (const float*)d_in[0];
    const float* n1g = (const float*)d_in[1];
    const float* n1b = (const float*)d_in[2];
    const float* n1m = (const float*)d_in[3];
    const float* n1v = (const float*)d_in[4];
    const float* n2g = (const float*)d_in[5];
    const float* n2b = (const float*)d_in[6];
    const float* n2m = (const float*)d_in[7];
    const float* n2v = (const float*)d_in[8];
    const float* Wq  = (const float*)d_in[9];
    const float* Wk  = (const float*)d_in[10];
    const float* Wv  = (const float*)d_in[11];
    const float* Wo  = (const float*)d_in[12];
    const float* Wp  = (const float*)d_in[13];
    const float* bq  = (const float*)d_in[14];
    const float* bk  = (const float*)d_in[15];
    const float* bv  = (const float*)d_in[16];
    const float* bo  = (const float*)d_in[17];
    const float* agg = (const float*)d_in[18];
    const float* agb = (const float*)d_in[19];
    const float* agm = (const float*)d_in[20];
    const float* agv = (const float*)d_in[21];
    const float* ang = (const float*)d_in[22];
    const float* anb = (const float*)d_in[23];
    const float* anm = (const float*)d_in[24];
    const float* anv = (const float*)d_in[25];
    const float* W1  = (const float*)d_in[26];
    const float* b1  = (const float*)d_in[27];
    const float* W2  = (const float*)d_in[28];
    const float* b2  = (const float*)d_in[29];

    float* out = (float*)d_out;
    unsigned short* wsb = (unsigned short*)d_ws;

    const int N = 8, Cc = 512, L = 3072, P = 4, dd = 128, FF = 2048;
    const int ratios[4] = {2, 4, 8, 16};
    const int WSZ = 65536, FSZ = 1048576;

    // ws layout (u16 elems); qTall aliases m1T (dead before FFN writes m1T)
    unsigned short* wbf   = wsb;
    unsigned short* hT    = wbf   + 5 * WSZ + 2 * FSZ;
    unsigned short* qTold = hT    + (size_t)N * L * Cc;
    unsigned short* obT   = qTold + (size_t)N * L * dd;
    unsigned short* xa0T  = obT   + (size_t)N * L * dd;
    unsigned short* xabT  = xa0T  + (size_t)N * (L / 2) * dd;
    unsigned short* kTb   = xabT  + (size_t)N * (L / 2) * dd;
    unsigned short* vNb   = kTb   + (size_t)N * (L / 2) * dd;
    unsigned short* h2T   = vNb   + (size_t)N * (L / 2) * dd;
    unsigned short* m1T   = h2T   + (size_t)N * L * Cc;
    unsigned short* qTall = m1T;   // [N][L][512]

    const unsigned short* WqB = wbf;
    const unsigned short* WkB = wbf + WSZ;
    const unsigned short* WvB = wbf + 2 * WSZ;
    const unsigned short* WoB = wbf + 3 * WSZ;
    const unsigned short* WpB = wbf + 4 * WSZ;
    const unsigned short* W1B = wbf + 5 * WSZ;
    const unsigned short* W2B = wbf + 5 * WSZ + FSZ;

    const float* nul = nullptr;
    float* nulf = nullptr;
    unsigned short* nulu = nullptr;

    {
        long long tot4 = (5LL * WSZ + 2LL * FSZ) / 4;
        wcvt_kernel<<<dim3((unsigned)((tot4 + 255) / 256)), dim3(256), 0, stream>>>(
            Wq, Wk, Wv, Wo, Wp, W1, W2, wbf);
    }
    bn_transpose_kernel<<<dim3(L / 64, Cc / 64, N), dim3(256), 0, stream>>>(
        x, n1g, n1b, n1m, n1v, hT, Cc, L);

    // grouped Q for ALL paths: Wq block-diag (path = m0/128, B k-offset m0)
    gemm_bf<1><<<dim3(L / 128, P, N), dim3(256), 0, stream>>>(
        WqB, hT, P * dd, dd, L, Cc, (long long)L * Cc,
        bq, 0.125f, F_BIAS,
        nul, nul, nul, nul, nul, nul, nul, nul,
        nulf, 0, nul, 0, qTall, P * dd, 0, (long long)L * P * dd, dd);

    for (int i = 0; i < P; ++i) {
        const int r = ratios[i], Lk = L / r;
        const int c0 = i * dd;
        const int gx = (Lk + 127) / 128;

        pool_bn_t_kernel<<<dim3(Lk / 64, 2, N), dim3(256), 0, stream>>>(
            x, n1g, n1b, n1m, n1v, xa0T, Cc, L, c0, r, Lk);

        // xabT = bf16(doubleBN(Wp @ xa0))^T
        gemm_bf<1><<<dim3(gx, 1, N), dim3(256), 0, stream>>>(
            WpB + (size_t)i * dd * dd, xa0T, dd, dd, Lk, dd, (long long)Lk * dd,
            nul, 1.f, F_DBN,
            agg + c0, agb + c0, agm + c0, agv + c0,
            ang + c0, anb + c0, anm + c0, anv + c0,
            nulf, 0, nul, 0, xabT, dd, 0, (long long)Lk * dd, 0);

        // kT = bf16(Wk @ xa + bk)^T
        gemm_bf<1><<<dim3(gx, 1, N), dim3(256), 0, stream>>>(
            WkB + (size_t)i * dd * dd, xabT, dd, dd, Lk, dd, (long long)Lk * dd,
            bk + c0, 1.f, F_BIAS,
            nul, nul, nul, nul, nul, nul, nul, nul,
            nulf, 0, nul, 0, kTb, dd, 0, (long long)Lk * dd, 0);

        // vN = bf16(Wv @ xa + bv) natural
        gemm_bf<2><<<dim3(gx, 1, N), dim3(256), 0, stream>>>(
            WvB + (size_t)i * dd * dd, xabT, dd, dd, Lk, dd, (long long)Lk * dd,
            bv + c0, 1.f, F_BIAS,
            nul, nul, nul, nul, nul, nul, nul, nul,
            nulf, 0, nul, 0, vNb, 0, 0, (long long)dd * Lk, 0);

        attn_bf_kernel<<<dim3(L / 64, N * 2), dim3(256), 0, stream>>>(
            qTall + (size_t)i * dd, kTb, vNb, obT, L, Lk, P * dd);

        // out_slice = x_slice + Wo @ o + bo  (f32) ; h2T aux = bf16(bn2(out))
        gemm_bf<3><<<dim3(L / 128, 1, N), dim3(256), 0, stream>>>(
            WoB + (size_t)i * dd * dd, obT, dd, dd, L, dd, (long long)L * dd,
            bo + c0, 1.f, F_BIAS | F_RESID,
            n2g + c0, n2b + c0, n2m + c0, n2v + c0,
            nul, nul, nul, nul,
            out + (size_t)c0 * L, (long long)Cc * L,
            x + (size_t)c0 * L, (long long)Cc * L,
            h2T, Cc, c0, (long long)L * Cc, 0);
    }

    // FFN: m1T = bf16(gelu(W1 @ h2 + b1))^T   (overwrites qTall -- Q is dead)
    gemm_bf<1><<<dim3(L / 128, FF / 128, N), dim3(256), 0, stream>>>(
        W1B, h2T, FF, Cc, L, Cc, (long long)L * Cc,
        b1, 1.f, F_BIAS | F_GELU,
        nul, nul, nul, nul, nul, nul, nul, nul,
        nulf, 0, nul, 0, m1T, FF, 0, (long long)L * FF, 0);

    // out += W2 @ m1 + b2
    gemm_bf<0><<<dim3(L / 128, Cc / 128, N), dim3(256), 0, stream>>>(
        W2B, m1T, Cc, FF, L, FF, (long long)L * FF,
        b2, 1.f, F_BIAS | F_RESID,
        nul, nul, nul, nul, nul, nul, nul, nul,
        out, (long long)Cc * L, out, (long long)Cc * L,
        nulu, 0, 0, 0, 0);
}

// Round 8
// 694.752 us; speedup vs baseline: 8.9656x; 1.4270x over previous
//
#include <hip/hip_runtime.h>
#include <math.h>

#define EPS 1e-5f

#define F_BIAS  1
#define F_DBN   2
#define F_GELU  4
#define F_RESID 8

typedef __attribute__((ext_vector_type(8))) __bf16 bf16x8;
typedef __attribute__((ext_vector_type(4))) float f32x4;
typedef __attribute__((ext_vector_type(8))) unsigned short u16x8;

__device__ __forceinline__ unsigned int pack2bf(float a, float b) {
    unsigned short ua = __builtin_bit_cast(unsigned short, (__bf16)a);
    unsigned short ub = __builtin_bit_cast(unsigned short, (__bf16)b);
    return (unsigned int)ua | ((unsigned int)ub << 16);
}

__device__ __forceinline__ void gload_lds16(const unsigned short* g, unsigned short* l) {
    __builtin_amdgcn_global_load_lds(
        (const __attribute__((address_space(1))) unsigned int*)g,
        (__attribute__((address_space(3))) unsigned int*)l,
        16, 0, 0);
}

// cheap tanh-gelu: u*sigmoid(2z), 2z = u*(1.5957691 + 0.07135481*u^2)
__device__ __forceinline__ float gelu_f(float u) {
    float s = u * u;
    float w = u * fmaf(s, 0.0713548162726f, 1.59576912161f);
    float e = __expf(-w);
    return u * __builtin_amdgcn_rcpf(1.f + e);
}

// path constants: ratios {2,4,8,16}
__device__ __constant__ int c_LKS[4]  = {1536, 768, 384, 192};
// u16-element offsets into the *_all buffers: N*128*cumLk, cumLk={0,1536,2304,2688}
__device__ __constant__ int c_OFFB[4] = {0, 1572864, 2359296, 2752512};

// ---------------------------------------------------------------------------
// weights fp32 -> bf16
// ---------------------------------------------------------------------------
__global__ __launch_bounds__(256) void wcvt_kernel(
    const float* __restrict__ Wq, const float* __restrict__ Wk,
    const float* __restrict__ Wv, const float* __restrict__ Wo,
    const float* __restrict__ Wp, const float* __restrict__ W1,
    const float* __restrict__ W2, unsigned short* __restrict__ dst)
{
    const int WSZ = 65536;
    const int FSZ = 1048576;
    int i4 = blockIdx.x * blockDim.x + threadIdx.x;
    long long i = (long long)i4 * 4;
    const long long total = 5LL * WSZ + 2LL * FSZ;
    if (i >= total) return;
    #pragma unroll
    for (int j = 0; j < 4; ++j) {
        long long idx = i + j;
        float v;
        if      (idx < WSZ)            v = Wq[idx];
        else if (idx < 2 * WSZ)        v = Wk[idx - WSZ];
        else if (idx < 3 * WSZ)        v = Wv[idx - 2 * WSZ];
        else if (idx < 4 * WSZ)        v = Wo[idx - 3 * WSZ];
        else if (idx < 5 * WSZ)        v = Wp[idx - 4 * WSZ];
        else if (idx < 5 * WSZ + FSZ)  v = W1[idx - 5 * WSZ];
        else                           v = W2[idx - 5 * WSZ - FSZ];
        dst[idx] = __builtin_bit_cast(unsigned short, (__bf16)v);
    }
}

// ---------------------------------------------------------------------------
// hT = bf16(bn1(x))^T : x (N,C,L) f32 -> hT (N,L,C) bf16
// ---------------------------------------------------------------------------
__global__ __launch_bounds__(256) void bn_transpose_kernel(
    const float* __restrict__ x,
    const float* __restrict__ g, const float* __restrict__ b,
    const float* __restrict__ bm, const float* __restrict__ bvv,
    unsigned short* __restrict__ hT, int C, int L)
{
    __shared__ float ps[64][65];
    const int l0 = blockIdx.x * 64, ct = blockIdx.y, n = blockIdx.z;
    const int tid = threadIdx.x;
    const int c = tid >> 2, q = tid & 3;
    const int cg = ct * 64 + c;
    float inv = g[cg] * rsqrtf(bvv[cg] + EPS);
    float add = b[cg] - bm[cg] * inv;
    const float* xp = x + ((size_t)n * C + cg) * L + l0 + q * 16;
    #pragma unroll
    for (int s = 0; s < 4; ++s) {
        float4 vv = *(const float4*)&xp[s * 4];
        ps[c][q * 16 + s * 4 + 0] = fmaf(vv.x, inv, add);
        ps[c][q * 16 + s * 4 + 1] = fmaf(vv.y, inv, add);
        ps[c][q * 16 + s * 4 + 2] = fmaf(vv.z, inv, add);
        ps[c][q * 16 + s * 4 + 3] = fmaf(vv.w, inv, add);
    }
    __syncthreads();
    #pragma unroll
    for (int j = 0; j < 2; ++j) {
        int row = (tid >> 3) + 32 * j;
        int cc0 = (tid & 7) * 8;
        unsigned int w0 = pack2bf(ps[cc0 + 0][row], ps[cc0 + 1][row]);
        unsigned int w1 = pack2bf(ps[cc0 + 2][row], ps[cc0 + 3][row]);
        unsigned int w2 = pack2bf(ps[cc0 + 4][row], ps[cc0 + 5][row]);
        unsigned int w3 = pack2bf(ps[cc0 + 6][row], ps[cc0 + 7][row]);
        *(uint4*)&hT[((size_t)n * L + l0 + row) * C + ct * 64 + cc0] =
            make_uint4(w0, w1, w2, w3);
    }
}

// ---------------------------------------------------------------------------
// Pool+BN1 for ALL paths in one dispatch: grid (24, 2, N*4)
// out: xa0T_all[p] = [n][Lk_p][128] bf16 at c_OFFB[p]
// ---------------------------------------------------------------------------
__global__ __launch_bounds__(256) void pool_bn_all_kernel(
    const float* __restrict__ x,
    const float* __restrict__ g, const float* __restrict__ b,
    const float* __restrict__ bm, const float* __restrict__ bvv,
    unsigned short* __restrict__ xa0T_all, int C, int L)
{
    const int p = blockIdx.z & 3;
    const int n = blockIdx.z >> 2;
    const int Lk = c_LKS[p];
    const int lk0 = blockIdx.x * 64;
    if (lk0 >= Lk) return;
    const int r = L / Lk;
    const int ct = blockIdx.y;
    __shared__ float ps[64][65];
    const int tid = threadIdx.x;
    const int c = tid >> 2, q = tid & 3;
    const int cg = p * 128 + ct * 64 + c;
    float inv = g[cg] * rsqrtf(bvv[cg] + EPS);
    float add = b[cg] - bm[cg] * inv;
    const float* xp = x + ((size_t)n * C + cg) * L;
    float rinv = 1.0f / (float)r;
    #pragma unroll
    for (int s = 0; s < 16; ++s) {
        int lk = q * 16 + s;
        const float* base = xp + (size_t)(lk0 + lk) * r;
        float sum = 0.f, mx = -INFINITY;
        for (int j = 0; j < r; j += 2) {
            float2 vv = *(const float2*)&base[j];
            float t0 = fmaf(vv.x, inv, add);
            float t1 = fmaf(vv.y, inv, add);
            sum += t0 + t1;
            mx = fmaxf(mx, fmaxf(t0, t1));
        }
        ps[c][lk] = sum * rinv + mx;
    }
    __syncthreads();
    unsigned short* dst = xa0T_all + c_OFFB[p];
    #pragma unroll
    for (int j = 0; j < 2; ++j) {
        int row = (tid >> 3) + 32 * j;
        int cc0 = (tid & 7) * 8;
        unsigned int w0 = pack2bf(ps[cc0 + 0][row], ps[cc0 + 1][row]);
        unsigned int w1 = pack2bf(ps[cc0 + 2][row], ps[cc0 + 3][row]);
        unsigned int w2 = pack2bf(ps[cc0 + 4][row], ps[cc0 + 5][row]);
        unsigned int w3 = pack2bf(ps[cc0 + 6][row], ps[cc0 + 7][row]);
        *(uint4*)&dst[((size_t)n * Lk + lk0 + row) * 128 + ct * 64 + cc0] =
            make_uint4(w0, w1, w2, w3);
    }
}

// ---------------------------------------------------------------------------
// bf16 MFMA GEMM, counted-vmcnt 2-buffer pipeline, hoisted addresses.
// OMODE: 0 f32 natural (+resid); 1 bf16T [p][ldT]+moff; 2 bf16 natural;
//        3 f32 natural (+resid) AND bf16T aux with BN(g1)
// ---------------------------------------------------------------------------
template<int OMODE>
__global__ __launch_bounds__(256) void gemm_bf(
    const unsigned short* __restrict__ A, const unsigned short* __restrict__ BT,
    int M, int K, int Npos, int ldBT, long long strideBT,
    const float* __restrict__ bias, float oscale, int flags,
    const float* __restrict__ g1, const float* __restrict__ b1p,
    const float* __restrict__ m1p, const float* __restrict__ v1p,
    const float* __restrict__ g2, const float* __restrict__ b2p,
    const float* __restrict__ m2p, const float* __restrict__ v2p,
    float* __restrict__ outN, long long strideN,
    const float* __restrict__ resid, long long strideR,
    unsigned short* __restrict__ outT, int ldT, int moff, long long strideT,
    int gKoff)
{
    __shared__ __align__(16) unsigned short As[2][128][32];
    __shared__ __align__(16) unsigned short Bs[2][128][32];

    const int tid = threadIdx.x;

    // bijective XCD-chunked swizzle (m204)
    const int gdx = gridDim.x, gdy = gridDim.y;
    const int nwg = gdx * gdy * gridDim.z;
    int bid = blockIdx.x + gdx * (blockIdx.y + gdy * blockIdx.z);
    {
        int q = nwg >> 3, rr = nwg & 7;
        int xcd = bid & 7, idx = bid >> 3;
        bid = (xcd < rr ? xcd * (q + 1) : rr * (q + 1) + (xcd - rr) * q) + idx;
    }
    const int bx = bid % gdx;
    const int by = (bid / gdx) % gdy;
    const int bz = bid / (gdx * gdy);

    const int m0 = by * 128;
    const int p0 = bx * 128;
    const unsigned short* Bn = BT + (size_t)bz * strideBT
                              + (size_t)(m0 >> 7) * gKoff;

    const int wave = tid >> 6;
    const int lane = tid & 63;
    const int qcol = lane & 15;
    const int hi   = lane >> 4;
    const int wr   = wave >> 1;
    const int wc   = wave & 1;
    const int lrow = lane >> 2;
    const int lseg = (lane & 3) * 8;

    // hoisted per-wave staging pointers (advance by t*32 in-loop)
    const unsigned short* aR0 = A + (size_t)(m0 + wave * 32 + lrow) * K + lseg;
    const unsigned short* aR1 = aR0 + (size_t)16 * K;
    int pr0 = p0 + wave * 32 + lrow;      if (pr0 > Npos - 1) pr0 = Npos - 1;
    int pr1 = p0 + wave * 32 + 16 + lrow; if (pr1 > Npos - 1) pr1 = Npos - 1;
    const unsigned short* bR0 = Bn + (size_t)pr0 * ldBT + lseg;
    const unsigned short* bR1 = Bn + (size_t)pr1 * ldBT + lseg;
    unsigned short* ldsA0 = &As[0][wave * 32][0];
    unsigned short* ldsA1 = &As[0][wave * 32 + 16][0];
    unsigned short* ldsB0 = &Bs[0][wave * 32][0];
    unsigned short* ldsB1 = &Bs[0][wave * 32 + 16][0];
    const int bufStride = 128 * 32;

    auto STAGE = [&](int b, int t) {   // 4 vm-ops per wave
        const int ko = t * 32;
        gload_lds16(aR0 + ko, ldsA0 + b * bufStride);
        gload_lds16(aR1 + ko, ldsA1 + b * bufStride);
        gload_lds16(bR0 + ko, ldsB0 + b * bufStride);
        gload_lds16(bR1 + ko, ldsB1 + b * bufStride);
    };

    f32x4 acc[4][4] = {};
    const int nt = K >> 5;

    STAGE(0, 0);
    STAGE(1, 1);

    auto MFMA_STEP = [&](int b) {
        bf16x8 af[4], bfr[4];
        #pragma unroll
        for (int mi = 0; mi < 4; ++mi)
            af[mi] = *(const bf16x8*)&As[b][wr * 64 + mi * 16 + qcol][hi * 8];
        #pragma unroll
        for (int ni = 0; ni < 4; ++ni)
            bfr[ni] = *(const bf16x8*)&Bs[b][wc * 64 + ni * 16 + qcol][hi * 8];
        #pragma unroll
        for (int mi = 0; mi < 4; ++mi)
            #pragma unroll
            for (int ni = 0; ni < 4; ++ni)
                acc[mi][ni] = __builtin_amdgcn_mfma_f32_16x16x32_bf16(
                    af[mi], bfr[ni], acc[mi][ni], 0, 0, 0);
    };

    int cur = 0;
    for (int t = 0; t < nt - 1; ++t) {
        asm volatile("s_waitcnt vmcnt(4)" ::: "memory");
        __builtin_amdgcn_s_barrier();
        MFMA_STEP(cur);
        __builtin_amdgcn_s_barrier();
        if (t + 2 < nt) STAGE(cur, t + 2);
        cur ^= 1;
    }
    asm volatile("s_waitcnt vmcnt(0)" ::: "memory");
    __builtin_amdgcn_s_barrier();
    MFMA_STEP(cur);

    float* Cn = outN + (size_t)bz * strideN;
    const float* Rn = resid + (size_t)bz * strideR;
    unsigned short* Tn = outT + (size_t)bz * strideT;

    #pragma unroll
    for (int mi = 0; mi < 4; ++mi) {
        const int mb = m0 + wr * 64 + mi * 16 + hi * 4;
        float4 bv4 = make_float4(0.f, 0.f, 0.f, 0.f);
        if (flags & F_BIAS) bv4 = *(const float4*)&bias[mb];
        float s1[4], t1[4];
        if ((flags & F_DBN) || OMODE == 3) {
            float4 gg = *(const float4*)&g1[mb];
            float4 bb = *(const float4*)&b1p[mb];
            float4 mm = *(const float4*)&m1p[mb];
            float4 vv = *(const float4*)&v1p[mb];
            float gga[4] = {gg.x, gg.y, gg.z, gg.w};
            float bba[4] = {bb.x, bb.y, bb.z, bb.w};
            float mma[4] = {mm.x, mm.y, mm.z, mm.w};
            float vva[4] = {vv.x, vv.y, vv.z, vv.w};
            #pragma unroll
            for (int r2 = 0; r2 < 4; ++r2) {
                float iv = gga[r2] * rsqrtf(vva[r2] + EPS);
                s1[r2] = iv; t1[r2] = bba[r2] - mma[r2] * iv;
            }
        }
        float s2[4], t2[4];
        if (flags & F_DBN) {
            float4 gg = *(const float4*)&g2[mb];
            float4 bb = *(const float4*)&b2p[mb];
            float4 mm = *(const float4*)&m2p[mb];
            float4 vv = *(const float4*)&v2p[mb];
            float gga[4] = {gg.x, gg.y, gg.z, gg.w};
            float bba[4] = {bb.x, bb.y, bb.z, bb.w};
            float mma[4] = {mm.x, mm.y, mm.z, mm.w};
            float vva[4] = {vv.x, vv.y, vv.z, vv.w};
            #pragma unroll
            for (int r2 = 0; r2 < 4; ++r2) {
                float iv = gga[r2] * rsqrtf(vva[r2] + EPS);
                s2[r2] = iv; t2[r2] = bba[r2] - mma[r2] * iv;
            }
        }
        const float ba[4] = {bv4.x, bv4.y, bv4.z, bv4.w};
        #pragma unroll
        for (int ni = 0; ni < 4; ++ni) {
            const int cp = p0 + wc * 64 + ni * 16 + qcol;
            if (cp >= Npos) continue;
            float vals[4];
            #pragma unroll
            for (int r2 = 0; r2 < 4; ++r2) {
                float val = (acc[mi][ni][r2] + ba[r2]) * oscale;
                if (flags & F_DBN) {
                    val = fmaf(val, s1[r2], t1[r2]);
                    val = fmaf(val, s2[r2], t2[r2]);
                }
                if (flags & F_GELU) val = gelu_f(val);
                vals[r2] = val;
            }
            if (OMODE == 0 || OMODE == 3) {
                #pragma unroll
                for (int r2 = 0; r2 < 4; ++r2) {
                    size_t off = (size_t)(mb + r2) * Npos + cp;
                    float v = vals[r2];
                    if (flags & F_RESID) v += Rn[off];
                    Cn[off] = v;
                    vals[r2] = v;
                }
            }
            if (OMODE == 1) {
                *(uint2*)&Tn[(size_t)cp * ldT + moff + mb] =
                    make_uint2(pack2bf(vals[0], vals[1]), pack2bf(vals[2], vals[3]));
            }
            if (OMODE == 2) {
                #pragma unroll
                for (int r2 = 0; r2 < 4; ++r2)
                    Tn[(size_t)(mb + r2) * Npos + cp] =
                        __builtin_bit_cast(unsigned short, (__bf16)vals[r2]);
            }
            if (OMODE == 3) {
                float a0 = fmaf(vals[0], s1[0], t1[0]);
                float a1 = fmaf(vals[1], s1[1], t1[1]);
                float a2 = fmaf(vals[2], s1[2], t1[2]);
                float a3 = fmaf(vals[3], s1[3], t1[3]);
                *(uint2*)&Tn[(size_t)cp * ldT + moff + mb] =
                    make_uint2(pack2bf(a0, a1), pack2bf(a2, a3));
            }
        }
    }
}

// ---------------------------------------------------------------------------
// Grouped per-path GEMM (K=128, M=128 per path), all 4 paths in one dispatch.
// grid (23, MODE?2:1, 8): bx -> (path, tile) via LUT {12,6,3,2}.
// MODE 0: Wp (DBN, bf16T out xabT_all)
// MODE 1: by=0 -> Wk (bias, bf16T out kT_all); by=1 -> Wv (bias, natural vN_all)
// ---------------------------------------------------------------------------
template<int MODE>
__global__ __launch_bounds__(256) void gemm_path(
    const unsigned short* __restrict__ A0, const unsigned short* __restrict__ A1,
    const unsigned short* __restrict__ Bsrc,
    const float* __restrict__ bias0, const float* __restrict__ bias1,
    const float* __restrict__ agg, const float* __restrict__ agb,
    const float* __restrict__ agm, const float* __restrict__ agv,
    const float* __restrict__ ang, const float* __restrict__ anb,
    const float* __restrict__ anm, const float* __restrict__ anv,
    unsigned short* __restrict__ out0, unsigned short* __restrict__ out1)
{
    __shared__ __align__(16) unsigned short As[2][128][32];
    __shared__ __align__(16) unsigned short Bs[2][128][32];

    const int tid = threadIdx.x;
    const int gdx = gridDim.x, gdy = gridDim.y;
    const int nwg = gdx * gdy * gridDim.z;
    int bid = blockIdx.x + gdx * (blockIdx.y + gdy * blockIdx.z);
    {
        int q = nwg >> 3, rr = nwg & 7;
        int xcd = bid & 7, idx = bid >> 3;
        bid = (xcd < rr ? xcd * (q + 1) : rr * (q + 1) + (xcd - rr) * q) + idx;
    }
    const int bx = bid % gdx;
    const int by = (bid / gdx) % gdy;
    const int bz = bid / (gdx * gdy);

    int p, px;
    if      (bx < 12) { p = 0; px = bx; }
    else if (bx < 18) { p = 1; px = bx - 12; }
    else if (bx < 21) { p = 2; px = bx - 18; }
    else              { p = 3; px = bx - 21; }
    const int Lk = c_LKS[p];
    const int offb = c_OFFB[p];
    const int c0 = p * 128;
    const int p0 = px * 128;
    const int K = 128;

    const unsigned short* A = (MODE == 1 && by == 1 ? A1 : A0) + p * 16384;
    const unsigned short* Bn = Bsrc + offb + (size_t)bz * Lk * 128;

    const int wave = tid >> 6;
    const int lane = tid & 63;
    const int qcol = lane & 15;
    const int hi   = lane >> 4;
    const int wr   = wave >> 1;
    const int wc   = wave & 1;
    const int lrow = lane >> 2;
    const int lseg = (lane & 3) * 8;

    const unsigned short* aR0 = A + (size_t)(wave * 32 + lrow) * K + lseg;
    const unsigned short* aR1 = aR0 + (size_t)16 * K;
    int pr0 = p0 + wave * 32 + lrow;      if (pr0 > Lk - 1) pr0 = Lk - 1;
    int pr1 = p0 + wave * 32 + 16 + lrow; if (pr1 > Lk - 1) pr1 = Lk - 1;
    const unsigned short* bR0 = Bn + (size_t)pr0 * 128 + lseg;
    const unsigned short* bR1 = Bn + (size_t)pr1 * 128 + lseg;
    unsigned short* ldsA0 = &As[0][wave * 32][0];
    unsigned short* ldsA1 = &As[0][wave * 32 + 16][0];
    unsigned short* ldsB0 = &Bs[0][wave * 32][0];
    unsigned short* ldsB1 = &Bs[0][wave * 32 + 16][0];
    const int bufStride = 128 * 32;

    auto STAGE = [&](int b, int t) {
        const int ko = t * 32;
        gload_lds16(aR0 + ko, ldsA0 + b * bufStride);
        gload_lds16(aR1 + ko, ldsA1 + b * bufStride);
        gload_lds16(bR0 + ko, ldsB0 + b * bufStride);
        gload_lds16(bR1 + ko, ldsB1 + b * bufStride);
    };

    f32x4 acc[4][4] = {};
    STAGE(0, 0);
    STAGE(1, 1);

    auto MFMA_STEP = [&](int b) {
        bf16x8 af[4], bfr[4];
        #pragma unroll
        for (int mi = 0; mi < 4; ++mi)
            af[mi] = *(const bf16x8*)&As[b][wr * 64 + mi * 16 + qcol][hi * 8];
        #pragma unroll
        for (int ni = 0; ni < 4; ++ni)
            bfr[ni] = *(const bf16x8*)&Bs[b][wc * 64 + ni * 16 + qcol][hi * 8];
        #pragma unroll
        for (int mi = 0; mi < 4; ++mi)
            #pragma unroll
            for (int ni = 0; ni < 4; ++ni)
                acc[mi][ni] = __builtin_amdgcn_mfma_f32_16x16x32_bf16(
                    af[mi], bfr[ni], acc[mi][ni], 0, 0, 0);
    };

    int cur = 0;
    const int nt = 4;
    for (int t = 0; t < nt - 1; ++t) {
        asm volatile("s_waitcnt vmcnt(4)" ::: "memory");
        __builtin_amdgcn_s_barrier();
        MFMA_STEP(cur);
        __builtin_amdgcn_s_barrier();
        if (t + 2 < nt) STAGE(cur, t + 2);
        cur ^= 1;
    }
    asm volatile("s_waitcnt vmcnt(0)" ::: "memory");
    __builtin_amdgcn_s_barrier();
    MFMA_STEP(cur);

    const bool isV = (MODE == 1 && by == 1);
    unsigned short* Tn = (isV ? out1 : out0) + offb + (size_t)bz * Lk * 128;
    const float* bias = (MODE == 0) ? nullptr : (by == 0 ? bias0 : bias1);

    #pragma unroll
    for (int mi = 0; mi < 4; ++mi) {
        const int mb = wr * 64 + mi * 16 + hi * 4;
        float ba[4] = {0.f, 0.f, 0.f, 0.f};
        if (MODE == 1) {
            float4 bv4 = *(const float4*)&bias[c0 + mb];
            ba[0] = bv4.x; ba[1] = bv4.y; ba[2] = bv4.z; ba[3] = bv4.w;
        }
        float s1[4], t1[4], s2[4], t2[4];
        if (MODE == 0) {
            #pragma unroll
            for (int r2 = 0; r2 < 4; ++r2) {
                int gm = c0 + mb + r2;
                float i1 = agg[gm] * rsqrtf(agv[gm] + EPS);
                s1[r2] = i1; t1[r2] = agb[gm] - agm[gm] * i1;
                float i2 = ang[gm] * rsqrtf(anv[gm] + EPS);
                s2[r2] = i2; t2[r2] = anb[gm] - anm[gm] * i2;
            }
        }
        #pragma unroll
        for (int ni = 0; ni < 4; ++ni) {
            const int cp = p0 + wc * 64 + ni * 16 + qcol;
            if (cp >= Lk) continue;
            float vals[4];
            #pragma unroll
            for (int r2 = 0; r2 < 4; ++r2) {
                float val = acc[mi][ni][r2] + ba[r2];
                if (MODE == 0) {
                    val = fmaf(val, s1[r2], t1[r2]);
                    val = fmaf(val, s2[r2], t2[r2]);
                }
                vals[r2] = val;
            }
            if (!isV) {
                *(uint2*)&Tn[(size_t)cp * 128 + mb] =
                    make_uint2(pack2bf(vals[0], vals[1]), pack2bf(vals[2], vals[3]));
            } else {
                #pragma unroll
                for (int r2 = 0; r2 < 4; ++r2)
                    Tn[(size_t)(mb + r2) * Lk + cp] =
                        __builtin_bit_cast(unsigned short, (__bf16)vals[r2]);
            }
        }
    }
}

// ---------------------------------------------------------------------------
// Flash attention, all paths in one dispatch. grid (48, N*2, 4).
// qT/obT: [n][L][512] (path at col p*128). kT_all/vN_all per-path at c_OFFB.
// ---------------------------------------------------------------------------
__global__ __launch_bounds__(256) void attn_bf_all_kernel(
    const unsigned short* __restrict__ qT, const unsigned short* __restrict__ kT_all,
    const unsigned short* __restrict__ vN_all, unsigned short* __restrict__ obT,
    int L)
{
    const int p = blockIdx.z;
    const int Lk = c_LKS[p];
    const int offb = c_OFFB[p];
    const int l0 = blockIdx.x * 64;
    const int nh = blockIdx.y;
    const int n = nh >> 1, h = nh & 1;
    const unsigned short* qn = qT + (size_t)n * L * 512 + p * 128 + h * 64;
    const unsigned short* kn = kT_all + offb + (size_t)n * Lk * 128 + h * 64;
    const unsigned short* vn = vN_all + offb + ((size_t)n * 128 + h * 64) * Lk;
    unsigned short*       on = obT + (size_t)n * L * 512 + p * 128 + h * 64;

    __shared__ __align__(16) unsigned short Ps[4][16][72];

    const int tid = threadIdx.x;
    const int wave = tid >> 6;
    const int lane = tid & 63;
    const int qcol = lane & 15;
    const int hi   = lane >> 4;
    const int ql   = wave * 16 + qcol;

    bf16x8 qf0 = *(const bf16x8*)&qn[(size_t)(l0 + ql) * 512 + hi * 8];
    bf16x8 qf1 = *(const bf16x8*)&qn[(size_t)(l0 + ql) * 512 + 32 + hi * 8];

    f32x4 o_acc[4] = {};
    float mrow = -INFINITY, lrow = 0.f;

    for (int mc = 0; mc < Lk; mc += 64) {
        f32x4 sacc[4];
        #pragma unroll
        for (int kt = 0; kt < 4; ++kt) {
            const size_t kr = (size_t)(mc + kt * 16 + qcol) * 128;
            bf16x8 k0 = *(const bf16x8*)&kn[kr + hi * 8];
            bf16x8 k1 = *(const bf16x8*)&kn[kr + 32 + hi * 8];
            f32x4 a = {};
            a = __builtin_amdgcn_mfma_f32_16x16x32_bf16(k0, qf0, a, 0, 0, 0);
            a = __builtin_amdgcn_mfma_f32_16x16x32_bf16(k1, qf1, a, 0, 0, 0);
            sacc[kt] = a;
        }

        float cm = -INFINITY;
        #pragma unroll
        for (int kt = 0; kt < 4; ++kt)
            #pragma unroll
            for (int r2 = 0; r2 < 4; ++r2) cm = fmaxf(cm, sacc[kt][r2]);
        cm = fmaxf(cm, __shfl_xor(cm, 16));
        cm = fmaxf(cm, __shfl_xor(cm, 32));
        float nm = fmaxf(mrow, cm);
        float alpha = __expf(mrow - nm);
        float csum = 0.f;
        unsigned int pw[4][2];
        #pragma unroll
        for (int kt = 0; kt < 4; ++kt) {
            float p0 = __expf(sacc[kt][0] - nm);
            float p1 = __expf(sacc[kt][1] - nm);
            float p2 = __expf(sacc[kt][2] - nm);
            float p3 = __expf(sacc[kt][3] - nm);
            csum += (p0 + p1) + (p2 + p3);
            pw[kt][0] = pack2bf(p0, p1);
            pw[kt][1] = pack2bf(p2, p3);
        }
        csum += __shfl_xor(csum, 16);
        csum += __shfl_xor(csum, 32);
        lrow = lrow * alpha + csum;
        mrow = nm;

        #pragma unroll
        for (int kt = 0; kt < 4; ++kt)
            *(uint2*)&Ps[wave][qcol][kt * 16 + hi * 4] =
                make_uint2(pw[kt][0], pw[kt][1]);

        #pragma unroll
        for (int et = 0; et < 4; ++et)
            #pragma unroll
            for (int r2 = 0; r2 < 4; ++r2) o_acc[et][r2] *= alpha;

        bf16x8 pf0 = *(const bf16x8*)&Ps[wave][qcol][hi * 8];
        bf16x8 pf1 = *(const bf16x8*)&Ps[wave][qcol][hi * 8 + 32];
        #pragma unroll
        for (int et = 0; et < 4; ++et) {
            const size_t vr = (size_t)(et * 16 + qcol) * Lk + mc;
            bf16x8 v0 = *(const bf16x8*)&vn[vr + hi * 8];
            bf16x8 v1 = *(const bf16x8*)&vn[vr + 32 + hi * 8];
            o_acc[et] = __builtin_amdgcn_mfma_f32_16x16x32_bf16(v0, pf0, o_acc[et], 0, 0, 0);
            o_acc[et] = __builtin_amdgcn_mfma_f32_16x16x32_bf16(v1, pf1, o_acc[et], 0, 0, 0);
        }
    }

    float invl = 1.f / lrow;
    #pragma unroll
    for (int et = 0; et < 4; ++et) {
        float a0 = o_acc[et][0] * invl, a1 = o_acc[et][1] * invl;
        float a2 = o_acc[et][2] * invl, a3 = o_acc[et][3] * invl;
        *(uint2*)&on[(size_t)(l0 + ql) * 512 + et * 16 + hi * 4] =
            make_uint2(pack2bf(a0, a1), pack2bf(a2, a3));
    }
}

// ---------------------------------------------------------------------------
extern "C" void kernel_launch(void* const* d_in, const int* in_sizes, int n_in,
                              void* d_out, int out_size, void* d_ws, size_t ws_size,
                              hipStream_t stream)
{
    const float* x   = (const float*)d_in[0];
    const float* n1g = (const float*)d_in[1];
    const float* n1b = (const float*)d_in[2];
    const float* n1m = (const float*)d_in[3];
    const float* n1v = (const float*)d_in[4];
    const float* n2g = (const float*)d_in[5];
    const float* n2b = (const float*)d_in[6];
    const float* n2m = (const float*)d_in[7];
    const float* n2v = (const float*)d_in[8];
    const float* Wq  = (const float*)d_in[9];
    const float* Wk  = (const float*)d_in[10];
    const float* Wv  = (const float*)d_in[11];
    const float* Wo  = (const float*)d_in[12];
    const float* Wp  = (const float*)d_in[13];
    const float* bq  = (const float*)d_in[14];
    const float* bk  = (const float*)d_in[15];
    const float* bv  = (const float*)d_in[16];
    const float* bo  = (const float*)d_in[17];
    const float* agg = (const float*)d_in[18];
    const float* agb = (const float*)d_in[19];
    const float* agm = (const float*)d_in[20];
    const float* agv = (const float*)d_in[21];
    const float* ang = (const float*)d_in[22];
    const float* anb = (const float*)d_in[23];
    const float* anm = (const float*)d_in[24];
    const float* anv = (const float*)d_in[25];
    const float* W1  = (const float*)d_in[26];
    const float* b1  = (const float*)d_in[27];
    const float* W2  = (const float*)d_in[28];
    const float* b2  = (const float*)d_in[29];

    float* out = (float*)d_out;
    unsigned short* wsb = (unsigned short*)d_ws;

    const int N = 8, Cc = 512, L = 3072, FF = 2048;
    const int WSZ = 65536, FSZ = 1048576;
    const size_t PATHBUF = 2949120;   // N*128*2880 u16

    // ws layout (u16). h2T aliases hT (Wq is hT's only reader, runs earlier).
    // qTall aliases m1T front (dead before W1 writes m1T).
    unsigned short* wbf      = wsb;
    unsigned short* hT       = wbf      + 5 * WSZ + 2 * FSZ;   // 12,582,912
    unsigned short* h2T      = hT;                              // alias
    unsigned short* obT      = hT       + (size_t)N * L * Cc;  // 12,582,912
    unsigned short* xa0T_all = obT      + (size_t)N * L * 512;
    unsigned short* xabT_all = xa0T_all + PATHBUF;
    unsigned short* kT_all   = xabT_all + PATHBUF;
    unsigned short* vN_all   = kT_all   + PATHBUF;
    unsigned short* m1T      = vN_all   + PATHBUF;             // 50,331,648
    unsigned short* qTall    = m1T;                             // [N][L][512]

    const unsigned short* WqB = wbf;
    const unsigned short* WkB = wbf + WSZ;
    const unsigned short* WvB = wbf + 2 * WSZ;
    const unsigned short* WoB = wbf + 3 * WSZ;
    const unsigned short* WpB = wbf + 4 * WSZ;
    const unsigned short* W1B = wbf + 5 * WSZ;
    const unsigned short* W2B = wbf + 5 * WSZ + FSZ;

    const float* nul = nullptr;
    float* nulf = nullptr;
    unsigned short* nulu = nullptr;

    {
        long long tot4 = (5LL * WSZ + 2LL * FSZ) / 4;
        wcvt_kernel<<<dim3((unsigned)((tot4 + 255) / 256)), dim3(256), 0, stream>>>(
            Wq, Wk, Wv, Wo, Wp, W1, W2, wbf);
    }
    bn_transpose_kernel<<<dim3(L / 64, Cc / 64, N), dim3(256), 0, stream>>>(
        x, n1g, n1b, n1m, n1v, hT, Cc, L);

    pool_bn_all_kernel<<<dim3(24, 2, N * 4), dim3(256), 0, stream>>>(
        x, n1g, n1b, n1m, n1v, xa0T_all, Cc, L);

    // grouped Q: all paths, block-diag Wq
    gemm_bf<1><<<dim3(L / 128, 4, N), dim3(256), 0, stream>>>(
        WqB, hT, 512, 128, L, Cc, (long long)L * Cc,
        bq, 0.125f, F_BIAS,
        nul, nul, nul, nul, nul, nul, nul, nul,
        nulf, 0, nul, 0, qTall, 512, 0, (long long)L * 512, 128);

    // grouped Wp (all paths): xabT = doubleBN(Wp @ xa0)
    gemm_path<0><<<dim3(23, 1, N), dim3(256), 0, stream>>>(
        WpB, nulu, xa0T_all, nul, nul,
        agg, agb, agm, agv, ang, anb, anm, anv,
        xabT_all, nulu);

    // grouped Wk+Wv (all paths)
    gemm_path<1><<<dim3(23, 2, N), dim3(256), 0, stream>>>(
        WkB, WvB, xabT_all, bk, bv,
        nul, nul, nul, nul, nul, nul, nul, nul,
        kT_all, vN_all);

    // all-path attention
    attn_bf_all_kernel<<<dim3(L / 64, N * 2, 4), dim3(256), 0, stream>>>(
        qTall, kT_all, vN_all, obT, L);

    // grouped Wo: out = x + Wo @ o + bo (f32), h2T aux = bf16(bn2(out))
    gemm_bf<3><<<dim3(L / 128, 4, N), dim3(256), 0, stream>>>(
        WoB, obT, 512, 128, L, 512, (long long)L * 512,
        bo, 1.f, F_BIAS | F_RESID,
        n2g, n2b, n2m, n2v,
        nul, nul, nul, nul,
        out, (long long)Cc * L,
        x, (long long)Cc * L,
        h2T, Cc, 0, (long long)L * Cc, 128);

    // FFN
    gemm_bf<1><<<dim3(L / 128, FF / 128, N), dim3(256), 0, stream>>>(
        W1B, h2T, FF, Cc, L, Cc, (long long)L * Cc,
        b1, 1.f, F_BIAS | F_GELU,
        nul, nul, nul, nul, nul, nul, nul, nul,
        nulf, 0, nul, 0, m1T, FF, 0, (long long)L * FF, 0);

    gemm_bf<0><<<dim3(L / 128, Cc / 128, N), dim3(256), 0, stream>>>(
        W2B, m1T, Cc, FF, L, FF, (long long)L * FF,
        b2, 1.f, F_BIAS | F_RESID,
        nul, nul, nul, nul, nul, nul, nul, nul,
        out, (long long)Cc * L, out, (long long)Cc * L,
        nulu, 0, 0, 0, 0);
}

// Round 9
// 532.695 us; speedup vs baseline: 11.6931x; 1.3042x over previous
//
#include <hip/hip_runtime.h>
#include <math.h>

#define EPS 1e-5f

#define F_BIAS  1
#define F_DBN   2
#define F_GELU  4
#define F_RESID 8

typedef __attribute__((ext_vector_type(8))) __bf16 bf16x8;
typedef __attribute__((ext_vector_type(4))) float f32x4;
typedef __attribute__((ext_vector_type(8))) unsigned short u16x8;

__device__ __forceinline__ unsigned int pack2bf(float a, float b) {
    unsigned short ua = __builtin_bit_cast(unsigned short, (__bf16)a);
    unsigned short ub = __builtin_bit_cast(unsigned short, (__bf16)b);
    return (unsigned int)ua | ((unsigned int)ub << 16);
}

__device__ __forceinline__ void gload_lds16(const unsigned short* g, unsigned short* l) {
    __builtin_amdgcn_global_load_lds(
        (const __attribute__((address_space(1))) unsigned int*)g,
        (__attribute__((address_space(3))) unsigned int*)l,
        16, 0, 0);
}

// cheap tanh-gelu: u*sigmoid(2z)
__device__ __forceinline__ float gelu_f(float u) {
    float s = u * u;
    float w = u * fmaf(s, 0.0713548162726f, 1.59576912161f);
    float e = __expf(-w);
    return u * __builtin_amdgcn_rcpf(1.f + e);
}

// path constants: ratios {2,4,8,16}
__device__ __constant__ int c_LKS[4]  = {1536, 768, 384, 192};
__device__ __constant__ int c_OFFB[4] = {0, 1572864, 2359296, 2752512};

// ---------------------------------------------------------------------------
// weights fp32 -> bf16
// ---------------------------------------------------------------------------
__global__ __launch_bounds__(256) void wcvt_kernel(
    const float* __restrict__ Wq, const float* __restrict__ Wk,
    const float* __restrict__ Wv, const float* __restrict__ Wo,
    const float* __restrict__ Wp, const float* __restrict__ W1,
    const float* __restrict__ W2, unsigned short* __restrict__ dst)
{
    const int WSZ = 65536;
    const int FSZ = 1048576;
    int i4 = blockIdx.x * blockDim.x + threadIdx.x;
    long long i = (long long)i4 * 4;
    const long long total = 5LL * WSZ + 2LL * FSZ;
    if (i >= total) return;
    #pragma unroll
    for (int j = 0; j < 4; ++j) {
        long long idx = i + j;
        float v;
        if      (idx < WSZ)            v = Wq[idx];
        else if (idx < 2 * WSZ)        v = Wk[idx - WSZ];
        else if (idx < 3 * WSZ)        v = Wv[idx - 2 * WSZ];
        else if (idx < 4 * WSZ)        v = Wo[idx - 3 * WSZ];
        else if (idx < 5 * WSZ)        v = Wp[idx - 4 * WSZ];
        else if (idx < 5 * WSZ + FSZ)  v = W1[idx - 5 * WSZ];
        else                           v = W2[idx - 5 * WSZ - FSZ];
        dst[idx] = __builtin_bit_cast(unsigned short, (__bf16)v);
    }
}

// ---------------------------------------------------------------------------
// hT = bf16(bn1(x))^T : x (N,C,L) f32 -> hT (N,L,C) bf16
// ---------------------------------------------------------------------------
__global__ __launch_bounds__(256) void bn_transpose_kernel(
    const float* __restrict__ x,
    const float* __restrict__ g, const float* __restrict__ b,
    const float* __restrict__ bm, const float* __restrict__ bvv,
    unsigned short* __restrict__ hT, int C, int L)
{
    __shared__ float ps[64][65];
    const int l0 = blockIdx.x * 64, ct = blockIdx.y, n = blockIdx.z;
    const int tid = threadIdx.x;
    const int c = tid >> 2, q = tid & 3;
    const int cg = ct * 64 + c;
    float inv = g[cg] * rsqrtf(bvv[cg] + EPS);
    float add = b[cg] - bm[cg] * inv;
    const float* xp = x + ((size_t)n * C + cg) * L + l0 + q * 16;
    #pragma unroll
    for (int s = 0; s < 4; ++s) {
        float4 vv = *(const float4*)&xp[s * 4];
        ps[c][q * 16 + s * 4 + 0] = fmaf(vv.x, inv, add);
        ps[c][q * 16 + s * 4 + 1] = fmaf(vv.y, inv, add);
        ps[c][q * 16 + s * 4 + 2] = fmaf(vv.z, inv, add);
        ps[c][q * 16 + s * 4 + 3] = fmaf(vv.w, inv, add);
    }
    __syncthreads();
    #pragma unroll
    for (int j = 0; j < 2; ++j) {
        int row = (tid >> 3) + 32 * j;
        int cc0 = (tid & 7) * 8;
        unsigned int w0 = pack2bf(ps[cc0 + 0][row], ps[cc0 + 1][row]);
        unsigned int w1 = pack2bf(ps[cc0 + 2][row], ps[cc0 + 3][row]);
        unsigned int w2 = pack2bf(ps[cc0 + 4][row], ps[cc0 + 5][row]);
        unsigned int w3 = pack2bf(ps[cc0 + 6][row], ps[cc0 + 7][row]);
        *(uint4*)&hT[((size_t)n * L + l0 + row) * C + ct * 64 + cc0] =
            make_uint4(w0, w1, w2, w3);
    }
}

// ---------------------------------------------------------------------------
// Pool+BN1 for ALL paths in one dispatch: grid (24, 2, N*4)
// ---------------------------------------------------------------------------
__global__ __launch_bounds__(256) void pool_bn_all_kernel(
    const float* __restrict__ x,
    const float* __restrict__ g, const float* __restrict__ b,
    const float* __restrict__ bm, const float* __restrict__ bvv,
    unsigned short* __restrict__ xa0T_all, int C, int L)
{
    const int p = blockIdx.z & 3;
    const int n = blockIdx.z >> 2;
    const int Lk = c_LKS[p];
    const int lk0 = blockIdx.x * 64;
    if (lk0 >= Lk) return;
    const int r = L / Lk;
    const int ct = blockIdx.y;
    __shared__ float ps[64][65];
    const int tid = threadIdx.x;
    const int c = tid >> 2, q = tid & 3;
    const int cg = p * 128 + ct * 64 + c;
    float inv = g[cg] * rsqrtf(bvv[cg] + EPS);
    float add = b[cg] - bm[cg] * inv;
    const float* xp = x + ((size_t)n * C + cg) * L;
    float rinv = 1.0f / (float)r;
    #pragma unroll
    for (int s = 0; s < 16; ++s) {
        int lk = q * 16 + s;
        const float* base = xp + (size_t)(lk0 + lk) * r;
        float sum = 0.f, mx = -INFINITY;
        for (int j = 0; j < r; j += 2) {
            float2 vv = *(const float2*)&base[j];
            float t0 = fmaf(vv.x, inv, add);
            float t1 = fmaf(vv.y, inv, add);
            sum += t0 + t1;
            mx = fmaxf(mx, fmaxf(t0, t1));
        }
        ps[c][lk] = sum * rinv + mx;
    }
    __syncthreads();
    unsigned short* dst = xa0T_all + c_OFFB[p];
    #pragma unroll
    for (int j = 0; j < 2; ++j) {
        int row = (tid >> 3) + 32 * j;
        int cc0 = (tid & 7) * 8;
        unsigned int w0 = pack2bf(ps[cc0 + 0][row], ps[cc0 + 1][row]);
        unsigned int w1 = pack2bf(ps[cc0 + 2][row], ps[cc0 + 3][row]);
        unsigned int w2 = pack2bf(ps[cc0 + 4][row], ps[cc0 + 5][row]);
        unsigned int w3 = pack2bf(ps[cc0 + 6][row], ps[cc0 + 7][row]);
        *(uint4*)&dst[((size_t)n * Lk + lk0 + row) * 128 + ct * 64 + cc0] =
            make_uint4(w0, w1, w2, w3);
    }
}

// ---------------------------------------------------------------------------
// bf16 MFMA GEMM, counted-vmcnt 2-buffer pipeline, hoisted addresses.
// ---------------------------------------------------------------------------
template<int OMODE>
__global__ __launch_bounds__(256) void gemm_bf(
    const unsigned short* __restrict__ A, const unsigned short* __restrict__ BT,
    int M, int K, int Npos, int ldBT, long long strideBT,
    const float* __restrict__ bias, float oscale, int flags,
    const float* __restrict__ g1, const float* __restrict__ b1p,
    const float* __restrict__ m1p, const float* __restrict__ v1p,
    const float* __restrict__ g2, const float* __restrict__ b2p,
    const float* __restrict__ m2p, const float* __restrict__ v2p,
    float* __restrict__ outN, long long strideN,
    const float* __restrict__ resid, long long strideR,
    unsigned short* __restrict__ outT, int ldT, int moff, long long strideT,
    int gKoff)
{
    __shared__ __align__(16) unsigned short As[2][128][32];
    __shared__ __align__(16) unsigned short Bs[2][128][32];

    const int tid = threadIdx.x;

    const int gdx = gridDim.x, gdy = gridDim.y;
    const int nwg = gdx * gdy * gridDim.z;
    int bid = blockIdx.x + gdx * (blockIdx.y + gdy * blockIdx.z);
    {
        int q = nwg >> 3, rr = nwg & 7;
        int xcd = bid & 7, idx = bid >> 3;
        bid = (xcd < rr ? xcd * (q + 1) : rr * (q + 1) + (xcd - rr) * q) + idx;
    }
    const int bx = bid % gdx;
    const int by = (bid / gdx) % gdy;
    const int bz = bid / (gdx * gdy);

    const int m0 = by * 128;
    const int p0 = bx * 128;
    const unsigned short* Bn = BT + (size_t)bz * strideBT
                              + (size_t)(m0 >> 7) * gKoff;

    const int wave = tid >> 6;
    const int lane = tid & 63;
    const int qcol = lane & 15;
    const int hi   = lane >> 4;
    const int wr   = wave >> 1;
    const int wc   = wave & 1;
    const int lrow = lane >> 2;
    const int lseg = (lane & 3) * 8;

    const unsigned short* aR0 = A + (size_t)(m0 + wave * 32 + lrow) * K + lseg;
    const unsigned short* aR1 = aR0 + (size_t)16 * K;
    int pr0 = p0 + wave * 32 + lrow;      if (pr0 > Npos - 1) pr0 = Npos - 1;
    int pr1 = p0 + wave * 32 + 16 + lrow; if (pr1 > Npos - 1) pr1 = Npos - 1;
    const unsigned short* bR0 = Bn + (size_t)pr0 * ldBT + lseg;
    const unsigned short* bR1 = Bn + (size_t)pr1 * ldBT + lseg;
    unsigned short* ldsA0 = &As[0][wave * 32][0];
    unsigned short* ldsA1 = &As[0][wave * 32 + 16][0];
    unsigned short* ldsB0 = &Bs[0][wave * 32][0];
    unsigned short* ldsB1 = &Bs[0][wave * 32 + 16][0];
    const int bufStride = 128 * 32;

    auto STAGE = [&](int b, int t) {
        const int ko = t * 32;
        gload_lds16(aR0 + ko, ldsA0 + b * bufStride);
        gload_lds16(aR1 + ko, ldsA1 + b * bufStride);
        gload_lds16(bR0 + ko, ldsB0 + b * bufStride);
        gload_lds16(bR1 + ko, ldsB1 + b * bufStride);
    };

    f32x4 acc[4][4] = {};
    const int nt = K >> 5;

    STAGE(0, 0);
    STAGE(1, 1);

    auto MFMA_STEP = [&](int b) {
        bf16x8 af[4], bfr[4];
        #pragma unroll
        for (int mi = 0; mi < 4; ++mi)
            af[mi] = *(const bf16x8*)&As[b][wr * 64 + mi * 16 + qcol][hi * 8];
        #pragma unroll
        for (int ni = 0; ni < 4; ++ni)
            bfr[ni] = *(const bf16x8*)&Bs[b][wc * 64 + ni * 16 + qcol][hi * 8];
        #pragma unroll
        for (int mi = 0; mi < 4; ++mi)
            #pragma unroll
            for (int ni = 0; ni < 4; ++ni)
                acc[mi][ni] = __builtin_amdgcn_mfma_f32_16x16x32_bf16(
                    af[mi], bfr[ni], acc[mi][ni], 0, 0, 0);
    };

    int cur = 0;
    for (int t = 0; t < nt - 1; ++t) {
        asm volatile("s_waitcnt vmcnt(4)" ::: "memory");
        __builtin_amdgcn_s_barrier();
        MFMA_STEP(cur);
        __builtin_amdgcn_s_barrier();
        if (t + 2 < nt) STAGE(cur, t + 2);
        cur ^= 1;
    }
    asm volatile("s_waitcnt vmcnt(0)" ::: "memory");
    __builtin_amdgcn_s_barrier();
    MFMA_STEP(cur);

    float* Cn = outN + (size_t)bz * strideN;
    const float* Rn = resid + (size_t)bz * strideR;
    unsigned short* Tn = outT + (size_t)bz * strideT;

    #pragma unroll
    for (int mi = 0; mi < 4; ++mi) {
        const int mb = m0 + wr * 64 + mi * 16 + hi * 4;
        float4 bv4 = make_float4(0.f, 0.f, 0.f, 0.f);
        if (flags & F_BIAS) bv4 = *(const float4*)&bias[mb];
        float s1[4], t1[4];
        if ((flags & F_DBN) || OMODE == 3) {
            float4 gg = *(const float4*)&g1[mb];
            float4 bb = *(const float4*)&b1p[mb];
            float4 mm = *(const float4*)&m1p[mb];
            float4 vv = *(const float4*)&v1p[mb];
            float gga[4] = {gg.x, gg.y, gg.z, gg.w};
            float bba[4] = {bb.x, bb.y, bb.z, bb.w};
            float mma[4] = {mm.x, mm.y, mm.z, mm.w};
            float vva[4] = {vv.x, vv.y, vv.z, vv.w};
            #pragma unroll
            for (int r2 = 0; r2 < 4; ++r2) {
                float iv = gga[r2] * rsqrtf(vva[r2] + EPS);
                s1[r2] = iv; t1[r2] = bba[r2] - mma[r2] * iv;
            }
        }
        float s2[4], t2[4];
        if (flags & F_DBN) {
            float4 gg = *(const float4*)&g2[mb];
            float4 bb = *(const float4*)&b2p[mb];
            float4 mm = *(const float4*)&m2p[mb];
            float4 vv = *(const float4*)&v2p[mb];
            float gga[4] = {gg.x, gg.y, gg.z, gg.w};
            float bba[4] = {bb.x, bb.y, bb.z, bb.w};
            float mma[4] = {mm.x, mm.y, mm.z, mm.w};
            float vva[4] = {vv.x, vv.y, vv.z, vv.w};
            #pragma unroll
            for (int r2 = 0; r2 < 4; ++r2) {
                float iv = gga[r2] * rsqrtf(vva[r2] + EPS);
                s2[r2] = iv; t2[r2] = bba[r2] - mma[r2] * iv;
            }
        }
        const float ba[4] = {bv4.x, bv4.y, bv4.z, bv4.w};
        #pragma unroll
        for (int ni = 0; ni < 4; ++ni) {
            const int cp = p0 + wc * 64 + ni * 16 + qcol;
            if (cp >= Npos) continue;
            float vals[4];
            #pragma unroll
            for (int r2 = 0; r2 < 4; ++r2) {
                float val = (acc[mi][ni][r2] + ba[r2]) * oscale;
                if (flags & F_DBN) {
                    val = fmaf(val, s1[r2], t1[r2]);
                    val = fmaf(val, s2[r2], t2[r2]);
                }
                if (flags & F_GELU) val = gelu_f(val);
                vals[r2] = val;
            }
            if (OMODE == 0 || OMODE == 3) {
                #pragma unroll
                for (int r2 = 0; r2 < 4; ++r2) {
                    size_t off = (size_t)(mb + r2) * Npos + cp;
                    float v = vals[r2];
                    if (flags & F_RESID) v += Rn[off];
                    Cn[off] = v;
                    vals[r2] = v;
                }
            }
            if (OMODE == 1) {
                *(uint2*)&Tn[(size_t)cp * ldT + moff + mb] =
                    make_uint2(pack2bf(vals[0], vals[1]), pack2bf(vals[2], vals[3]));
            }
            if (OMODE == 2) {
                #pragma unroll
                for (int r2 = 0; r2 < 4; ++r2)
                    Tn[(size_t)(mb + r2) * Npos + cp] =
                        __builtin_bit_cast(unsigned short, (__bf16)vals[r2]);
            }
            if (OMODE == 3) {
                float a0 = fmaf(vals[0], s1[0], t1[0]);
                float a1 = fmaf(vals[1], s1[1], t1[1]);
                float a2 = fmaf(vals[2], s1[2], t1[2]);
                float a3 = fmaf(vals[3], s1[3], t1[3]);
                *(uint2*)&Tn[(size_t)cp * ldT + moff + mb] =
                    make_uint2(pack2bf(a0, a1), pack2bf(a2, a3));
            }
        }
    }
}

// ---------------------------------------------------------------------------
// Grouped per-path GEMM (K=128, M=128 per path), all 4 paths in one dispatch.
// ---------------------------------------------------------------------------
template<int MODE>
__global__ __launch_bounds__(256) void gemm_path(
    const unsigned short* __restrict__ A0, const unsigned short* __restrict__ A1,
    const unsigned short* __restrict__ Bsrc,
    const float* __restrict__ bias0, const float* __restrict__ bias1,
    const float* __restrict__ agg, const float* __restrict__ agb,
    const float* __restrict__ agm, const float* __restrict__ agv,
    const float* __restrict__ ang, const float* __restrict__ anb,
    const float* __restrict__ anm, const float* __restrict__ anv,
    unsigned short* __restrict__ out0, unsigned short* __restrict__ out1)
{
    __shared__ __align__(16) unsigned short As[2][128][32];
    __shared__ __align__(16) unsigned short Bs[2][128][32];

    const int tid = threadIdx.x;
    const int gdx = gridDim.x, gdy = gridDim.y;
    const int nwg = gdx * gdy * gridDim.z;
    int bid = blockIdx.x + gdx * (blockIdx.y + gdy * blockIdx.z);
    {
        int q = nwg >> 3, rr = nwg & 7;
        int xcd = bid & 7, idx = bid >> 3;
        bid = (xcd < rr ? xcd * (q + 1) : rr * (q + 1) + (xcd - rr) * q) + idx;
    }
    const int bx = bid % gdx;
    const int by = (bid / gdx) % gdy;
    const int bz = bid / (gdx * gdy);

    int p, px;
    if      (bx < 12) { p = 0; px = bx; }
    else if (bx < 18) { p = 1; px = bx - 12; }
    else if (bx < 21) { p = 2; px = bx - 18; }
    else              { p = 3; px = bx - 21; }
    const int Lk = c_LKS[p];
    const int offb = c_OFFB[p];
    const int c0 = p * 128;
    const int p0 = px * 128;
    const int K = 128;

    const unsigned short* A = (MODE == 1 && by == 1 ? A1 : A0) + p * 16384;
    const unsigned short* Bn = Bsrc + offb + (size_t)bz * Lk * 128;

    const int wave = tid >> 6;
    const int lane = tid & 63;
    const int qcol = lane & 15;
    const int hi   = lane >> 4;
    const int wr   = wave >> 1;
    const int wc   = wave & 1;
    const int lrow = lane >> 2;
    const int lseg = (lane & 3) * 8;

    const unsigned short* aR0 = A + (size_t)(wave * 32 + lrow) * K + lseg;
    const unsigned short* aR1 = aR0 + (size_t)16 * K;
    int pr0 = p0 + wave * 32 + lrow;      if (pr0 > Lk - 1) pr0 = Lk - 1;
    int pr1 = p0 + wave * 32 + 16 + lrow; if (pr1 > Lk - 1) pr1 = Lk - 1;
    const unsigned short* bR0 = Bn + (size_t)pr0 * 128 + lseg;
    const unsigned short* bR1 = Bn + (size_t)pr1 * 128 + lseg;
    unsigned short* ldsA0 = &As[0][wave * 32][0];
    unsigned short* ldsA1 = &As[0][wave * 32 + 16][0];
    unsigned short* ldsB0 = &Bs[0][wave * 32][0];
    unsigned short* ldsB1 = &Bs[0][wave * 32 + 16][0];
    const int bufStride = 128 * 32;

    auto STAGE = [&](int b, int t) {
        const int ko = t * 32;
        gload_lds16(aR0 + ko, ldsA0 + b * bufStride);
        gload_lds16(aR1 + ko, ldsA1 + b * bufStride);
        gload_lds16(bR0 + ko, ldsB0 + b * bufStride);
        gload_lds16(bR1 + ko, ldsB1 + b * bufStride);
    };

    f32x4 acc[4][4] = {};
    STAGE(0, 0);
    STAGE(1, 1);

    auto MFMA_STEP = [&](int b) {
        bf16x8 af[4], bfr[4];
        #pragma unroll
        for (int mi = 0; mi < 4; ++mi)
            af[mi] = *(const bf16x8*)&As[b][wr * 64 + mi * 16 + qcol][hi * 8];
        #pragma unroll
        for (int ni = 0; ni < 4; ++ni)
            bfr[ni] = *(const bf16x8*)&Bs[b][wc * 64 + ni * 16 + qcol][hi * 8];
        #pragma unroll
        for (int mi = 0; mi < 4; ++mi)
            #pragma unroll
            for (int ni = 0; ni < 4; ++ni)
                acc[mi][ni] = __builtin_amdgcn_mfma_f32_16x16x32_bf16(
                    af[mi], bfr[ni], acc[mi][ni], 0, 0, 0);
    };

    int cur = 0;
    const int nt = 4;
    for (int t = 0; t < nt - 1; ++t) {
        asm volatile("s_waitcnt vmcnt(4)" ::: "memory");
        __builtin_amdgcn_s_barrier();
        MFMA_STEP(cur);
        __builtin_amdgcn_s_barrier();
        if (t + 2 < nt) STAGE(cur, t + 2);
        cur ^= 1;
    }
    asm volatile("s_waitcnt vmcnt(0)" ::: "memory");
    __builtin_amdgcn_s_barrier();
    MFMA_STEP(cur);

    const bool isV = (MODE == 1 && by == 1);
    unsigned short* Tn = (isV ? out1 : out0) + offb + (size_t)bz * Lk * 128;
    const float* bias = (MODE == 0) ? nullptr : (by == 0 ? bias0 : bias1);

    #pragma unroll
    for (int mi = 0; mi < 4; ++mi) {
        const int mb = wr * 64 + mi * 16 + hi * 4;
        float ba[4] = {0.f, 0.f, 0.f, 0.f};
        if (MODE == 1) {
            float4 bv4 = *(const float4*)&bias[c0 + mb];
            ba[0] = bv4.x; ba[1] = bv4.y; ba[2] = bv4.z; ba[3] = bv4.w;
        }
        float s1[4], t1[4], s2[4], t2[4];
        if (MODE == 0) {
            #pragma unroll
            for (int r2 = 0; r2 < 4; ++r2) {
                int gm = c0 + mb + r2;
                float i1 = agg[gm] * rsqrtf(agv[gm] + EPS);
                s1[r2] = i1; t1[r2] = agb[gm] - agm[gm] * i1;
                float i2 = ang[gm] * rsqrtf(anv[gm] + EPS);
                s2[r2] = i2; t2[r2] = anb[gm] - anm[gm] * i2;
            }
        }
        #pragma unroll
        for (int ni = 0; ni < 4; ++ni) {
            const int cp = p0 + wc * 64 + ni * 16 + qcol;
            if (cp >= Lk) continue;
            float vals[4];
            #pragma unroll
            for (int r2 = 0; r2 < 4; ++r2) {
                float val = acc[mi][ni][r2] + ba[r2];
                if (MODE == 0) {
                    val = fmaf(val, s1[r2], t1[r2]);
                    val = fmaf(val, s2[r2], t2[r2]);
                }
                vals[r2] = val;
            }
            if (!isV) {
                *(uint2*)&Tn[(size_t)cp * 128 + mb] =
                    make_uint2(pack2bf(vals[0], vals[1]), pack2bf(vals[2], vals[3]));
            } else {
                #pragma unroll
                for (int r2 = 0; r2 < 4; ++r2)
                    Tn[(size_t)(mb + r2) * Lk + cp] =
                        __builtin_bit_cast(unsigned short, (__bf16)vals[r2]);
            }
        }
    }
}

// ---------------------------------------------------------------------------
// Flash attention, all paths; K/V staged in block-shared LDS with the
// counted-vmcnt 2-buffer pipeline (same schedule as gemm_bf).
// LDS tiles XOR-swizzled (both sides, rule #21): write side pre-swizzles the
// GLOBAL source seg (seg' = seg ^ (row&7)); read side applies the same XOR.
// Ks[64 keys][64 e], Vs[64 e][64 m]; wave w stages rows [16w..16w+15] of each.
// grid (48, N*2, 4), 256 threads = 4 waves x 16 queries.
// ---------------------------------------------------------------------------
__global__ __launch_bounds__(256) void attn_bf_all_kernel(
    const unsigned short* __restrict__ qT, const unsigned short* __restrict__ kT_all,
    const unsigned short* __restrict__ vN_all, unsigned short* __restrict__ obT,
    int L)
{
    const int p = blockIdx.z;
    const int Lk = c_LKS[p];
    const int offb = c_OFFB[p];
    const int l0 = blockIdx.x * 64;
    const int nh = blockIdx.y;
    const int n = nh >> 1, h = nh & 1;
    const unsigned short* qn = qT + (size_t)n * L * 512 + p * 128 + h * 64;
    const unsigned short* kn = kT_all + offb + (size_t)n * Lk * 128 + h * 64;
    const unsigned short* vn = vN_all + offb + ((size_t)n * 128 + h * 64) * Lk;
    unsigned short*       on = obT + (size_t)n * L * 512 + p * 128 + h * 64;

    __shared__ __align__(16) unsigned short Ks[2][64][64];
    __shared__ __align__(16) unsigned short Vs[2][64][64];
    __shared__ __align__(16) unsigned short Ps[4][16][72];

    const int tid = threadIdx.x;
    const int wave = tid >> 6;
    const int lane = tid & 63;
    const int qcol = lane & 15;
    const int hi   = lane >> 4;
    const int ql   = wave * 16 + qcol;

    // staging: wave w stages K rows [16w..16w+15] (2 instrs) + V rows same.
    // lane l -> row j*8 + (l>>3), seg slot (l&7); SOURCE seg = (l&7)^(l>>3)
    // (so LDS slot (row,seg) holds global seg seg^(row&7): read-XOR inverts).
    const int srow = lane >> 3;
    const int sxor = (lane & 7) ^ srow;
    const unsigned short* kS0 = kn + (size_t)(wave * 16 + srow) * 128 + sxor * 8;
    const unsigned short* kS1 = kn + (size_t)(wave * 16 + 8 + srow) * 128 + sxor * 8;
    const unsigned short* vS0 = vn + (size_t)(wave * 16 + srow) * Lk + sxor * 8;
    const unsigned short* vS1 = vn + (size_t)(wave * 16 + 8 + srow) * Lk + sxor * 8;
    unsigned short* ldsK0 = &Ks[0][wave * 16][0];
    unsigned short* ldsK1 = &Ks[0][wave * 16 + 8][0];
    unsigned short* ldsV0 = &Vs[0][wave * 16][0];
    unsigned short* ldsV1 = &Vs[0][wave * 16 + 8][0];
    const int bufStride = 64 * 64;

    auto STAGE = [&](int b, int t) {   // 4 vm-ops per wave
        const int mc = t * 64;
        gload_lds16(kS0 + (size_t)mc * 128, ldsK0 + b * bufStride);
        gload_lds16(kS1 + (size_t)mc * 128, ldsK1 + b * bufStride);
        gload_lds16(vS0 + mc, ldsV0 + b * bufStride);
        gload_lds16(vS1 + mc, ldsV1 + b * bufStride);
    };

    // read-side swizzled cols (u16): seg hi -> x0, seg 4+hi -> x1 = x0^32
    const int x0 = (hi ^ (qcol & 7)) * 8;
    const int x1 = x0 ^ 32;

    bf16x8 qf0 = *(const bf16x8*)&qn[(size_t)(l0 + ql) * 512 + hi * 8];
    bf16x8 qf1 = *(const bf16x8*)&qn[(size_t)(l0 + ql) * 512 + 32 + hi * 8];

    f32x4 o_acc[4] = {};
    float mrow = -INFINITY, lrow = 0.f;
    const int nt = Lk >> 6;

    STAGE(0, 0);
    STAGE(1, 1);

    auto COMPUTE = [&](int b) {
        // ---- QK^T: S^T[key, q] ----
        f32x4 sacc[4];
        #pragma unroll
        for (int kt = 0; kt < 4; ++kt) {
            bf16x8 k0 = *(const bf16x8*)&Ks[b][kt * 16 + qcol][x0];
            bf16x8 k1 = *(const bf16x8*)&Ks[b][kt * 16 + qcol][x1];
            f32x4 a = {};
            a = __builtin_amdgcn_mfma_f32_16x16x32_bf16(k0, qf0, a, 0, 0, 0);
            a = __builtin_amdgcn_mfma_f32_16x16x32_bf16(k1, qf1, a, 0, 0, 0);
            sacc[kt] = a;
        }
        // ---- online softmax (pairwise max tree) ----
        float m0 = fmaxf(fmaxf(sacc[0][0], sacc[0][1]), fmaxf(sacc[0][2], sacc[0][3]));
        float m1 = fmaxf(fmaxf(sacc[1][0], sacc[1][1]), fmaxf(sacc[1][2], sacc[1][3]));
        float m2 = fmaxf(fmaxf(sacc[2][0], sacc[2][1]), fmaxf(sacc[2][2], sacc[2][3]));
        float m3 = fmaxf(fmaxf(sacc[3][0], sacc[3][1]), fmaxf(sacc[3][2], sacc[3][3]));
        float cm = fmaxf(fmaxf(m0, m1), fmaxf(m2, m3));
        cm = fmaxf(cm, __shfl_xor(cm, 16));
        cm = fmaxf(cm, __shfl_xor(cm, 32));
        float nm = fmaxf(mrow, cm);
        float alpha = __expf(mrow - nm);
        float csum = 0.f;
        unsigned int pw[4][2];
        #pragma unroll
        for (int kt = 0; kt < 4; ++kt) {
            float p0 = __expf(sacc[kt][0] - nm);
            float p1 = __expf(sacc[kt][1] - nm);
            float p2 = __expf(sacc[kt][2] - nm);
            float p3 = __expf(sacc[kt][3] - nm);
            csum += (p0 + p1) + (p2 + p3);
            pw[kt][0] = pack2bf(p0, p1);
            pw[kt][1] = pack2bf(p2, p3);
        }
        csum += __shfl_xor(csum, 16);
        csum += __shfl_xor(csum, 32);
        lrow = lrow * alpha + csum;
        mrow = nm;

        #pragma unroll
        for (int kt = 0; kt < 4; ++kt)
            *(uint2*)&Ps[wave][qcol][kt * 16 + hi * 4] =
                make_uint2(pw[kt][0], pw[kt][1]);

        #pragma unroll
        for (int et = 0; et < 4; ++et)
            #pragma unroll
            for (int r2 = 0; r2 < 4; ++r2) o_acc[et][r2] *= alpha;

        bf16x8 pf0 = *(const bf16x8*)&Ps[wave][qcol][hi * 8];
        bf16x8 pf1 = *(const bf16x8*)&Ps[wave][qcol][hi * 8 + 32];
        #pragma unroll
        for (int et = 0; et < 4; ++et) {
            bf16x8 v0 = *(const bf16x8*)&Vs[b][et * 16 + qcol][x0];
            bf16x8 v1 = *(const bf16x8*)&Vs[b][et * 16 + qcol][x1];
            o_acc[et] = __builtin_amdgcn_mfma_f32_16x16x32_bf16(v0, pf0, o_acc[et], 0, 0, 0);
            o_acc[et] = __builtin_amdgcn_mfma_f32_16x16x32_bf16(v1, pf1, o_acc[et], 0, 0, 0);
        }
    };

    int cur = 0;
    for (int t = 0; t < nt - 1; ++t) {
        asm volatile("s_waitcnt vmcnt(4)" ::: "memory");
        __builtin_amdgcn_s_barrier();
        COMPUTE(cur);
        __builtin_amdgcn_s_barrier();
        if (t + 2 < nt) STAGE(cur, t + 2);
        cur ^= 1;
    }
    asm volatile("s_waitcnt vmcnt(0)" ::: "memory");
    __builtin_amdgcn_s_barrier();
    COMPUTE(cur);

    float invl = 1.f / lrow;
    #pragma unroll
    for (int et = 0; et < 4; ++et) {
        float a0 = o_acc[et][0] * invl, a1 = o_acc[et][1] * invl;
        float a2 = o_acc[et][2] * invl, a3 = o_acc[et][3] * invl;
        *(uint2*)&on[(size_t)(l0 + ql) * 512 + et * 16 + hi * 4] =
            make_uint2(pack2bf(a0, a1), pack2bf(a2, a3));
    }
}

// ---------------------------------------------------------------------------
extern "C" void kernel_launch(void* const* d_in, const int* in_sizes, int n_in,
                              void* d_out, int out_size, void* d_ws, size_t ws_size,
                              hipStream_t stream)
{
    const float* x   = (const float*)d_in[0];
    const float* n1g = (const float*)d_in[1];
    const float* n1b = (const float*)d_in[2];
    const float* n1m = (const float*)d_in[3];
    const float* n1v = (const float*)d_in[4];
    const float* n2g = (const float*)d_in[5];
    const float* n2b = (const float*)d_in[6];
    const float* n2m = (const float*)d_in[7];
    const float* n2v = (const float*)d_in[8];
    const float* Wq  = (const float*)d_in[9];
    const float* Wk  = (const float*)d_in[10];
    const float* Wv  = (const float*)d_in[11];
    const float* Wo  = (const float*)d_in[12];
    const float* Wp  = (const float*)d_in[13];
    const float* bq  = (const float*)d_in[14];
    const float* bk  = (const float*)d_in[15];
    const float* bv  = (const float*)d_in[16];
    const float* bo  = (const float*)d_in[17];
    const float* agg = (const float*)d_in[18];
    const float* agb = (const float*)d_in[19];
    const float* agm = (const float*)d_in[20];
    const float* agv = (const float*)d_in[21];
    const float* ang = (const float*)d_in[22];
    const float* anb = (const float*)d_in[23];
    const float* anm = (const float*)d_in[24];
    const float* anv = (const float*)d_in[25];
    const float* W1  = (const float*)d_in[26];
    const float* b1  = (const float*)d_in[27];
    const float* W2  = (const float*)d_in[28];
    const float* b2  = (const float*)d_in[29];

    float* out = (float*)d_out;
    unsigned short* wsb = (unsigned short*)d_ws;

    const int N = 8, Cc = 512, L = 3072, FF = 2048;
    const int WSZ = 65536, FSZ = 1048576;
    const size_t PATHBUF = 2949120;

    unsigned short* wbf      = wsb;
    unsigned short* hT       = wbf      + 5 * WSZ + 2 * FSZ;
    unsigned short* h2T      = hT;                              // alias
    unsigned short* obT      = hT       + (size_t)N * L * Cc;
    unsigned short* xa0T_all = obT      + (size_t)N * L * 512;
    unsigned short* xabT_all = xa0T_all + PATHBUF;
    unsigned short* kT_all   = xabT_all + PATHBUF;
    unsigned short* vN_all   = kT_all   + PATHBUF;
    unsigned short* m1T      = vN_all   + PATHBUF;
    unsigned short* qTall    = m1T;

    const unsigned short* WqB = wbf;
    const unsigned short* WkB = wbf + WSZ;
    const unsigned short* WvB = wbf + 2 * WSZ;
    const unsigned short* WoB = wbf + 3 * WSZ;
    const unsigned short* WpB = wbf + 4 * WSZ;
    const unsigned short* W1B = wbf + 5 * WSZ;
    const unsigned short* W2B = wbf + 5 * WSZ + FSZ;

    const float* nul = nullptr;
    float* nulf = nullptr;
    unsigned short* nulu = nullptr;

    {
        long long tot4 = (5LL * WSZ + 2LL * FSZ) / 4;
        wcvt_kernel<<<dim3((unsigned)((tot4 + 255) / 256)), dim3(256), 0, stream>>>(
            Wq, Wk, Wv, Wo, Wp, W1, W2, wbf);
    }
    bn_transpose_kernel<<<dim3(L / 64, Cc / 64, N), dim3(256), 0, stream>>>(
        x, n1g, n1b, n1m, n1v, hT, Cc, L);

    pool_bn_all_kernel<<<dim3(24, 2, N * 4), dim3(256), 0, stream>>>(
        x, n1g, n1b, n1m, n1v, xa0T_all, Cc, L);

    // grouped Q: all paths, block-diag Wq
    gemm_bf<1><<<dim3(L / 128, 4, N), dim3(256), 0, stream>>>(
        WqB, hT, 512, 128, L, Cc, (long long)L * Cc,
        bq, 0.125f, F_BIAS,
        nul, nul, nul, nul, nul, nul, nul, nul,
        nulf, 0, nul, 0, qTall, 512, 0, (long long)L * 512, 128);

    // grouped Wp (all paths)
    gemm_path<0><<<dim3(23, 1, N), dim3(256), 0, stream>>>(
        WpB, nulu, xa0T_all, nul, nul,
        agg, agb, agm, agv, ang, anb, anm, anv,
        xabT_all, nulu);

    // grouped Wk+Wv (all paths)
    gemm_path<1><<<dim3(23, 2, N), dim3(256), 0, stream>>>(
        WkB, WvB, xabT_all, bk, bv,
        nul, nul, nul, nul, nul, nul, nul, nul,
        kT_all, vN_all);

    // all-path attention
    attn_bf_all_kernel<<<dim3(L / 64, N * 2, 4), dim3(256), 0, stream>>>(
        qTall, kT_all, vN_all, obT, L);

    // grouped Wo: out = x + Wo @ o + bo (f32), h2T aux = bf16(bn2(out))
    gemm_bf<3><<<dim3(L / 128, 4, N), dim3(256), 0, stream>>>(
        WoB, obT, 512, 128, L, 512, (long long)L * 512,
        bo, 1.f, F_BIAS | F_RESID,
        n2g, n2b, n2m, n2v,
        nul, nul, nul, nul,
        out, (long long)Cc * L,
        x, (long long)Cc * L,
        h2T, Cc, 0, (long long)L * Cc, 128);

    // FFN
    gemm_bf<1><<<dim3(L / 128, FF / 128, N), dim3(256), 0, stream>>>(
        W1B, h2T, FF, Cc, L, Cc, (long long)L * Cc,
        b1, 1.f, F_BIAS | F_GELU,
        nul, nul, nul, nul, nul, nul, nul, nul,
        nulf, 0, nul, 0, m1T, FF, 0, (long long)L * FF, 0);

    gemm_bf<0><<<dim3(L / 128, Cc / 128, N), dim3(256), 0, stream>>>(
        W2B, m1T, Cc, FF, L, FF, (long long)L * FF,
        b2, 1.f, F_BIAS | F_RESID,
        nul, nul, nul, nul, nul, nul, nul, nul,
        out, (long long)Cc * L, out, (long long)Cc * L,
        nulu, 0, 0, 0, 0);
}

// Round 10
// 517.082 us; speedup vs baseline: 12.0462x; 1.0302x over previous
//
#include <hip/hip_runtime.h>
#include <math.h>

#define EPS 1e-5f

#define F_BIAS  1
#define F_DBN   2
#define F_GELU  4
#define F_RESID 8

typedef __attribute__((ext_vector_type(8))) __bf16 bf16x8;
typedef __attribute__((ext_vector_type(4))) float f32x4;
typedef __attribute__((ext_vector_type(8))) unsigned short u16x8;

__device__ __forceinline__ unsigned int pack2bf(float a, float b) {
    unsigned short ua = __builtin_bit_cast(unsigned short, (__bf16)a);
    unsigned short ub = __builtin_bit_cast(unsigned short, (__bf16)b);
    return (unsigned int)ua | ((unsigned int)ub << 16);
}

__device__ __forceinline__ void gload_lds16(const unsigned short* g, unsigned short* l) {
    __builtin_amdgcn_global_load_lds(
        (const __attribute__((address_space(1))) unsigned int*)g,
        (__attribute__((address_space(3))) unsigned int*)l,
        16, 0, 0);
}

// cheap tanh-gelu: u*sigmoid(2z)
__device__ __forceinline__ float gelu_f(float u) {
    float s = u * u;
    float w = u * fmaf(s, 0.0713548162726f, 1.59576912161f);
    float e = __expf(-w);
    return u * __builtin_amdgcn_rcpf(1.f + e);
}

// path constants: ratios {2,4,8,16}
__device__ __constant__ int c_LKS[4]  = {1536, 768, 384, 192};
__device__ __constant__ int c_OFFB[4] = {0, 1572864, 2359296, 2752512};

// ---------------------------------------------------------------------------
// weights fp32 -> bf16
// ---------------------------------------------------------------------------
__global__ __launch_bounds__(256) void wcvt_kernel(
    const float* __restrict__ Wq, const float* __restrict__ Wk,
    const float* __restrict__ Wv, const float* __restrict__ Wo,
    const float* __restrict__ Wp, const float* __restrict__ W1,
    const float* __restrict__ W2, unsigned short* __restrict__ dst)
{
    const int WSZ = 65536;
    const int FSZ = 1048576;
    int i4 = blockIdx.x * blockDim.x + threadIdx.x;
    long long i = (long long)i4 * 4;
    const long long total = 5LL * WSZ + 2LL * FSZ;
    if (i >= total) return;
    #pragma unroll
    for (int j = 0; j < 4; ++j) {
        long long idx = i + j;
        float v;
        if      (idx < WSZ)            v = Wq[idx];
        else if (idx < 2 * WSZ)        v = Wk[idx - WSZ];
        else if (idx < 3 * WSZ)        v = Wv[idx - 2 * WSZ];
        else if (idx < 4 * WSZ)        v = Wo[idx - 3 * WSZ];
        else if (idx < 5 * WSZ)        v = Wp[idx - 4 * WSZ];
        else if (idx < 5 * WSZ + FSZ)  v = W1[idx - 5 * WSZ];
        else                           v = W2[idx - 5 * WSZ - FSZ];
        dst[idx] = __builtin_bit_cast(unsigned short, (__bf16)v);
    }
}

// ---------------------------------------------------------------------------
// hT = bf16(bn1(x))^T : x (N,C,L) f32 -> hT (N,L,C) bf16
// ---------------------------------------------------------------------------
__global__ __launch_bounds__(256) void bn_transpose_kernel(
    const float* __restrict__ x,
    const float* __restrict__ g, const float* __restrict__ b,
    const float* __restrict__ bm, const float* __restrict__ bvv,
    unsigned short* __restrict__ hT, int C, int L)
{
    __shared__ float ps[64][65];
    const int l0 = blockIdx.x * 64, ct = blockIdx.y, n = blockIdx.z;
    const int tid = threadIdx.x;
    const int c = tid >> 2, q = tid & 3;
    const int cg = ct * 64 + c;
    float inv = g[cg] * rsqrtf(bvv[cg] + EPS);
    float add = b[cg] - bm[cg] * inv;
    const float* xp = x + ((size_t)n * C + cg) * L + l0 + q * 16;
    #pragma unroll
    for (int s = 0; s < 4; ++s) {
        float4 vv = *(const float4*)&xp[s * 4];
        ps[c][q * 16 + s * 4 + 0] = fmaf(vv.x, inv, add);
        ps[c][q * 16 + s * 4 + 1] = fmaf(vv.y, inv, add);
        ps[c][q * 16 + s * 4 + 2] = fmaf(vv.z, inv, add);
        ps[c][q * 16 + s * 4 + 3] = fmaf(vv.w, inv, add);
    }
    __syncthreads();
    #pragma unroll
    for (int j = 0; j < 2; ++j) {
        int row = (tid >> 3) + 32 * j;
        int cc0 = (tid & 7) * 8;
        unsigned int w0 = pack2bf(ps[cc0 + 0][row], ps[cc0 + 1][row]);
        unsigned int w1 = pack2bf(ps[cc0 + 2][row], ps[cc0 + 3][row]);
        unsigned int w2 = pack2bf(ps[cc0 + 4][row], ps[cc0 + 5][row]);
        unsigned int w3 = pack2bf(ps[cc0 + 6][row], ps[cc0 + 7][row]);
        *(uint4*)&hT[((size_t)n * L + l0 + row) * C + ct * 64 + cc0] =
            make_uint4(w0, w1, w2, w3);
    }
}

// ---------------------------------------------------------------------------
// Pool+BN1 for ALL paths in one dispatch: grid (24, 2, N*4)
// ---------------------------------------------------------------------------
__global__ __launch_bounds__(256) void pool_bn_all_kernel(
    const float* __restrict__ x,
    const float* __restrict__ g, const float* __restrict__ b,
    const float* __restrict__ bm, const float* __restrict__ bvv,
    unsigned short* __restrict__ xa0T_all, int C, int L)
{
    const int p = blockIdx.z & 3;
    const int n = blockIdx.z >> 2;
    const int Lk = c_LKS[p];
    const int lk0 = blockIdx.x * 64;
    if (lk0 >= Lk) return;
    const int r = L / Lk;
    const int ct = blockIdx.y;
    __shared__ float ps[64][65];
    const int tid = threadIdx.x;
    const int c = tid >> 2, q = tid & 3;
    const int cg = p * 128 + ct * 64 + c;
    float inv = g[cg] * rsqrtf(bvv[cg] + EPS);
    float add = b[cg] - bm[cg] * inv;
    const float* xp = x + ((size_t)n * C + cg) * L;
    float rinv = 1.0f / (float)r;
    #pragma unroll
    for (int s = 0; s < 16; ++s) {
        int lk = q * 16 + s;
        const float* base = xp + (size_t)(lk0 + lk) * r;
        float sum = 0.f, mx = -INFINITY;
        for (int j = 0; j < r; j += 2) {
            float2 vv = *(const float2*)&base[j];
            float t0 = fmaf(vv.x, inv, add);
            float t1 = fmaf(vv.y, inv, add);
            sum += t0 + t1;
            mx = fmaxf(mx, fmaxf(t0, t1));
        }
        ps[c][lk] = sum * rinv + mx;
    }
    __syncthreads();
    unsigned short* dst = xa0T_all + c_OFFB[p];
    #pragma unroll
    for (int j = 0; j < 2; ++j) {
        int row = (tid >> 3) + 32 * j;
        int cc0 = (tid & 7) * 8;
        unsigned int w0 = pack2bf(ps[cc0 + 0][row], ps[cc0 + 1][row]);
        unsigned int w1 = pack2bf(ps[cc0 + 2][row], ps[cc0 + 3][row]);
        unsigned int w2 = pack2bf(ps[cc0 + 4][row], ps[cc0 + 5][row]);
        unsigned int w3 = pack2bf(ps[cc0 + 6][row], ps[cc0 + 7][row]);
        *(uint4*)&dst[((size_t)n * Lk + lk0 + row) * 128 + ct * 64 + cc0] =
            make_uint4(w0, w1, w2, w3);
    }
}

// ---------------------------------------------------------------------------
// bf16 MFMA GEMM 128x128, counted-vmcnt 2-buffer pipeline (Wq/Wo shapes).
// ---------------------------------------------------------------------------
template<int OMODE>
__global__ __launch_bounds__(256) void gemm_bf(
    const unsigned short* __restrict__ A, const unsigned short* __restrict__ BT,
    int M, int K, int Npos, int ldBT, long long strideBT,
    const float* __restrict__ bias, float oscale, int flags,
    const float* __restrict__ g1, const float* __restrict__ b1p,
    const float* __restrict__ m1p, const float* __restrict__ v1p,
    const float* __restrict__ g2, const float* __restrict__ b2p,
    const float* __restrict__ m2p, const float* __restrict__ v2p,
    float* __restrict__ outN, long long strideN,
    const float* __restrict__ resid, long long strideR,
    unsigned short* __restrict__ outT, int ldT, int moff, long long strideT,
    int gKoff)
{
    __shared__ __align__(16) unsigned short As[2][128][32];
    __shared__ __align__(16) unsigned short Bs[2][128][32];

    const int tid = threadIdx.x;

    const int gdx = gridDim.x, gdy = gridDim.y;
    const int nwg = gdx * gdy * gridDim.z;
    int bid = blockIdx.x + gdx * (blockIdx.y + gdy * blockIdx.z);
    {
        int q = nwg >> 3, rr = nwg & 7;
        int xcd = bid & 7, idx = bid >> 3;
        bid = (xcd < rr ? xcd * (q + 1) : rr * (q + 1) + (xcd - rr) * q) + idx;
    }
    const int bx = bid % gdx;
    const int by = (bid / gdx) % gdy;
    const int bz = bid / (gdx * gdy);

    const int m0 = by * 128;
    const int p0 = bx * 128;
    const unsigned short* Bn = BT + (size_t)bz * strideBT
                              + (size_t)(m0 >> 7) * gKoff;

    const int wave = tid >> 6;
    const int lane = tid & 63;
    const int qcol = lane & 15;
    const int hi   = lane >> 4;
    const int wr   = wave >> 1;
    const int wc   = wave & 1;
    const int lrow = lane >> 2;
    const int lseg = (lane & 3) * 8;

    const unsigned short* aR0 = A + (size_t)(m0 + wave * 32 + lrow) * K + lseg;
    const unsigned short* aR1 = aR0 + (size_t)16 * K;
    int pr0 = p0 + wave * 32 + lrow;      if (pr0 > Npos - 1) pr0 = Npos - 1;
    int pr1 = p0 + wave * 32 + 16 + lrow; if (pr1 > Npos - 1) pr1 = Npos - 1;
    const unsigned short* bR0 = Bn + (size_t)pr0 * ldBT + lseg;
    const unsigned short* bR1 = Bn + (size_t)pr1 * ldBT + lseg;
    unsigned short* ldsA0 = &As[0][wave * 32][0];
    unsigned short* ldsA1 = &As[0][wave * 32 + 16][0];
    unsigned short* ldsB0 = &Bs[0][wave * 32][0];
    unsigned short* ldsB1 = &Bs[0][wave * 32 + 16][0];
    const int bufStride = 128 * 32;

    auto STAGE = [&](int b, int t) {
        const int ko = t * 32;
        gload_lds16(aR0 + ko, ldsA0 + b * bufStride);
        gload_lds16(aR1 + ko, ldsA1 + b * bufStride);
        gload_lds16(bR0 + ko, ldsB0 + b * bufStride);
        gload_lds16(bR1 + ko, ldsB1 + b * bufStride);
    };

    f32x4 acc[4][4] = {};
    const int nt = K >> 5;

    STAGE(0, 0);
    STAGE(1, 1);

    auto MFMA_STEP = [&](int b) {
        bf16x8 af[4], bfr[4];
        #pragma unroll
        for (int mi = 0; mi < 4; ++mi)
            af[mi] = *(const bf16x8*)&As[b][wr * 64 + mi * 16 + qcol][hi * 8];
        #pragma unroll
        for (int ni = 0; ni < 4; ++ni)
            bfr[ni] = *(const bf16x8*)&Bs[b][wc * 64 + ni * 16 + qcol][hi * 8];
        #pragma unroll
        for (int mi = 0; mi < 4; ++mi)
            #pragma unroll
            for (int ni = 0; ni < 4; ++ni)
                acc[mi][ni] = __builtin_amdgcn_mfma_f32_16x16x32_bf16(
                    af[mi], bfr[ni], acc[mi][ni], 0, 0, 0);
    };

    int cur = 0;
    for (int t = 0; t < nt - 1; ++t) {
        asm volatile("s_waitcnt vmcnt(4)" ::: "memory");
        __builtin_amdgcn_s_barrier();
        MFMA_STEP(cur);
        __builtin_amdgcn_s_barrier();
        if (t + 2 < nt) STAGE(cur, t + 2);
        cur ^= 1;
    }
    asm volatile("s_waitcnt vmcnt(0)" ::: "memory");
    __builtin_amdgcn_s_barrier();
    MFMA_STEP(cur);

    float* Cn = outN + (size_t)bz * strideN;
    const float* Rn = resid + (size_t)bz * strideR;
    unsigned short* Tn = outT + (size_t)bz * strideT;

    #pragma unroll
    for (int mi = 0; mi < 4; ++mi) {
        const int mb = m0 + wr * 64 + mi * 16 + hi * 4;
        float4 bv4 = make_float4(0.f, 0.f, 0.f, 0.f);
        if (flags & F_BIAS) bv4 = *(const float4*)&bias[mb];
        float s1[4], t1[4];
        if ((flags & F_DBN) || OMODE == 3) {
            float4 gg = *(const float4*)&g1[mb];
            float4 bb = *(const float4*)&b1p[mb];
            float4 mm = *(const float4*)&m1p[mb];
            float4 vv = *(const float4*)&v1p[mb];
            float gga[4] = {gg.x, gg.y, gg.z, gg.w};
            float bba[4] = {bb.x, bb.y, bb.z, bb.w};
            float mma[4] = {mm.x, mm.y, mm.z, mm.w};
            float vva[4] = {vv.x, vv.y, vv.z, vv.w};
            #pragma unroll
            for (int r2 = 0; r2 < 4; ++r2) {
                float iv = gga[r2] * rsqrtf(vva[r2] + EPS);
                s1[r2] = iv; t1[r2] = bba[r2] - mma[r2] * iv;
            }
        }
        float s2[4], t2[4];
        if (flags & F_DBN) {
            float4 gg = *(const float4*)&g2[mb];
            float4 bb = *(const float4*)&b2p[mb];
            float4 mm = *(const float4*)&m2p[mb];
            float4 vv = *(const float4*)&v2p[mb];
            float gga[4] = {gg.x, gg.y, gg.z, gg.w};
            float bba[4] = {bb.x, bb.y, bb.z, bb.w};
            float mma[4] = {mm.x, mm.y, mm.z, mm.w};
            float vva[4] = {vv.x, vv.y, vv.z, vv.w};
            #pragma unroll
            for (int r2 = 0; r2 < 4; ++r2) {
                float iv = gga[r2] * rsqrtf(vva[r2] + EPS);
                s2[r2] = iv; t2[r2] = bba[r2] - mma[r2] * iv;
            }
        }
        const float ba[4] = {bv4.x, bv4.y, bv4.z, bv4.w};
        #pragma unroll
        for (int ni = 0; ni < 4; ++ni) {
            const int cp = p0 + wc * 64 + ni * 16 + qcol;
            if (cp >= Npos) continue;
            float vals[4];
            #pragma unroll
            for (int r2 = 0; r2 < 4; ++r2) {
                float val = (acc[mi][ni][r2] + ba[r2]) * oscale;
                if (flags & F_DBN) {
                    val = fmaf(val, s1[r2], t1[r2]);
                    val = fmaf(val, s2[r2], t2[r2]);
                }
                if (flags & F_GELU) val = gelu_f(val);
                vals[r2] = val;
            }
            if (OMODE == 0 || OMODE == 3) {
                #pragma unroll
                for (int r2 = 0; r2 < 4; ++r2) {
                    size_t off = (size_t)(mb + r2) * Npos + cp;
                    float v = vals[r2];
                    if (flags & F_RESID) v += Rn[off];
                    Cn[off] = v;
                    vals[r2] = v;
                }
            }
            if (OMODE == 1) {
                *(uint2*)&Tn[(size_t)cp * ldT + moff + mb] =
                    make_uint2(pack2bf(vals[0], vals[1]), pack2bf(vals[2], vals[3]));
            }
            if (OMODE == 2) {
                #pragma unroll
                for (int r2 = 0; r2 < 4; ++r2)
                    Tn[(size_t)(mb + r2) * Npos + cp] =
                        __builtin_bit_cast(unsigned short, (__bf16)vals[r2]);
            }
            if (OMODE == 3) {
                float a0 = fmaf(vals[0], s1[0], t1[0]);
                float a1 = fmaf(vals[1], s1[1], t1[1]);
                float a2 = fmaf(vals[2], s1[2], t1[2]);
                float a3 = fmaf(vals[3], s1[3], t1[3]);
                *(uint2*)&Tn[(size_t)cp * ldT + moff + mb] =
                    make_uint2(pack2bf(a0, a1), pack2bf(a2, a3));
            }
        }
    }
}

// ---------------------------------------------------------------------------
// bf16 MFMA GEMM 256x256, 8 waves (512 thr), BK=64, counted-vmcnt 2-buffer
// pipeline with XOR-swizzled LDS (T2: 128B rows would be 16-way conflicted;
// swizzle pattern identical to the proven attention staging: source seg
// pre-XOR + read-side XOR, slot = seg ^ (row&7)).
// Requires M%256==0, Npos%256==0, K%64==0, K>=128. FFN (W1/W2) only.
// OMODE: 0 = f32 natural out (+resid);  1 = bf16 transposed out [cp][ldT].
// ---------------------------------------------------------------------------
template<int OMODE, int FLAGS>
__global__ __launch_bounds__(512, 1) void gemm_bf256(
    const unsigned short* __restrict__ A, const unsigned short* __restrict__ BT,
    int K, int Npos, int ldBT, long long strideBT,
    const float* __restrict__ bias,
    float* __restrict__ outN, long long strideN,
    const float* __restrict__ resid, long long strideR,
    unsigned short* __restrict__ outT, int ldT, long long strideT)
{
    __shared__ __align__(16) unsigned short As[2][256][64];
    __shared__ __align__(16) unsigned short Bs[2][256][64];

    const int tid = threadIdx.x;

    // bijective XCD-chunked swizzle (m204)
    const int gdx = gridDim.x, gdy = gridDim.y;
    const int nwg = gdx * gdy * gridDim.z;
    int bid = blockIdx.x + gdx * (blockIdx.y + gdy * blockIdx.z);
    {
        int q = nwg >> 3, rr = nwg & 7;
        int xcd = bid & 7, idx = bid >> 3;
        bid = (xcd < rr ? xcd * (q + 1) : rr * (q + 1) + (xcd - rr) * q) + idx;
    }
    const int bx = bid % gdx;
    const int by = (bid / gdx) % gdy;
    const int bz = bid / (gdx * gdy);

    const int m0 = by * 256;
    const int p0 = bx * 256;
    const unsigned short* Bn = BT + (size_t)bz * strideBT;

    const int wave = tid >> 6;
    const int lane = tid & 63;
    const int qcol = lane & 15;
    const int hi   = lane >> 4;
    const int wr   = wave >> 2;      // 0..1  (M-half, 128 rows)
    const int wc   = wave & 3;       // 0..3  (N-quarter, 64 cols)

    // staging: lane -> row l>>3, LDS slot l&7; SOURCE seg = (l&7)^(l>>3)
    // => LDS slot (row,s) holds global seg s^(row&7); read-XOR inverts.
    const int srow = lane >> 3;
    const int sxor = ((lane & 7) ^ srow) * 8;

    const unsigned short* aS = A + (size_t)(m0 + wave * 32 + srow) * K + sxor;
    const unsigned short* bS = Bn + (size_t)(p0 + wave * 32 + srow) * ldBT + sxor;
    unsigned short* ldsA = &As[0][wave * 32][0];
    unsigned short* ldsB = &Bs[0][wave * 32][0];
    const int bufStride = 256 * 64;

    auto STAGE = [&](int b, int t) {      // 8 vm-ops per wave
        const int ko = t * 64;
        #pragma unroll
        for (int j = 0; j < 4; ++j) {
            gload_lds16(aS + (size_t)(j * 8) * K + ko,
                        ldsA + b * bufStride + j * 8 * 64);
            gload_lds16(bS + (size_t)(j * 8) * ldBT + ko,
                        ldsB + b * bufStride + j * 8 * 64);
        }
    };

    // read-side swizzled col (u16): k-half kk seg = hi + 4*kk; slot = seg^(qcol&7)
    const int xr0 = (hi ^ (qcol & 7)) * 8;

    f32x4 acc[8][4] = {};
    const int nt = K >> 6;

    STAGE(0, 0);
    STAGE(1, 1);

    auto MFMA_STEP = [&](int b) {
        #pragma unroll
        for (int kk = 0; kk < 2; ++kk) {
            const int xx = xr0 ^ (kk << 5);
            bf16x8 af[8], bfr[4];
            #pragma unroll
            for (int mi = 0; mi < 8; ++mi)
                af[mi] = *(const bf16x8*)&As[b][wr * 128 + mi * 16 + qcol][xx];
            #pragma unroll
            for (int ni = 0; ni < 4; ++ni)
                bfr[ni] = *(const bf16x8*)&Bs[b][wc * 64 + ni * 16 + qcol][xx];
            #pragma unroll
            for (int mi = 0; mi < 8; ++mi)
                #pragma unroll
                for (int ni = 0; ni < 4; ++ni)
                    acc[mi][ni] = __builtin_amdgcn_mfma_f32_16x16x32_bf16(
                        af[mi], bfr[ni], acc[mi][ni], 0, 0, 0);
        }
    };

    int cur = 0;
    for (int t = 0; t < nt - 1; ++t) {
        asm volatile("s_waitcnt vmcnt(8)" ::: "memory");
        __builtin_amdgcn_s_barrier();
        MFMA_STEP(cur);
        __builtin_amdgcn_s_barrier();
        if (t + 2 < nt) STAGE(cur, t + 2);
        cur ^= 1;
    }
    asm volatile("s_waitcnt vmcnt(0)" ::: "memory");
    __builtin_amdgcn_s_barrier();
    MFMA_STEP(cur);

    float* Cn = outN + (size_t)bz * strideN;
    const float* Rn = resid + (size_t)bz * strideR;
    unsigned short* Tn = outT + (size_t)bz * strideT;

    #pragma unroll
    for (int mi = 0; mi < 8; ++mi) {
        const int mb = m0 + wr * 128 + mi * 16 + hi * 4;
        float ba[4] = {0.f, 0.f, 0.f, 0.f};
        if (FLAGS & F_BIAS) {
            float4 bv4 = *(const float4*)&bias[mb];
            ba[0] = bv4.x; ba[1] = bv4.y; ba[2] = bv4.z; ba[3] = bv4.w;
        }
        #pragma unroll
        for (int ni = 0; ni < 4; ++ni) {
            const int cp = p0 + wc * 64 + ni * 16 + qcol;
            float vals[4];
            #pragma unroll
            for (int r2 = 0; r2 < 4; ++r2) {
                float val = acc[mi][ni][r2] + ba[r2];
                if (FLAGS & F_GELU) val = gelu_f(val);
                vals[r2] = val;
            }
            if (OMODE == 0) {
                #pragma unroll
                for (int r2 = 0; r2 < 4; ++r2) {
                    size_t off = (size_t)(mb + r2) * Npos + cp;
                    float v = vals[r2];
                    if (FLAGS & F_RESID) v += Rn[off];
                    Cn[off] = v;
                }
            } else {
                *(uint2*)&Tn[(size_t)cp * ldT + mb] =
                    make_uint2(pack2bf(vals[0], vals[1]), pack2bf(vals[2], vals[3]));
            }
        }
    }
}

// ---------------------------------------------------------------------------
// Grouped per-path GEMM (K=128, M=128 per path), all 4 paths in one dispatch.
// ---------------------------------------------------------------------------
template<int MODE>
__global__ __launch_bounds__(256) void gemm_path(
    const unsigned short* __restrict__ A0, const unsigned short* __restrict__ A1,
    const unsigned short* __restrict__ Bsrc,
    const float* __restrict__ bias0, const float* __restrict__ bias1,
    const float* __restrict__ agg, const float* __restrict__ agb,
    const float* __restrict__ agm, const float* __restrict__ agv,
    const float* __restrict__ ang, const float* __restrict__ anb,
    const float* __restrict__ anm, const float* __restrict__ anv,
    unsigned short* __restrict__ out0, unsigned short* __restrict__ out1)
{
    __shared__ __align__(16) unsigned short As[2][128][32];
    __shared__ __align__(16) unsigned short Bs[2][128][32];

    const int tid = threadIdx.x;
    const int gdx = gridDim.x, gdy = gridDim.y;
    const int nwg = gdx * gdy * gridDim.z;
    int bid = blockIdx.x + gdx * (blockIdx.y + gdy * blockIdx.z);
    {
        int q = nwg >> 3, rr = nwg & 7;
        int xcd = bid & 7, idx = bid >> 3;
        bid = (xcd < rr ? xcd * (q + 1) : rr * (q + 1) + (xcd - rr) * q) + idx;
    }
    const int bx = bid % gdx;
    const int by = (bid / gdx) % gdy;
    const int bz = bid / (gdx * gdy);

    int p, px;
    if      (bx < 12) { p = 0; px = bx; }
    else if (bx < 18) { p = 1; px = bx - 12; }
    else if (bx < 21) { p = 2; px = bx - 18; }
    else              { p = 3; px = bx - 21; }
    const int Lk = c_LKS[p];
    const int offb = c_OFFB[p];
    const int c0 = p * 128;
    const int p0 = px * 128;
    const int K = 128;

    const unsigned short* A = (MODE == 1 && by == 1 ? A1 : A0) + p * 16384;
    const unsigned short* Bn = Bsrc + offb + (size_t)bz * Lk * 128;

    const int wave = tid >> 6;
    const int lane = tid & 63;
    const int qcol = lane & 15;
    const int hi   = lane >> 4;
    const int wr   = wave >> 1;
    const int wc   = wave & 1;
    const int lrow = lane >> 2;
    const int lseg = (lane & 3) * 8;

    const unsigned short* aR0 = A + (size_t)(wave * 32 + lrow) * K + lseg;
    const unsigned short* aR1 = aR0 + (size_t)16 * K;
    int pr0 = p0 + wave * 32 + lrow;      if (pr0 > Lk - 1) pr0 = Lk - 1;
    int pr1 = p0 + wave * 32 + 16 + lrow; if (pr1 > Lk - 1) pr1 = Lk - 1;
    const unsigned short* bR0 = Bn + (size_t)pr0 * 128 + lseg;
    const unsigned short* bR1 = Bn + (size_t)pr1 * 128 + lseg;
    unsigned short* ldsA0 = &As[0][wave * 32][0];
    unsigned short* ldsA1 = &As[0][wave * 32 + 16][0];
    unsigned short* ldsB0 = &Bs[0][wave * 32][0];
    unsigned short* ldsB1 = &Bs[0][wave * 32 + 16][0];
    const int bufStride = 128 * 32;

    auto STAGE = [&](int b, int t) {
        const int ko = t * 32;
        gload_lds16(aR0 + ko, ldsA0 + b * bufStride);
        gload_lds16(aR1 + ko, ldsA1 + b * bufStride);
        gload_lds16(bR0 + ko, ldsB0 + b * bufStride);
        gload_lds16(bR1 + ko, ldsB1 + b * bufStride);
    };

    f32x4 acc[4][4] = {};
    STAGE(0, 0);
    STAGE(1, 1);

    auto MFMA_STEP = [&](int b) {
        bf16x8 af[4], bfr[4];
        #pragma unroll
        for (int mi = 0; mi < 4; ++mi)
            af[mi] = *(const bf16x8*)&As[b][wr * 64 + mi * 16 + qcol][hi * 8];
        #pragma unroll
        for (int ni = 0; ni < 4; ++ni)
            bfr[ni] = *(const bf16x8*)&Bs[b][wc * 64 + ni * 16 + qcol][hi * 8];
        #pragma unroll
        for (int mi = 0; mi < 4; ++mi)
            #pragma unroll
            for (int ni = 0; ni < 4; ++ni)
                acc[mi][ni] = __builtin_amdgcn_mfma_f32_16x16x32_bf16(
                    af[mi], bfr[ni], acc[mi][ni], 0, 0, 0);
    };

    int cur = 0;
    const int nt = 4;
    for (int t = 0; t < nt - 1; ++t) {
        asm volatile("s_waitcnt vmcnt(4)" ::: "memory");
        __builtin_amdgcn_s_barrier();
        MFMA_STEP(cur);
        __builtin_amdgcn_s_barrier();
        if (t + 2 < nt) STAGE(cur, t + 2);
        cur ^= 1;
    }
    asm volatile("s_waitcnt vmcnt(0)" ::: "memory");
    __builtin_amdgcn_s_barrier();
    MFMA_STEP(cur);

    const bool isV = (MODE == 1 && by == 1);
    unsigned short* Tn = (isV ? out1 : out0) + offb + (size_t)bz * Lk * 128;
    const float* bias = (MODE == 0) ? nullptr : (by == 0 ? bias0 : bias1);

    #pragma unroll
    for (int mi = 0; mi < 4; ++mi) {
        const int mb = wr * 64 + mi * 16 + hi * 4;
        float ba[4] = {0.f, 0.f, 0.f, 0.f};
        if (MODE == 1) {
            float4 bv4 = *(const float4*)&bias[c0 + mb];
            ba[0] = bv4.x; ba[1] = bv4.y; ba[2] = bv4.z; ba[3] = bv4.w;
        }
        float s1[4], t1[4], s2[4], t2[4];
        if (MODE == 0) {
            #pragma unroll
            for (int r2 = 0; r2 < 4; ++r2) {
                int gm = c0 + mb + r2;
                float i1 = agg[gm] * rsqrtf(agv[gm] + EPS);
                s1[r2] = i1; t1[r2] = agb[gm] - agm[gm] * i1;
                float i2 = ang[gm] * rsqrtf(anv[gm] + EPS);
                s2[r2] = i2; t2[r2] = anb[gm] - anm[gm] * i2;
            }
        }
        #pragma unroll
        for (int ni = 0; ni < 4; ++ni) {
            const int cp = p0 + wc * 64 + ni * 16 + qcol;
            if (cp >= Lk) continue;
            float vals[4];
            #pragma unroll
            for (int r2 = 0; r2 < 4; ++r2) {
                float val = acc[mi][ni][r2] + ba[r2];
                if (MODE == 0) {
                    val = fmaf(val, s1[r2], t1[r2]);
                    val = fmaf(val, s2[r2], t2[r2]);
                }
                vals[r2] = val;
            }
            if (!isV) {
                *(uint2*)&Tn[(size_t)cp * 128 + mb] =
                    make_uint2(pack2bf(vals[0], vals[1]), pack2bf(vals[2], vals[3]));
            } else {
                #pragma unroll
                for (int r2 = 0; r2 < 4; ++r2)
                    Tn[(size_t)(mb + r2) * Lk + cp] =
                        __builtin_bit_cast(unsigned short, (__bf16)vals[r2]);
            }
        }
    }
}

// ---------------------------------------------------------------------------
// Flash attention, all paths; K/V staged in block-shared LDS (counted-vmcnt
// 2-buffer pipeline, XOR-swizzled both sides). grid (48, N*2, 4).
// ---------------------------------------------------------------------------
__global__ __launch_bounds__(256) void attn_bf_all_kernel(
    const unsigned short* __restrict__ qT, const unsigned short* __restrict__ kT_all,
    const unsigned short* __restrict__ vN_all, unsigned short* __restrict__ obT,
    int L)
{
    const int p = blockIdx.z;
    const int Lk = c_LKS[p];
    const int offb = c_OFFB[p];
    const int l0 = blockIdx.x * 64;
    const int nh = blockIdx.y;
    const int n = nh >> 1, h = nh & 1;
    const unsigned short* qn = qT + (size_t)n * L * 512 + p * 128 + h * 64;
    const unsigned short* kn = kT_all + offb + (size_t)n * Lk * 128 + h * 64;
    const unsigned short* vn = vN_all + offb + ((size_t)n * 128 + h * 64) * Lk;
    unsigned short*       on = obT + (size_t)n * L * 512 + p * 128 + h * 64;

    __shared__ __align__(16) unsigned short Ks[2][64][64];
    __shared__ __align__(16) unsigned short Vs[2][64][64];
    __shared__ __align__(16) unsigned short Ps[4][16][72];

    const int tid = threadIdx.x;
    const int wave = tid >> 6;
    const int lane = tid & 63;
    const int qcol = lane & 15;
    const int hi   = lane >> 4;
    const int ql   = wave * 16 + qcol;

    const int srow = lane >> 3;
    const int sxor = (lane & 7) ^ srow;
    const unsigned short* kS0 = kn + (size_t)(wave * 16 + srow) * 128 + sxor * 8;
    const unsigned short* kS1 = kn + (size_t)(wave * 16 + 8 + srow) * 128 + sxor * 8;
    const unsigned short* vS0 = vn + (size_t)(wave * 16 + srow) * Lk + sxor * 8;
    const unsigned short* vS1 = vn + (size_t)(wave * 16 + 8 + srow) * Lk + sxor * 8;
    unsigned short* ldsK0 = &Ks[0][wave * 16][0];
    unsigned short* ldsK1 = &Ks[0][wave * 16 + 8][0];
    unsigned short* ldsV0 = &Vs[0][wave * 16][0];
    unsigned short* ldsV1 = &Vs[0][wave * 16 + 8][0];
    const int bufStride = 64 * 64;

    auto STAGE = [&](int b, int t) {
        const int mc = t * 64;
        gload_lds16(kS0 + (size_t)mc * 128, ldsK0 + b * bufStride);
        gload_lds16(kS1 + (size_t)mc * 128, ldsK1 + b * bufStride);
        gload_lds16(vS0 + mc, ldsV0 + b * bufStride);
        gload_lds16(vS1 + mc, ldsV1 + b * bufStride);
    };

    const int x0 = (hi ^ (qcol & 7)) * 8;
    const int x1 = x0 ^ 32;

    bf16x8 qf0 = *(const bf16x8*)&qn[(size_t)(l0 + ql) * 512 + hi * 8];
    bf16x8 qf1 = *(const bf16x8*)&qn[(size_t)(l0 + ql) * 512 + 32 + hi * 8];

    f32x4 o_acc[4] = {};
    float mrow = -INFINITY, lrow = 0.f;
    const int nt = Lk >> 6;

    STAGE(0, 0);
    STAGE(1, 1);

    auto COMPUTE = [&](int b) {
        f32x4 sacc[4];
        #pragma unroll
        for (int kt = 0; kt < 4; ++kt) {
            bf16x8 k0 = *(const bf16x8*)&Ks[b][kt * 16 + qcol][x0];
            bf16x8 k1 = *(const bf16x8*)&Ks[b][kt * 16 + qcol][x1];
            f32x4 a = {};
            a = __builtin_amdgcn_mfma_f32_16x16x32_bf16(k0, qf0, a, 0, 0, 0);
            a = __builtin_amdgcn_mfma_f32_16x16x32_bf16(k1, qf1, a, 0, 0, 0);
            sacc[kt] = a;
        }
        float m0 = fmaxf(fmaxf(sacc[0][0], sacc[0][1]), fmaxf(sacc[0][2], sacc[0][3]));
        float m1 = fmaxf(fmaxf(sacc[1][0], sacc[1][1]), fmaxf(sacc[1][2], sacc[1][3]));
        float m2 = fmaxf(fmaxf(sacc[2][0], sacc[2][1]), fmaxf(sacc[2][2], sacc[2][3]));
        float m3 = fmaxf(fmaxf(sacc[3][0], sacc[3][1]), fmaxf(sacc[3][2], sacc[3][3]));
        float cm = fmaxf(fmaxf(m0, m1), fmaxf(m2, m3));
        cm = fmaxf(cm, __shfl_xor(cm, 16));
        cm = fmaxf(cm, __shfl_xor(cm, 32));
        float nm = fmaxf(mrow, cm);
        float alpha = __expf(mrow - nm);
        float csum = 0.f;
        unsigned int pw[4][2];
        #pragma unroll
        for (int kt = 0; kt < 4; ++kt) {
            float p0 = __expf(sacc[kt][0] - nm);
            float p1 = __expf(sacc[kt][1] - nm);
            float p2 = __expf(sacc[kt][2] - nm);
            float p3 = __expf(sacc[kt][3] - nm);
            csum += (p0 + p1) + (p2 + p3);
            pw[kt][0] = pack2bf(p0, p1);
            pw[kt][1] = pack2bf(p2, p3);
        }
        csum += __shfl_xor(csum, 16);
        csum += __shfl_xor(csum, 32);
        lrow = lrow * alpha + csum;
        mrow = nm;

        #pragma unroll
        for (int kt = 0; kt < 4; ++kt)
            *(uint2*)&Ps[wave][qcol][kt * 16 + hi * 4] =
                make_uint2(pw[kt][0], pw[kt][1]);

        #pragma unroll
        for (int et = 0; et < 4; ++et)
            #pragma unroll
            for (int r2 = 0; r2 < 4; ++r2) o_acc[et][r2] *= alpha;

        bf16x8 pf0 = *(const bf16x8*)&Ps[wave][qcol][hi * 8];
        bf16x8 pf1 = *(const bf16x8*)&Ps[wave][qcol][hi * 8 + 32];
        #pragma unroll
        for (int et = 0; et < 4; ++et) {
            bf16x8 v0 = *(const bf16x8*)&Vs[b][et * 16 + qcol][x0];
            bf16x8 v1 = *(const bf16x8*)&Vs[b][et * 16 + qcol][x1];
            o_acc[et] = __builtin_amdgcn_mfma_f32_16x16x32_bf16(v0, pf0, o_acc[et], 0, 0, 0);
            o_acc[et] = __builtin_amdgcn_mfma_f32_16x16x32_bf16(v1, pf1, o_acc[et], 0, 0, 0);
        }
    };

    int cur = 0;
    for (int t = 0; t < nt - 1; ++t) {
        asm volatile("s_waitcnt vmcnt(4)" ::: "memory");
        __builtin_amdgcn_s_barrier();
        COMPUTE(cur);
        __builtin_amdgcn_s_barrier();
        if (t + 2 < nt) STAGE(cur, t + 2);
        cur ^= 1;
    }
    asm volatile("s_waitcnt vmcnt(0)" ::: "memory");
    __builtin_amdgcn_s_barrier();
    COMPUTE(cur);

    float invl = 1.f / lrow;
    #pragma unroll
    for (int et = 0; et < 4; ++et) {
        float a0 = o_acc[et][0] * invl, a1 = o_acc[et][1] * invl;
        float a2 = o_acc[et][2] * invl, a3 = o_acc[et][3] * invl;
        *(uint2*)&on[(size_t)(l0 + ql) * 512 + et * 16 + hi * 4] =
            make_uint2(pack2bf(a0, a1), pack2bf(a2, a3));
    }
}

// ---------------------------------------------------------------------------
extern "C" void kernel_launch(void* const* d_in, const int* in_sizes, int n_in,
                              void* d_out, int out_size, void* d_ws, size_t ws_size,
                              hipStream_t stream)
{
    const float* x   = (const float*)d_in[0];
    const float* n1g = (const float*)d_in[1];
    const float* n1b = (const float*)d_in[2];
    const float* n1m = (const float*)d_in[3];
    const float* n1v = (const float*)d_in[4];
    const float* n2g = (const float*)d_in[5];
    const float* n2b = (const float*)d_in[6];
    const float* n2m = (const float*)d_in[7];
    const float* n2v = (const float*)d_in[8];
    const float* Wq  = (const float*)d_in[9];
    const float* Wk  = (const float*)d_in[10];
    const float* Wv  = (const float*)d_in[11];
    const float* Wo  = (const float*)d_in[12];
    const float* Wp  = (const float*)d_in[13];
    const float* bq  = (const float*)d_in[14];
    const float* bk  = (const float*)d_in[15];
    const float* bv  = (const float*)d_in[16];
    const float* bo  = (const float*)d_in[17];
    const float* agg = (const float*)d_in[18];
    const float* agb = (const float*)d_in[19];
    const float* agm = (const float*)d_in[20];
    const float* agv = (const float*)d_in[21];
    const float* ang = (const float*)d_in[22];
    const float* anb = (const float*)d_in[23];
    const float* anm = (const float*)d_in[24];
    const float* anv = (const float*)d_in[25];
    const float* W1  = (const float*)d_in[26];
    const float* b1  = (const float*)d_in[27];
    const float* W2  = (const float*)d_in[28];
    const float* b2  = (const float*)d_in[29];

    float* out = (float*)d_out;
    unsigned short* wsb = (unsigned short*)d_ws;

    const int N = 8, Cc = 512, L = 3072, FF = 2048;
    const int WSZ = 65536, FSZ = 1048576;
    const size_t PATHBUF = 2949120;

    unsigned short* wbf      = wsb;
    unsigned short* hT       = wbf      + 5 * WSZ + 2 * FSZ;
    unsigned short* h2T      = hT;                              // alias
    unsigned short* obT      = hT       + (size_t)N * L * Cc;
    unsigned short* xa0T_all = obT      + (size_t)N * L * 512;
    unsigned short* xabT_all = xa0T_all + PATHBUF;
    unsigned short* kT_all   = xabT_all + PATHBUF;
    unsigned short* vN_all   = kT_all   + PATHBUF;
    unsigned short* m1T      = vN_all   + PATHBUF;
    unsigned short* qTall    = m1T;

    const unsigned short* WqB = wbf;
    const unsigned short* WkB = wbf + WSZ;
    const unsigned short* WvB = wbf + 2 * WSZ;
    const unsigned short* WoB = wbf + 3 * WSZ;
    const unsigned short* WpB = wbf + 4 * WSZ;
    const unsigned short* W1B = wbf + 5 * WSZ;
    const unsigned short* W2B = wbf + 5 * WSZ + FSZ;

    const float* nul = nullptr;
    float* nulf = nullptr;
    unsigned short* nulu = nullptr;

    {
        long long tot4 = (5LL * WSZ + 2LL * FSZ) / 4;
        wcvt_kernel<<<dim3((unsigned)((tot4 + 255) / 256)), dim3(256), 0, stream>>>(
            Wq, Wk, Wv, Wo, Wp, W1, W2, wbf);
    }
    bn_transpose_kernel<<<dim3(L / 64, Cc / 64, N), dim3(256), 0, stream>>>(
        x, n1g, n1b, n1m, n1v, hT, Cc, L);

    pool_bn_all_kernel<<<dim3(24, 2, N * 4), dim3(256), 0, stream>>>(
        x, n1g, n1b, n1m, n1v, xa0T_all, Cc, L);

    // grouped Q: all paths, block-diag Wq (128^2 kernel, K=128)
    gemm_bf<1><<<dim3(L / 128, 4, N), dim3(256), 0, stream>>>(
        WqB, hT, 512, 128, L, Cc, (long long)L * Cc,
        bq, 0.125f, F_BIAS,
        nul, nul, nul, nul, nul, nul, nul, nul,
        nulf, 0, nul, 0, qTall, 512, 0, (long long)L * 512, 128);

    // grouped Wp (all paths)
    gemm_path<0><<<dim3(23, 1, N), dim3(256), 0, stream>>>(
        WpB, nulu, xa0T_all, nul, nul,
        agg, agb, agm, agv, ang, anb, anm, anv,
        xabT_all, nulu);

    // grouped Wk+Wv (all paths)
    gemm_path<1><<<dim3(23, 2, N), dim3(256), 0, stream>>>(
        WkB, WvB, xabT_all, bk, bv,
        nul, nul, nul, nul, nul, nul, nul, nul,
        kT_all, vN_all);

    // all-path attention
    attn_bf_all_kernel<<<dim3(L / 64, N * 2, 4), dim3(256), 0, stream>>>(
        qTall, kT_all, vN_all, obT, L);

    // grouped Wo: out = x + Wo @ o + bo (f32), h2T aux = bf16(bn2(out))
    gemm_bf<3><<<dim3(L / 128, 4, N), dim3(256), 0, stream>>>(
        WoB, obT, 512, 128, L, 512, (long long)L * 512,
        bo, 1.f, F_BIAS | F_RESID,
        n2g, n2b, n2m, n2v,
        nul, nul, nul, nul,
        out, (long long)Cc * L,
        x, (long long)Cc * L,
        h2T, Cc, 0, (long long)L * Cc, 128);

    // FFN on the 256^2 8-wave pipeline
    // m1T = bf16(gelu(W1 @ h2 + b1))^T
    gemm_bf256<1, F_BIAS | F_GELU><<<dim3(L / 256, FF / 256, N), dim3(512), 0, stream>>>(
        W1B, h2T, Cc, L, Cc, (long long)L * Cc,
        b1,
        nulf, 0, nul, 0,
        m1T, FF, (long long)L * FF);

    // out += W2 @ m1 + b2
    gemm_bf256<0, F_BIAS | F_RESID><<<dim3(L / 256, Cc / 256, N), dim3(512), 0, stream>>>(
        W2B, m1T, FF, L, FF, (long long)L * FF,
        b2,
        out, (long long)Cc * L, out, (long long)Cc * L,
        nulu, 0, 0);
}

// Round 11
// 507.912 us; speedup vs baseline: 12.2637x; 1.0181x over previous
//
#include <hip/hip_runtime.h>
#include <math.h>

#define EPS 1e-5f

#define F_BIAS  1
#define F_DBN   2
#define F_GELU  4
#define F_RESID 8

typedef __attribute__((ext_vector_type(8))) __bf16 bf16x8;
typedef __attribute__((ext_vector_type(4))) float f32x4;
typedef __attribute__((ext_vector_type(8))) unsigned short u16x8;

__device__ __forceinline__ unsigned int pack2bf(float a, float b) {
    unsigned short ua = __builtin_bit_cast(unsigned short, (__bf16)a);
    unsigned short ub = __builtin_bit_cast(unsigned short, (__bf16)b);
    return (unsigned int)ua | ((unsigned int)ub << 16);
}

__device__ __forceinline__ void gload_lds16(const unsigned short* g, unsigned short* l) {
    __builtin_amdgcn_global_load_lds(
        (const __attribute__((address_space(1))) unsigned int*)g,
        (__attribute__((address_space(3))) unsigned int*)l,
        16, 0, 0);
}

// cheap tanh-gelu: u*sigmoid(2z)
__device__ __forceinline__ float gelu_f(float u) {
    float s = u * u;
    float w = u * fmaf(s, 0.0713548162726f, 1.59576912161f);
    float e = __expf(-w);
    return u * __builtin_amdgcn_rcpf(1.f + e);
}

// path constants: ratios {2,4,8,16}
__device__ __constant__ int c_LKS[4]  = {1536, 768, 384, 192};
__device__ __constant__ int c_OFFB[4] = {0, 1572864, 2359296, 2752512};

// ---------------------------------------------------------------------------
// weights fp32 -> bf16
// ---------------------------------------------------------------------------
__global__ __launch_bounds__(256) void wcvt_kernel(
    const float* __restrict__ Wq, const float* __restrict__ Wk,
    const float* __restrict__ Wv, const float* __restrict__ Wo,
    const float* __restrict__ Wp, const float* __restrict__ W1,
    const float* __restrict__ W2, unsigned short* __restrict__ dst)
{
    const int WSZ = 65536;
    const int FSZ = 1048576;
    int i4 = blockIdx.x * blockDim.x + threadIdx.x;
    long long i = (long long)i4 * 4;
    const long long total = 5LL * WSZ + 2LL * FSZ;
    if (i >= total) return;
    #pragma unroll
    for (int j = 0; j < 4; ++j) {
        long long idx = i + j;
        float v;
        if      (idx < WSZ)            v = Wq[idx];
        else if (idx < 2 * WSZ)        v = Wk[idx - WSZ];
        else if (idx < 3 * WSZ)        v = Wv[idx - 2 * WSZ];
        else if (idx < 4 * WSZ)        v = Wo[idx - 3 * WSZ];
        else if (idx < 5 * WSZ)        v = Wp[idx - 4 * WSZ];
        else if (idx < 5 * WSZ + FSZ)  v = W1[idx - 5 * WSZ];
        else                           v = W2[idx - 5 * WSZ - FSZ];
        dst[idx] = __builtin_bit_cast(unsigned short, (__bf16)v);
    }
}

// ---------------------------------------------------------------------------
// hT = bf16(bn1(x))^T : x (N,C,L) f32 -> hT (N,L,C) bf16
// ---------------------------------------------------------------------------
__global__ __launch_bounds__(256) void bn_transpose_kernel(
    const float* __restrict__ x,
    const float* __restrict__ g, const float* __restrict__ b,
    const float* __restrict__ bm, const float* __restrict__ bvv,
    unsigned short* __restrict__ hT, int C, int L)
{
    __shared__ float ps[64][65];
    const int l0 = blockIdx.x * 64, ct = blockIdx.y, n = blockIdx.z;
    const int tid = threadIdx.x;
    const int c = tid >> 2, q = tid & 3;
    const int cg = ct * 64 + c;
    float inv = g[cg] * rsqrtf(bvv[cg] + EPS);
    float add = b[cg] - bm[cg] * inv;
    const float* xp = x + ((size_t)n * C + cg) * L + l0 + q * 16;
    #pragma unroll
    for (int s = 0; s < 4; ++s) {
        float4 vv = *(const float4*)&xp[s * 4];
        ps[c][q * 16 + s * 4 + 0] = fmaf(vv.x, inv, add);
        ps[c][q * 16 + s * 4 + 1] = fmaf(vv.y, inv, add);
        ps[c][q * 16 + s * 4 + 2] = fmaf(vv.z, inv, add);
        ps[c][q * 16 + s * 4 + 3] = fmaf(vv.w, inv, add);
    }
    __syncthreads();
    #pragma unroll
    for (int j = 0; j < 2; ++j) {
        int row = (tid >> 3) + 32 * j;
        int cc0 = (tid & 7) * 8;
        unsigned int w0 = pack2bf(ps[cc0 + 0][row], ps[cc0 + 1][row]);
        unsigned int w1 = pack2bf(ps[cc0 + 2][row], ps[cc0 + 3][row]);
        unsigned int w2 = pack2bf(ps[cc0 + 4][row], ps[cc0 + 5][row]);
        unsigned int w3 = pack2bf(ps[cc0 + 6][row], ps[cc0 + 7][row]);
        *(uint4*)&hT[((size_t)n * L + l0 + row) * C + ct * 64 + cc0] =
            make_uint4(w0, w1, w2, w3);
    }
}

// ---------------------------------------------------------------------------
// Pool+BN1 for ALL paths in one dispatch: grid (24, 2, N*4)
// ---------------------------------------------------------------------------
__global__ __launch_bounds__(256) void pool_bn_all_kernel(
    const float* __restrict__ x,
    const float* __restrict__ g, const float* __restrict__ b,
    const float* __restrict__ bm, const float* __restrict__ bvv,
    unsigned short* __restrict__ xa0T_all, int C, int L)
{
    const int p = blockIdx.z & 3;
    const int n = blockIdx.z >> 2;
    const int Lk = c_LKS[p];
    const int lk0 = blockIdx.x * 64;
    if (lk0 >= Lk) return;
    const int r = L / Lk;
    const int ct = blockIdx.y;
    __shared__ float ps[64][65];
    const int tid = threadIdx.x;
    const int c = tid >> 2, q = tid & 3;
    const int cg = p * 128 + ct * 64 + c;
    float inv = g[cg] * rsqrtf(bvv[cg] + EPS);
    float add = b[cg] - bm[cg] * inv;
    const float* xp = x + ((size_t)n * C + cg) * L;
    float rinv = 1.0f / (float)r;
    #pragma unroll
    for (int s = 0; s < 16; ++s) {
        int lk = q * 16 + s;
        const float* base = xp + (size_t)(lk0 + lk) * r;
        float sum = 0.f, mx = -INFINITY;
        for (int j = 0; j < r; j += 2) {
            float2 vv = *(const float2*)&base[j];
            float t0 = fmaf(vv.x, inv, add);
            float t1 = fmaf(vv.y, inv, add);
            sum += t0 + t1;
            mx = fmaxf(mx, fmaxf(t0, t1));
        }
        ps[c][lk] = sum * rinv + mx;
    }
    __syncthreads();
    unsigned short* dst = xa0T_all + c_OFFB[p];
    #pragma unroll
    for (int j = 0; j < 2; ++j) {
        int row = (tid >> 3) + 32 * j;
        int cc0 = (tid & 7) * 8;
        unsigned int w0 = pack2bf(ps[cc0 + 0][row], ps[cc0 + 1][row]);
        unsigned int w1 = pack2bf(ps[cc0 + 2][row], ps[cc0 + 3][row]);
        unsigned int w2 = pack2bf(ps[cc0 + 4][row], ps[cc0 + 5][row]);
        unsigned int w3 = pack2bf(ps[cc0 + 6][row], ps[cc0 + 7][row]);
        *(uint4*)&dst[((size_t)n * Lk + lk0 + row) * 128 + ct * 64 + cc0] =
            make_uint4(w0, w1, w2, w3);
    }
}

// ---------------------------------------------------------------------------
// bf16 MFMA GEMM 128x128, counted-vmcnt 2-buffer pipeline (Wq/Wo shapes).
// ---------------------------------------------------------------------------
template<int OMODE>
__global__ __launch_bounds__(256) void gemm_bf(
    const unsigned short* __restrict__ A, const unsigned short* __restrict__ BT,
    int M, int K, int Npos, int ldBT, long long strideBT,
    const float* __restrict__ bias, float oscale, int flags,
    const float* __restrict__ g1, const float* __restrict__ b1p,
    const float* __restrict__ m1p, const float* __restrict__ v1p,
    const float* __restrict__ g2, const float* __restrict__ b2p,
    const float* __restrict__ m2p, const float* __restrict__ v2p,
    float* __restrict__ outN, long long strideN,
    const float* __restrict__ resid, long long strideR,
    unsigned short* __restrict__ outT, int ldT, int moff, long long strideT,
    int gKoff)
{
    __shared__ __align__(16) unsigned short As[2][128][32];
    __shared__ __align__(16) unsigned short Bs[2][128][32];

    const int tid = threadIdx.x;

    const int gdx = gridDim.x, gdy = gridDim.y;
    const int nwg = gdx * gdy * gridDim.z;
    int bid = blockIdx.x + gdx * (blockIdx.y + gdy * blockIdx.z);
    {
        int q = nwg >> 3, rr = nwg & 7;
        int xcd = bid & 7, idx = bid >> 3;
        bid = (xcd < rr ? xcd * (q + 1) : rr * (q + 1) + (xcd - rr) * q) + idx;
    }
    const int bx = bid % gdx;
    const int by = (bid / gdx) % gdy;
    const int bz = bid / (gdx * gdy);

    const int m0 = by * 128;
    const int p0 = bx * 128;
    const unsigned short* Bn = BT + (size_t)bz * strideBT
                              + (size_t)(m0 >> 7) * gKoff;

    const int wave = tid >> 6;
    const int lane = tid & 63;
    const int qcol = lane & 15;
    const int hi   = lane >> 4;
    const int wr   = wave >> 1;
    const int wc   = wave & 1;
    const int lrow = lane >> 2;
    const int lseg = (lane & 3) * 8;

    const unsigned short* aR0 = A + (size_t)(m0 + wave * 32 + lrow) * K + lseg;
    const unsigned short* aR1 = aR0 + (size_t)16 * K;
    int pr0 = p0 + wave * 32 + lrow;      if (pr0 > Npos - 1) pr0 = Npos - 1;
    int pr1 = p0 + wave * 32 + 16 + lrow; if (pr1 > Npos - 1) pr1 = Npos - 1;
    const unsigned short* bR0 = Bn + (size_t)pr0 * ldBT + lseg;
    const unsigned short* bR1 = Bn + (size_t)pr1 * ldBT + lseg;
    unsigned short* ldsA0 = &As[0][wave * 32][0];
    unsigned short* ldsA1 = &As[0][wave * 32 + 16][0];
    unsigned short* ldsB0 = &Bs[0][wave * 32][0];
    unsigned short* ldsB1 = &Bs[0][wave * 32 + 16][0];
    const int bufStride = 128 * 32;

    auto STAGE = [&](int b, int t) {
        const int ko = t * 32;
        gload_lds16(aR0 + ko, ldsA0 + b * bufStride);
        gload_lds16(aR1 + ko, ldsA1 + b * bufStride);
        gload_lds16(bR0 + ko, ldsB0 + b * bufStride);
        gload_lds16(bR1 + ko, ldsB1 + b * bufStride);
    };

    f32x4 acc[4][4] = {};
    const int nt = K >> 5;

    STAGE(0, 0);
    STAGE(1, 1);

    auto MFMA_STEP = [&](int b) {
        bf16x8 af[4], bfr[4];
        #pragma unroll
        for (int mi = 0; mi < 4; ++mi)
            af[mi] = *(const bf16x8*)&As[b][wr * 64 + mi * 16 + qcol][hi * 8];
        #pragma unroll
        for (int ni = 0; ni < 4; ++ni)
            bfr[ni] = *(const bf16x8*)&Bs[b][wc * 64 + ni * 16 + qcol][hi * 8];
        #pragma unroll
        for (int mi = 0; mi < 4; ++mi)
            #pragma unroll
            for (int ni = 0; ni < 4; ++ni)
                acc[mi][ni] = __builtin_amdgcn_mfma_f32_16x16x32_bf16(
                    af[mi], bfr[ni], acc[mi][ni], 0, 0, 0);
    };

    int cur = 0;
    for (int t = 0; t < nt - 1; ++t) {
        asm volatile("s_waitcnt vmcnt(4)" ::: "memory");
        __builtin_amdgcn_s_barrier();
        MFMA_STEP(cur);
        __builtin_amdgcn_s_barrier();
        if (t + 2 < nt) STAGE(cur, t + 2);
        cur ^= 1;
    }
    asm volatile("s_waitcnt vmcnt(0)" ::: "memory");
    __builtin_amdgcn_s_barrier();
    MFMA_STEP(cur);

    float* Cn = outN + (size_t)bz * strideN;
    const float* Rn = resid + (size_t)bz * strideR;
    unsigned short* Tn = outT + (size_t)bz * strideT;

    #pragma unroll
    for (int mi = 0; mi < 4; ++mi) {
        const int mb = m0 + wr * 64 + mi * 16 + hi * 4;
        float4 bv4 = make_float4(0.f, 0.f, 0.f, 0.f);
        if (flags & F_BIAS) bv4 = *(const float4*)&bias[mb];
        float s1[4], t1[4];
        if ((flags & F_DBN) || OMODE == 3) {
            float4 gg = *(const float4*)&g1[mb];
            float4 bb = *(const float4*)&b1p[mb];
            float4 mm = *(const float4*)&m1p[mb];
            float4 vv = *(const float4*)&v1p[mb];
            float gga[4] = {gg.x, gg.y, gg.z, gg.w};
            float bba[4] = {bb.x, bb.y, bb.z, bb.w};
            float mma[4] = {mm.x, mm.y, mm.z, mm.w};
            float vva[4] = {vv.x, vv.y, vv.z, vv.w};
            #pragma unroll
            for (int r2 = 0; r2 < 4; ++r2) {
                float iv = gga[r2] * rsqrtf(vva[r2] + EPS);
                s1[r2] = iv; t1[r2] = bba[r2] - mma[r2] * iv;
            }
        }
        float s2[4], t2[4];
        if (flags & F_DBN) {
            float4 gg = *(const float4*)&g2[mb];
            float4 bb = *(const float4*)&b2p[mb];
            float4 mm = *(const float4*)&m2p[mb];
            float4 vv = *(const float4*)&v2p[mb];
            float gga[4] = {gg.x, gg.y, gg.z, gg.w};
            float bba[4] = {bb.x, bb.y, bb.z, bb.w};
            float mma[4] = {mm.x, mm.y, mm.z, mm.w};
            float vva[4] = {vv.x, vv.y, vv.z, vv.w};
            #pragma unroll
            for (int r2 = 0; r2 < 4; ++r2) {
                float iv = gga[r2] * rsqrtf(vva[r2] + EPS);
                s2[r2] = iv; t2[r2] = bba[r2] - mma[r2] * iv;
            }
        }
        const float ba[4] = {bv4.x, bv4.y, bv4.z, bv4.w};
        #pragma unroll
        for (int ni = 0; ni < 4; ++ni) {
            const int cp = p0 + wc * 64 + ni * 16 + qcol;
            if (cp >= Npos) continue;
            float vals[4];
            #pragma unroll
            for (int r2 = 0; r2 < 4; ++r2) {
                float val = (acc[mi][ni][r2] + ba[r2]) * oscale;
                if (flags & F_DBN) {
                    val = fmaf(val, s1[r2], t1[r2]);
                    val = fmaf(val, s2[r2], t2[r2]);
                }
                if (flags & F_GELU) val = gelu_f(val);
                vals[r2] = val;
            }
            if (OMODE == 0 || OMODE == 3) {
                #pragma unroll
                for (int r2 = 0; r2 < 4; ++r2) {
                    size_t off = (size_t)(mb + r2) * Npos + cp;
                    float v = vals[r2];
                    if (flags & F_RESID) v += Rn[off];
                    Cn[off] = v;
                    vals[r2] = v;
                }
            }
            if (OMODE == 1) {
                *(uint2*)&Tn[(size_t)cp * ldT + moff + mb] =
                    make_uint2(pack2bf(vals[0], vals[1]), pack2bf(vals[2], vals[3]));
            }
            if (OMODE == 2) {
                #pragma unroll
                for (int r2 = 0; r2 < 4; ++r2)
                    Tn[(size_t)(mb + r2) * Npos + cp] =
                        __builtin_bit_cast(unsigned short, (__bf16)vals[r2]);
            }
            if (OMODE == 3) {
                float a0 = fmaf(vals[0], s1[0], t1[0]);
                float a1 = fmaf(vals[1], s1[1], t1[1]);
                float a2 = fmaf(vals[2], s1[2], t1[2]);
                float a3 = fmaf(vals[3], s1[3], t1[3]);
                *(uint2*)&Tn[(size_t)cp * ldT + moff + mb] =
                    make_uint2(pack2bf(a0, a1), pack2bf(a2, a3));
            }
        }
    }
}

// ---------------------------------------------------------------------------
// bf16 MFMA GEMM 256x256, 8 waves, BK=64 -- 8-PHASE schedule (m201 template):
// 4 phases per K-tile, phase (a,b) = {mi-half a}x{ni-half b}, 16 MFMA between
// two raw barriers with setprio(1) (T5). Staging is part-granular:
//   A-halfpair(a): rows {a*64..a*64+63} U {128+a*64..}, read only in phases a*2,a*2+1
//   B-quarterpair(b): rows {wc*64+b*32..+31 for all wc}, read in phases b, b+2
// Issue map: q0 -> A1(t+1), q1 -> B1(t+1), q2 -> A0(t+2), q3 -> B0(t+2)
//   (each part's rows last-read >=1 barrier before its overwrite is issued).
// Counted vmcnt once per tile: vmcnt(4) leaves only {A0,B0}(t+2) in flight and
// guarantees tile t+1 fully landed; drain vmcnt(0) at t==nt-2.
// LDS XOR-swizzle (T2, proven 0-conflict in round 10): slot = seg ^ (row&7),
// source pre-swizzled, read-side XOR inverts.
// OMODE: 0 = f32 natural out (+resid);  1 = bf16 transposed out [cp][ldT].
// ---------------------------------------------------------------------------
template<int OMODE, int FLAGS>
__global__ __launch_bounds__(512, 1) void gemm_bf256(
    const unsigned short* __restrict__ A, const unsigned short* __restrict__ BT,
    int K, int Npos, int ldBT, long long strideBT,
    const float* __restrict__ bias,
    float* __restrict__ outN, long long strideN,
    const float* __restrict__ resid, long long strideR,
    unsigned short* __restrict__ outT, int ldT, long long strideT)
{
    __shared__ __align__(16) unsigned short As[2][256][64];
    __shared__ __align__(16) unsigned short Bs[2][256][64];

    const int tid = threadIdx.x;

    // bijective XCD-chunked swizzle (m204)
    const int gdx = gridDim.x, gdy = gridDim.y;
    const int nwg = gdx * gdy * gridDim.z;
    int bid = blockIdx.x + gdx * (blockIdx.y + gdy * blockIdx.z);
    {
        int q = nwg >> 3, rr = nwg & 7;
        int xcd = bid & 7, idx = bid >> 3;
        bid = (xcd < rr ? xcd * (q + 1) : rr * (q + 1) + (xcd - rr) * q) + idx;
    }
    const int bx = bid % gdx;
    const int by = (bid / gdx) % gdy;
    const int bz = bid / (gdx * gdy);

    const int m0 = by * 256;
    const int p0 = bx * 256;
    const unsigned short* Bn = BT + (size_t)bz * strideBT;

    const int wave = tid >> 6;
    const int lane = tid & 63;
    const int qcol = lane & 15;
    const int hi   = lane >> 4;
    const int wr   = wave >> 2;      // 0..1  (M-half, 128 rows)
    const int wc   = wave & 3;       // 0..3  (N-quarter, 64 cols)

    // staging lane roles: row-in-gload = lane>>3, slot = lane&7,
    // source seg = (lane&7)^(lane>>3)  (involution with read-side XOR)
    const int lrow8 = lane >> 3;
    const int scol  = ((lane & 7) ^ lrow8) * 8;

    // part-relative row bases for this wave's two gloads
    const int rb0 = wave * 16, rb1 = rb0 + 8;
    const int pa00 = rb0 + ((rb0 >> 6) << 6);           // A-hp0
    const int pa01 = rb1 + ((rb1 >> 6) << 6);
    const int pa10 = 64 + rb0 + ((rb0 >> 6) << 6);      // A-hp1
    const int pa11 = 64 + rb1 + ((rb1 >> 6) << 6);
    const int pb00 = ((rb0 >> 5) << 6) + (rb0 & 31);        // B-qp0
    const int pb01 = ((rb1 >> 5) << 6) + (rb1 & 31);
    const int pb10 = ((rb0 >> 5) << 6) + 32 + (rb0 & 31);   // B-qp1
    const int pb11 = ((rb1 >> 5) << 6) + 32 + (rb1 & 31);

    const unsigned short* sa00 = A + (size_t)(m0 + pa00 + lrow8) * K + scol;
    const unsigned short* sa01 = A + (size_t)(m0 + pa01 + lrow8) * K + scol;
    const unsigned short* sa10 = A + (size_t)(m0 + pa10 + lrow8) * K + scol;
    const unsigned short* sa11 = A + (size_t)(m0 + pa11 + lrow8) * K + scol;
    const unsigned short* sb00 = Bn + (size_t)(p0 + pb00 + lrow8) * ldBT + scol;
    const unsigned short* sb01 = Bn + (size_t)(p0 + pb01 + lrow8) * ldBT + scol;
    const unsigned short* sb10 = Bn + (size_t)(p0 + pb10 + lrow8) * ldBT + scol;
    const unsigned short* sb11 = Bn + (size_t)(p0 + pb11 + lrow8) * ldBT + scol;

    auto STAGE_A0 = [&](int buf, int tt) {
        const int ko = tt * 64;
        gload_lds16(sa00 + ko, &As[buf][pa00][0]);
        gload_lds16(sa01 + ko, &As[buf][pa01][0]);
    };
    auto STAGE_A1 = [&](int buf, int tt) {
        const int ko = tt * 64;
        gload_lds16(sa10 + ko, &As[buf][pa10][0]);
        gload_lds16(sa11 + ko, &As[buf][pa11][0]);
    };
    auto STAGE_B0 = [&](int buf, int tt) {
        const int ko = tt * 64;
        gload_lds16(sb00 + ko, &Bs[buf][pb00][0]);
        gload_lds16(sb01 + ko, &Bs[buf][pb01][0]);
    };
    auto STAGE_B1 = [&](int buf, int tt) {
        const int ko = tt * 64;
        gload_lds16(sb10 + ko, &Bs[buf][pb10][0]);
        gload_lds16(sb11 + ko, &Bs[buf][pb11][0]);
    };

    const int xr0 = (hi ^ (qcol & 7)) * 8;

    f32x4 acc[8][4] = {};
    const int nt = K >> 6;        // >= 8 for our shapes

    // prologue: tile 0 fully + tile 1's {A-hp0, B-qp0}
    STAGE_A0(0, 0); STAGE_B0(0, 0); STAGE_A1(0, 0); STAGE_B1(0, 0);
    if (nt > 1) { STAGE_A0(1, 1); STAGE_B0(1, 1); }
    asm volatile("s_waitcnt vmcnt(4)" ::: "memory");
    __builtin_amdgcn_s_barrier();

#define PH_READ(a, b)                                                         \
    bf16x8 af[4][2], bfr[2][2];                                               \
    _Pragma("unroll") for (int m2 = 0; m2 < 4; ++m2)                          \
    _Pragma("unroll") for (int kk = 0; kk < 2; ++kk)                          \
        af[m2][kk] = *(const bf16x8*)&As[cur][wr * 128 + (a) * 64 + m2 * 16 + qcol][xr0 ^ (kk << 5)]; \
    _Pragma("unroll") for (int n2 = 0; n2 < 2; ++n2)                          \
    _Pragma("unroll") for (int kk = 0; kk < 2; ++kk)                          \
        bfr[n2][kk] = *(const bf16x8*)&Bs[cur][wc * 64 + ((b) * 2 + n2) * 16 + qcol][xr0 ^ (kk << 5)];

#define PH_MMA(a, b)                                                          \
    __builtin_amdgcn_s_barrier();                                             \
    __builtin_amdgcn_s_setprio(1);                                            \
    _Pragma("unroll") for (int m2 = 0; m2 < 4; ++m2)                          \
    _Pragma("unroll") for (int n2 = 0; n2 < 2; ++n2)                          \
    _Pragma("unroll") for (int kk = 0; kk < 2; ++kk)                          \
        acc[(a) * 4 + m2][(b) * 2 + n2] = __builtin_amdgcn_mfma_f32_16x16x32_bf16( \
            af[m2][kk], bfr[n2][kk], acc[(a) * 4 + m2][(b) * 2 + n2], 0, 0, 0);    \
    __builtin_amdgcn_s_setprio(0);                                            \
    __builtin_amdgcn_s_barrier();

    int cur = 0;
    for (int t = 0; t < nt; ++t) {
        const int nxt = cur ^ 1;
        {   // phase 0: mi 0-3, ni 0-1 | stage A-hp1(t+1) into nxt
            PH_READ(0, 0)
            if (t + 1 < nt) STAGE_A1(nxt, t + 1);
            PH_MMA(0, 0)
        }
        {   // phase 1: mi 0-3, ni 2-3 | stage B-qp1(t+1) into nxt
            PH_READ(0, 1)
            if (t + 1 < nt) STAGE_B1(nxt, t + 1);
            PH_MMA(0, 1)
        }
        {   // phase 2: mi 4-7, ni 0-1 | stage A-hp0(t+2) into cur
            PH_READ(1, 0)
            if (t + 2 < nt) STAGE_A0(cur, t + 2);
            PH_MMA(1, 0)
        }
        {   // phase 3: mi 4-7, ni 2-3 | stage B-qp0(t+2); tile-end wait
            PH_READ(1, 1)
            if (t + 2 < nt) STAGE_B0(cur, t + 2);
            if (t + 2 < nt) {
                asm volatile("s_waitcnt vmcnt(4)" ::: "memory");
            } else if (t + 2 == nt) {
                asm volatile("s_waitcnt vmcnt(0)" ::: "memory");
            }
            PH_MMA(1, 1)
        }
        cur = nxt;
    }
#undef PH_READ
#undef PH_MMA

    float* Cn = outN + (size_t)bz * strideN;
    const float* Rn = resid + (size_t)bz * strideR;
    unsigned short* Tn = outT + (size_t)bz * strideT;

    #pragma unroll
    for (int mi = 0; mi < 8; ++mi) {
        const int mb = m0 + wr * 128 + mi * 16 + hi * 4;
        float ba[4] = {0.f, 0.f, 0.f, 0.f};
        if (FLAGS & F_BIAS) {
            float4 bv4 = *(const float4*)&bias[mb];
            ba[0] = bv4.x; ba[1] = bv4.y; ba[2] = bv4.z; ba[3] = bv4.w;
        }
        #pragma unroll
        for (int ni = 0; ni < 4; ++ni) {
            const int cp = p0 + wc * 64 + ni * 16 + qcol;
            float vals[4];
            #pragma unroll
            for (int r2 = 0; r2 < 4; ++r2) {
                float val = acc[mi][ni][r2] + ba[r2];
                if (FLAGS & F_GELU) val = gelu_f(val);
                vals[r2] = val;
            }
            if (OMODE == 0) {
                #pragma unroll
                for (int r2 = 0; r2 < 4; ++r2) {
                    size_t off = (size_t)(mb + r2) * Npos + cp;
                    float v = vals[r2];
                    if (FLAGS & F_RESID) v += Rn[off];
                    Cn[off] = v;
                }
            } else {
                *(uint2*)&Tn[(size_t)cp * ldT + mb] =
                    make_uint2(pack2bf(vals[0], vals[1]), pack2bf(vals[2], vals[3]));
            }
        }
    }
}

// ---------------------------------------------------------------------------
// Grouped per-path GEMM (K=128, M=128 per path), all 4 paths in one dispatch.
// ---------------------------------------------------------------------------
template<int MODE>
__global__ __launch_bounds__(256) void gemm_path(
    const unsigned short* __restrict__ A0, const unsigned short* __restrict__ A1,
    const unsigned short* __restrict__ Bsrc,
    const float* __restrict__ bias0, const float* __restrict__ bias1,
    const float* __restrict__ agg, const float* __restrict__ agb,
    const float* __restrict__ agm, const float* __restrict__ agv,
    const float* __restrict__ ang, const float* __restrict__ anb,
    const float* __restrict__ anm, const float* __restrict__ anv,
    unsigned short* __restrict__ out0, unsigned short* __restrict__ out1)
{
    __shared__ __align__(16) unsigned short As[2][128][32];
    __shared__ __align__(16) unsigned short Bs[2][128][32];

    const int tid = threadIdx.x;
    const int gdx = gridDim.x, gdy = gridDim.y;
    const int nwg = gdx * gdy * gridDim.z;
    int bid = blockIdx.x + gdx * (blockIdx.y + gdy * blockIdx.z);
    {
        int q = nwg >> 3, rr = nwg & 7;
        int xcd = bid & 7, idx = bid >> 3;
        bid = (xcd < rr ? xcd * (q + 1) : rr * (q + 1) + (xcd - rr) * q) + idx;
    }
    const int bx = bid % gdx;
    const int by = (bid / gdx) % gdy;
    const int bz = bid / (gdx * gdy);

    int p, px;
    if      (bx < 12) { p = 0; px = bx; }
    else if (bx < 18) { p = 1; px = bx - 12; }
    else if (bx < 21) { p = 2; px = bx - 18; }
    else              { p = 3; px = bx - 21; }
    const int Lk = c_LKS[p];
    const int offb = c_OFFB[p];
    const int c0 = p * 128;
    const int p0 = px * 128;
    const int K = 128;

    const unsigned short* A = (MODE == 1 && by == 1 ? A1 : A0) + p * 16384;
    const unsigned short* Bn = Bsrc + offb + (size_t)bz * Lk * 128;

    const int wave = tid >> 6;
    const int lane = tid & 63;
    const int qcol = lane & 15;
    const int hi   = lane >> 4;
    const int wr   = wave >> 1;
    const int wc   = wave & 1;
    const int lrow = lane >> 2;
    const int lseg = (lane & 3) * 8;

    const unsigned short* aR0 = A + (size_t)(wave * 32 + lrow) * K + lseg;
    const unsigned short* aR1 = aR0 + (size_t)16 * K;
    int pr0 = p0 + wave * 32 + lrow;      if (pr0 > Lk - 1) pr0 = Lk - 1;
    int pr1 = p0 + wave * 32 + 16 + lrow; if (pr1 > Lk - 1) pr1 = Lk - 1;
    const unsigned short* bR0 = Bn + (size_t)pr0 * 128 + lseg;
    const unsigned short* bR1 = Bn + (size_t)pr1 * 128 + lseg;
    unsigned short* ldsA0 = &As[0][wave * 32][0];
    unsigned short* ldsA1 = &As[0][wave * 32 + 16][0];
    unsigned short* ldsB0 = &Bs[0][wave * 32][0];
    unsigned short* ldsB1 = &Bs[0][wave * 32 + 16][0];
    const int bufStride = 128 * 32;

    auto STAGE = [&](int b, int t) {
        const int ko = t * 32;
        gload_lds16(aR0 + ko, ldsA0 + b * bufStride);
        gload_lds16(aR1 + ko, ldsA1 + b * bufStride);
        gload_lds16(bR0 + ko, ldsB0 + b * bufStride);
        gload_lds16(bR1 + ko, ldsB1 + b * bufStride);
    };

    f32x4 acc[4][4] = {};
    STAGE(0, 0);
    STAGE(1, 1);

    auto MFMA_STEP = [&](int b) {
        bf16x8 af[4], bfr[4];
        #pragma unroll
        for (int mi = 0; mi < 4; ++mi)
            af[mi] = *(const bf16x8*)&As[b][wr * 64 + mi * 16 + qcol][hi * 8];
        #pragma unroll
        for (int ni = 0; ni < 4; ++ni)
            bfr[ni] = *(const bf16x8*)&Bs[b][wc * 64 + ni * 16 + qcol][hi * 8];
        #pragma unroll
        for (int mi = 0; mi < 4; ++mi)
            #pragma unroll
            for (int ni = 0; ni < 4; ++ni)
                acc[mi][ni] = __builtin_amdgcn_mfma_f32_16x16x32_bf16(
                    af[mi], bfr[ni], acc[mi][ni], 0, 0, 0);
    };

    int cur = 0;
    const int nt = 4;
    for (int t = 0; t < nt - 1; ++t) {
        asm volatile("s_waitcnt vmcnt(4)" ::: "memory");
        __builtin_amdgcn_s_barrier();
        MFMA_STEP(cur);
        __builtin_amdgcn_s_barrier();
        if (t + 2 < nt) STAGE(cur, t + 2);
        cur ^= 1;
    }
    asm volatile("s_waitcnt vmcnt(0)" ::: "memory");
    __builtin_amdgcn_s_barrier();
    MFMA_STEP(cur);

    const bool isV = (MODE == 1 && by == 1);
    unsigned short* Tn = (isV ? out1 : out0) + offb + (size_t)bz * Lk * 128;
    const float* bias = (MODE == 0) ? nullptr : (by == 0 ? bias0 : bias1);

    #pragma unroll
    for (int mi = 0; mi < 4; ++mi) {
        const int mb = wr * 64 + mi * 16 + hi * 4;
        float ba[4] = {0.f, 0.f, 0.f, 0.f};
        if (MODE == 1) {
            float4 bv4 = *(const float4*)&bias[c0 + mb];
            ba[0] = bv4.x; ba[1] = bv4.y; ba[2] = bv4.z; ba[3] = bv4.w;
        }
        float s1[4], t1[4], s2[4], t2[4];
        if (MODE == 0) {
            #pragma unroll
            for (int r2 = 0; r2 < 4; ++r2) {
                int gm = c0 + mb + r2;
                float i1 = agg[gm] * rsqrtf(agv[gm] + EPS);
                s1[r2] = i1; t1[r2] = agb[gm] - agm[gm] * i1;
                float i2 = ang[gm] * rsqrtf(anv[gm] + EPS);
                s2[r2] = i2; t2[r2] = anb[gm] - anm[gm] * i2;
            }
        }
        #pragma unroll
        for (int ni = 0; ni < 4; ++ni) {
            const int cp = p0 + wc * 64 + ni * 16 + qcol;
            if (cp >= Lk) continue;
            float vals[4];
            #pragma unroll
            for (int r2 = 0; r2 < 4; ++r2) {
                float val = acc[mi][ni][r2] + ba[r2];
                if (MODE == 0) {
                    val = fmaf(val, s1[r2], t1[r2]);
                    val = fmaf(val, s2[r2], t2[r2]);
                }
                vals[r2] = val;
            }
            if (!isV) {
                *(uint2*)&Tn[(size_t)cp * 128 + mb] =
                    make_uint2(pack2bf(vals[0], vals[1]), pack2bf(vals[2], vals[3]));
            } else {
                #pragma unroll
                for (int r2 = 0; r2 < 4; ++r2)
                    Tn[(size_t)(mb + r2) * Lk + cp] =
                        __builtin_bit_cast(unsigned short, (__bf16)vals[r2]);
            }
        }
    }
}

// ---------------------------------------------------------------------------
// Flash attention, all paths; K/V staged in block-shared LDS (counted-vmcnt
// 2-buffer pipeline, XOR-swizzled both sides). grid (48, N*2, 4).
// ---------------------------------------------------------------------------
__global__ __launch_bounds__(256) void attn_bf_all_kernel(
    const unsigned short* __restrict__ qT, const unsigned short* __restrict__ kT_all,
    const unsigned short* __restrict__ vN_all, unsigned short* __restrict__ obT,
    int L)
{
    const int p = blockIdx.z;
    const int Lk = c_LKS[p];
    const int offb = c_OFFB[p];
    const int l0 = blockIdx.x * 64;
    const int nh = blockIdx.y;
    const int n = nh >> 1, h = nh & 1;
    const unsigned short* qn = qT + (size_t)n * L * 512 + p * 128 + h * 64;
    const unsigned short* kn = kT_all + offb + (size_t)n * Lk * 128 + h * 64;
    const unsigned short* vn = vN_all + offb + ((size_t)n * 128 + h * 64) * Lk;
    unsigned short*       on = obT + (size_t)n * L * 512 + p * 128 + h * 64;

    __shared__ __align__(16) unsigned short Ks[2][64][64];
    __shared__ __align__(16) unsigned short Vs[2][64][64];
    __shared__ __align__(16) unsigned short Ps[4][16][72];

    const int tid = threadIdx.x;
    const int wave = tid >> 6;
    const int lane = tid & 63;
    const int qcol = lane & 15;
    const int hi   = lane >> 4;
    const int ql   = wave * 16 + qcol;

    const int srow = lane >> 3;
    const int sxor = (lane & 7) ^ srow;
    const unsigned short* kS0 = kn + (size_t)(wave * 16 + srow) * 128 + sxor * 8;
    const unsigned short* kS1 = kn + (size_t)(wave * 16 + 8 + srow) * 128 + sxor * 8;
    const unsigned short* vS0 = vn + (size_t)(wave * 16 + srow) * Lk + sxor * 8;
    const unsigned short* vS1 = vn + (size_t)(wave * 16 + 8 + srow) * Lk + sxor * 8;
    unsigned short* ldsK0 = &Ks[0][wave * 16][0];
    unsigned short* ldsK1 = &Ks[0][wave * 16 + 8][0];
    unsigned short* ldsV0 = &Vs[0][wave * 16][0];
    unsigned short* ldsV1 = &Vs[0][wave * 16 + 8][0];
    const int bufStride = 64 * 64;

    auto STAGE = [&](int b, int t) {
        const int mc = t * 64;
        gload_lds16(kS0 + (size_t)mc * 128, ldsK0 + b * bufStride);
        gload_lds16(kS1 + (size_t)mc * 128, ldsK1 + b * bufStride);
        gload_lds16(vS0 + mc, ldsV0 + b * bufStride);
        gload_lds16(vS1 + mc, ldsV1 + b * bufStride);
    };

    const int x0 = (hi ^ (qcol & 7)) * 8;
    const int x1 = x0 ^ 32;

    bf16x8 qf0 = *(const bf16x8*)&qn[(size_t)(l0 + ql) * 512 + hi * 8];
    bf16x8 qf1 = *(const bf16x8*)&qn[(size_t)(l0 + ql) * 512 + 32 + hi * 8];

    f32x4 o_acc[4] = {};
    float mrow = -INFINITY, lrow = 0.f;
    const int nt = Lk >> 6;

    STAGE(0, 0);
    STAGE(1, 1);

    auto COMPUTE = [&](int b) {
        f32x4 sacc[4];
        #pragma unroll
        for (int kt = 0; kt < 4; ++kt) {
            bf16x8 k0 = *(const bf16x8*)&Ks[b][kt * 16 + qcol][x0];
            bf16x8 k1 = *(const bf16x8*)&Ks[b][kt * 16 + qcol][x1];
            f32x4 a = {};
            a = __builtin_amdgcn_mfma_f32_16x16x32_bf16(k0, qf0, a, 0, 0, 0);
            a = __builtin_amdgcn_mfma_f32_16x16x32_bf16(k1, qf1, a, 0, 0, 0);
            sacc[kt] = a;
        }
        float m0 = fmaxf(fmaxf(sacc[0][0], sacc[0][1]), fmaxf(sacc[0][2], sacc[0][3]));
        float m1 = fmaxf(fmaxf(sacc[1][0], sacc[1][1]), fmaxf(sacc[1][2], sacc[1][3]));
        float m2 = fmaxf(fmaxf(sacc[2][0], sacc[2][1]), fmaxf(sacc[2][2], sacc[2][3]));
        float m3 = fmaxf(fmaxf(sacc[3][0], sacc[3][1]), fmaxf(sacc[3][2], sacc[3][3]));
        float cm = fmaxf(fmaxf(m0, m1), fmaxf(m2, m3));
        cm = fmaxf(cm, __shfl_xor(cm, 16));
        cm = fmaxf(cm, __shfl_xor(cm, 32));
        float nm = fmaxf(mrow, cm);
        float alpha = __expf(mrow - nm);
        float csum = 0.f;
        unsigned int pw[4][2];
        #pragma unroll
        for (int kt = 0; kt < 4; ++kt) {
            float p0 = __expf(sacc[kt][0] - nm);
            float p1 = __expf(sacc[kt][1] - nm);
            float p2 = __expf(sacc[kt][2] - nm);
            float p3 = __expf(sacc[kt][3] - nm);
            csum += (p0 + p1) + (p2 + p3);
            pw[kt][0] = pack2bf(p0, p1);
            pw[kt][1] = pack2bf(p2, p3);
        }
        csum += __shfl_xor(csum, 16);
        csum += __shfl_xor(csum, 32);
        lrow = lrow * alpha + csum;
        mrow = nm;

        #pragma unroll
        for (int kt = 0; kt < 4; ++kt)
            *(uint2*)&Ps[wave][qcol][kt * 16 + hi * 4] =
                make_uint2(pw[kt][0], pw[kt][1]);

        #pragma unroll
        for (int et = 0; et < 4; ++et)
            #pragma unroll
            for (int r2 = 0; r2 < 4; ++r2) o_acc[et][r2] *= alpha;

        bf16x8 pf0 = *(const bf16x8*)&Ps[wave][qcol][hi * 8];
        bf16x8 pf1 = *(const bf16x8*)&Ps[wave][qcol][hi * 8 + 32];
        #pragma unroll
        for (int et = 0; et < 4; ++et) {
            bf16x8 v0 = *(const bf16x8*)&Vs[b][et * 16 + qcol][x0];
            bf16x8 v1 = *(const bf16x8*)&Vs[b][et * 16 + qcol][x1];
            o_acc[et] = __builtin_amdgcn_mfma_f32_16x16x32_bf16(v0, pf0, o_acc[et], 0, 0, 0);
            o_acc[et] = __builtin_amdgcn_mfma_f32_16x16x32_bf16(v1, pf1, o_acc[et], 0, 0, 0);
        }
    };

    int cur = 0;
    for (int t = 0; t < nt - 1; ++t) {
        asm volatile("s_waitcnt vmcnt(4)" ::: "memory");
        __builtin_amdgcn_s_barrier();
        COMPUTE(cur);
        __builtin_amdgcn_s_barrier();
        if (t + 2 < nt) STAGE(cur, t + 2);
        cur ^= 1;
    }
    asm volatile("s_waitcnt vmcnt(0)" ::: "memory");
    __builtin_amdgcn_s_barrier();
    COMPUTE(cur);

    float invl = 1.f / lrow;
    #pragma unroll
    for (int et = 0; et < 4; ++et) {
        float a0 = o_acc[et][0] * invl, a1 = o_acc[et][1] * invl;
        float a2 = o_acc[et][2] * invl, a3 = o_acc[et][3] * invl;
        *(uint2*)&on[(size_t)(l0 + ql) * 512 + et * 16 + hi * 4] =
            make_uint2(pack2bf(a0, a1), pack2bf(a2, a3));
    }
}

// ---------------------------------------------------------------------------
extern "C" void kernel_launch(void* const* d_in, const int* in_sizes, int n_in,
                              void* d_out, int out_size, void* d_ws, size_t ws_size,
                              hipStream_t stream)
{
    const float* x   = (const float*)d_in[0];
    const float* n1g = (const float*)d_in[1];
    const float* n1b = (const float*)d_in[2];
    const float* n1m = (const float*)d_in[3];
    const float* n1v = (const float*)d_in[4];
    const float* n2g = (const float*)d_in[5];
    const float* n2b = (const float*)d_in[6];
    const float* n2m = (const float*)d_in[7];
    const float* n2v = (const float*)d_in[8];
    const float* Wq  = (const float*)d_in[9];
    const float* Wk  = (const float*)d_in[10];
    const float* Wv  = (const float*)d_in[11];
    const float* Wo  = (const float*)d_in[12];
    const float* Wp  = (const float*)d_in[13];
    const float* bq  = (const float*)d_in[14];
    const float* bk  = (const float*)d_in[15];
    const float* bv  = (const float*)d_in[16];
    const float* bo  = (const float*)d_in[17];
    const float* agg = (const float*)d_in[18];
    const float* agb = (const float*)d_in[19];
    const float* agm = (const float*)d_in[20];
    const float* agv = (const float*)d_in[21];
    const float* ang = (const float*)d_in[22];
    const float* anb = (const float*)d_in[23];
    const float* anm = (const float*)d_in[24];
    const float* anv = (const float*)d_in[25];
    const float* W1  = (const float*)d_in[26];
    const float* b1  = (const float*)d_in[27];
    const float* W2  = (const float*)d_in[28];
    const float* b2  = (const float*)d_in[29];

    float* out = (float*)d_out;
    unsigned short* wsb = (unsigned short*)d_ws;

    const int N = 8, Cc = 512, L = 3072, FF = 2048;
    const int WSZ = 65536, FSZ = 1048576;
    const size_t PATHBUF = 2949120;

    unsigned short* wbf      = wsb;
    unsigned short* hT       = wbf      + 5 * WSZ + 2 * FSZ;
    unsigned short* h2T      = hT;                              // alias
    unsigned short* obT      = hT       + (size_t)N * L * Cc;
    unsigned short* xa0T_all = obT      + (size_t)N * L * 512;
    unsigned short* xabT_all = xa0T_all + PATHBUF;
    unsigned short* kT_all   = xabT_all + PATHBUF;
    unsigned short* vN_all   = kT_all   + PATHBUF;
    unsigned short* m1T      = vN_all   + PATHBUF;
    unsigned short* qTall    = m1T;

    const unsigned short* WqB = wbf;
    const unsigned short* WkB = wbf + WSZ;
    const unsigned short* WvB = wbf + 2 * WSZ;
    const unsigned short* WoB = wbf + 3 * WSZ;
    const unsigned short* WpB = wbf + 4 * WSZ;
    const unsigned short* W1B = wbf + 5 * WSZ;
    const unsigned short* W2B = wbf + 5 * WSZ + FSZ;

    const float* nul = nullptr;
    float* nulf = nullptr;
    unsigned short* nulu = nullptr;

    {
        long long tot4 = (5LL * WSZ + 2LL * FSZ) / 4;
        wcvt_kernel<<<dim3((unsigned)((tot4 + 255) / 256)), dim3(256), 0, stream>>>(
            Wq, Wk, Wv, Wo, Wp, W1, W2, wbf);
    }
    bn_transpose_kernel<<<dim3(L / 64, Cc / 64, N), dim3(256), 0, stream>>>(
        x, n1g, n1b, n1m, n1v, hT, Cc, L);

    pool_bn_all_kernel<<<dim3(24, 2, N * 4), dim3(256), 0, stream>>>(
        x, n1g, n1b, n1m, n1v, xa0T_all, Cc, L);

    // grouped Q: all paths, block-diag Wq (128^2 kernel, K=128)
    gemm_bf<1><<<dim3(L / 128, 4, N), dim3(256), 0, stream>>>(
        WqB, hT, 512, 128, L, Cc, (long long)L * Cc,
        bq, 0.125f, F_BIAS,
        nul, nul, nul, nul, nul, nul, nul, nul,
        nulf, 0, nul, 0, qTall, 512, 0, (long long)L * 512, 128);

    // grouped Wp (all paths)
    gemm_path<0><<<dim3(23, 1, N), dim3(256), 0, stream>>>(
        WpB, nulu, xa0T_all, nul, nul,
        agg, agb, agm, agv, ang, anb, anm, anv,
        xabT_all, nulu);

    // grouped Wk+Wv (all paths)
    gemm_path<1><<<dim3(23, 2, N), dim3(256), 0, stream>>>(
        WkB, WvB, xabT_all, bk, bv,
        nul, nul, nul, nul, nul, nul, nul, nul,
        kT_all, vN_all);

    // all-path attention
    attn_bf_all_kernel<<<dim3(L / 64, N * 2, 4), dim3(256), 0, stream>>>(
        qTall, kT_all, vN_all, obT, L);

    // grouped Wo: out = x + Wo @ o + bo (f32), h2T aux = bf16(bn2(out))
    gemm_bf<3><<<dim3(L / 128, 4, N), dim3(256), 0, stream>>>(
        WoB, obT, 512, 128, L, 512, (long long)L * 512,
        bo, 1.f, F_BIAS | F_RESID,
        n2g, n2b, n2m, n2v,
        nul, nul, nul, nul,
        out, (long long)Cc * L,
        x, (long long)Cc * L,
        h2T, Cc, 0, (long long)L * Cc, 128);

    // FFN on the 256^2 8-phase pipeline
    // m1T = bf16(gelu(W1 @ h2 + b1))^T
    gemm_bf256<1, F_BIAS | F_GELU><<<dim3(L / 256, FF / 256, N), dim3(512), 0, stream>>>(
        W1B, h2T, Cc, L, Cc, (long long)L * Cc,
        b1,
        nulf, 0, nul, 0,
        m1T, FF, (long long)L * FF);

    // out += W2 @ m1 + b2
    gemm_bf256<0, F_BIAS | F_RESID><<<dim3(L / 256, Cc / 256, N), dim3(512), 0, stream>>>(
        W2B, m1T, FF, L, FF, (long long)L * FF,
        b2,
        out, (long long)Cc * L, out, (long long)Cc * L,
        nulu, 0, 0);
}